// Round 1
// baseline (2912.713 us; speedup 1.0000x reference)
//
#include <hip/hip_runtime.h>
#include <math.h>

// ---- problem constants ----
static constexpr int B_    = 2;
static constexpr int N_    = 12544;   // 112*112
static constexpr int DIM_  = 512;
static constexpr int D0_   = 64;
static constexpr int DL_   = 448;
static constexpr int Himg  = 112;
static constexpr int Wimg  = 112;
static constexpr int HS_   = 56;
static constexpr int NR_   = 3136;    // 56*56
static constexpr int NH_   = 8;
static constexpr int HD_   = 28;

// =====================================================================
// Generic tiled fp32 GEMM: C[M,N] = A[M,K] @ W (+bias)
// BT=false: W row-major [K][N]; BT=true: W is [N][K] (transposed access)
// =====================================================================
template<bool BT, bool HASBIAS>
__global__ __launch_bounds__(256)
void gemm_kernel(const float* __restrict__ A, int lda,
                 const float* __restrict__ W,
                 const float* __restrict__ bias,
                 float* __restrict__ C, int ldc,
                 int M, int Nn, int K) {
    constexpr int BM = 64, BN = 64, BK = 16;
    __shared__ float As[BK][BM];
    __shared__ float Bs[BK][BN];
    const int bm = blockIdx.x * BM;
    const int bn = blockIdx.y * BN;
    const int t  = threadIdx.x;
    const int tx = t % 16, ty = t / 16;
    float acc[4][4] = {};
    for (int k0 = 0; k0 < K; k0 += BK) {
        #pragma unroll
        for (int i = 0; i < 4; ++i) {
            int k = t % BK;
            int m = t / BK + i * 16;
            As[k][m] = A[(size_t)(bm + m) * lda + k0 + k];
        }
        if (!BT) {
            #pragma unroll
            for (int i = 0; i < 4; ++i) {
                int n = t % BN;
                int k = t / BN + i * 4;
                Bs[k][n] = W[(size_t)(k0 + k) * Nn + bn + n];
            }
        } else {
            #pragma unroll
            for (int i = 0; i < 4; ++i) {
                int k = t % BK;
                int n = t / BK + i * 16;
                Bs[k][n] = W[(size_t)(bn + n) * K + k0 + k];
            }
        }
        __syncthreads();
        #pragma unroll
        for (int kk = 0; kk < BK; ++kk) {
            float a[4], b[4];
            #pragma unroll
            for (int i = 0; i < 4; ++i) a[i] = As[kk][ty * 4 + i];
            #pragma unroll
            for (int j = 0; j < 4; ++j) b[j] = Bs[kk][tx * 4 + j];
            #pragma unroll
            for (int i = 0; i < 4; ++i)
                #pragma unroll
                for (int j = 0; j < 4; ++j)
                    acc[i][j] += a[i] * b[j];
        }
        __syncthreads();
    }
    #pragma unroll
    for (int i = 0; i < 4; ++i) {
        int m = bm + ty * 4 + i;
        #pragma unroll
        for (int j = 0; j < 4; ++j) {
            int n = bn + tx * 4 + j;
            float v = acc[i][j];
            if (HASBIAS) v += bias[n];
            C[(size_t)m * ldc + n] = v;
        }
    }
}

// =====================================================================
// sr-conv (2x2 stride2, 64->64) + LayerNorm(64) + kv GEMM (64->128)
// one 64-thread block per output position
// =====================================================================
__global__ __launch_bounds__(64)
void srlnkv_kernel(const float* __restrict__ x,
                   const float* __restrict__ sr_w, const float* __restrict__ sr_b,
                   const float* __restrict__ ln_g, const float* __restrict__ ln_b,
                   const float* __restrict__ wkv,
                   float* __restrict__ kg, float* __restrict__ vg) {
    const int pos = blockIdx.x;              // b*NR + n
    const int b = pos / NR_, n = pos % NR_;
    const int y = n / HS_, xx = n % HS_;
    const int o = threadIdx.x;               // 0..63
    __shared__ float xs[4][64];
    __shared__ float lnv_s[64];
    #pragma unroll
    for (int tap = 0; tap < 4; ++tap) {
        int ky = tap / 2, kx = tap % 2;
        xs[tap][o] = x[((size_t)b * N_ + (2 * y + ky) * Wimg + 2 * xx + kx) * DIM_ + o];
    }
    __syncthreads();
    float sum = sr_b[o];
    for (int i = 0; i < 64; ++i) {
        const float* w = sr_w + o * 256 + i * 4;
        sum += xs[0][i] * w[0] + xs[1][i] * w[1] + xs[2][i] * w[2] + xs[3][i] * w[3];
    }
    // LN over 64 lanes (one wave)
    float m = sum;
    #pragma unroll
    for (int off = 1; off < 64; off <<= 1) m += __shfl_xor(m, off);
    m *= (1.0f / 64.0f);
    float d = sum - m;
    float v = d * d;
    #pragma unroll
    for (int off = 1; off < 64; off <<= 1) v += __shfl_xor(v, off);
    v *= (1.0f / 64.0f);
    float lnv = d * rsqrtf(v + 1e-5f) * ln_g[o] + ln_b[o];
    lnv_s[o] = lnv;
    __syncthreads();
    float s0 = 0.f, s1 = 0.f;
    for (int i = 0; i < 64; ++i) {
        float lv = lnv_s[i];
        s0 += lv * wkv[i * 128 + o];
        s1 += lv * wkv[i * 128 + o + 64];
    }
    kg[((size_t)b * NR_ + n) * 64 + o] = s0;
    vg[((size_t)b * NR_ + n) * 64 + o] = s1;
}

// =====================================================================
// depthwise 3x3 + bias on v_g image (B,64,56,56), vg stored (B,NR,64)
// vg2 = vg + conv
// =====================================================================
__global__ __launch_bounds__(256)
void lcg_kernel(const float* __restrict__ vg, const float* __restrict__ w,
                const float* __restrict__ bias, float* __restrict__ vg2) {
    int idx = blockIdx.x * 256 + threadIdx.x;
    if (idx >= B_ * NR_ * 64) return;
    int c = idx % 64;
    int n = (idx / 64) % NR_;
    int b = idx / (64 * NR_);
    int y = n / HS_, xx = n % HS_;
    float sum = vg[idx] + bias[c];
    #pragma unroll
    for (int ky = 0; ky < 3; ++ky)
        #pragma unroll
        for (int kx = 0; kx < 3; ++kx) {
            int yy = y + ky - 1, x2 = xx + kx - 1;
            if (yy >= 0 && yy < HS_ && x2 >= 0 && x2 < HS_)
                sum += vg[((size_t)b * NR_ + yy * HS_ + x2) * 64 + c] * w[c * 9 + ky * 3 + kx];
        }
    vg2[idx] = sum;
}

// =====================================================================
// flash attention, global branch. q cols 0..63 of (B,N,512).
// out -> cat cols 0..63.  32 q-rows/block, 256 threads.
// =====================================================================
__global__ __launch_bounds__(256)
void attn_global_kernel(const float* __restrict__ q,
                        const float* __restrict__ kg,
                        const float* __restrict__ vg,
                        float* __restrict__ cat) {
    constexpr int TQ = 32, TK = 64;
    __shared__ float Qs[TQ][64];
    __shared__ float Ks[TK][64];
    __shared__ float Vs[TK][64];
    __shared__ float Ps[TQ][TK];
    const int b  = blockIdx.y;
    const int n0 = blockIdx.x * TQ;
    const int t  = threadIdx.x;
    for (int i = t; i < TQ * 64; i += 256) {
        int r = i / 64, d = i % 64;
        Qs[r][d] = q[((size_t)b * N_ + n0 + r) * DIM_ + d];
    }
    const int r = t / 8, c = t % 8;
    float m_run = -1e30f, l_run = 0.f;
    float acc[8] = {};
    const float scale = 0.125f;
    for (int k0 = 0; k0 < NR_; k0 += TK) {
        for (int i = t; i < TK * 64; i += 256) {
            int mm = i / 64, d = i % 64;
            Ks[mm][d] = kg[((size_t)b * NR_ + k0 + mm) * 64 + d];
            Vs[mm][d] = vg[((size_t)b * NR_ + k0 + mm) * 64 + d];
        }
        __syncthreads();
        float s[8];
        float tmax = -1e30f;
        #pragma unroll
        for (int j = 0; j < 8; ++j) {
            int mm = c * 8 + j;
            float sum = 0.f;
            #pragma unroll
            for (int d = 0; d < 64; ++d) sum += Qs[r][d] * Ks[mm][d];
            s[j] = sum * scale;
            tmax = fmaxf(tmax, s[j]);
        }
        #pragma unroll
        for (int off = 1; off < 8; off <<= 1) tmax = fmaxf(tmax, __shfl_xor(tmax, off));
        float m_new = fmaxf(m_run, tmax);
        float corr = __expf(m_run - m_new);
        float psum = 0.f;
        #pragma unroll
        for (int j = 0; j < 8; ++j) { s[j] = __expf(s[j] - m_new); psum += s[j]; }
        #pragma unroll
        for (int off = 1; off < 8; off <<= 1) psum += __shfl_xor(psum, off);
        l_run = l_run * corr + psum;
        m_run = m_new;
        #pragma unroll
        for (int j = 0; j < 8; ++j) Ps[r][c * 8 + j] = s[j];
        __syncthreads();
        #pragma unroll
        for (int i = 0; i < 8; ++i) acc[i] *= corr;
        for (int mm = 0; mm < TK; ++mm) {
            float pm = Ps[r][mm];
            #pragma unroll
            for (int i = 0; i < 8; ++i) acc[i] += pm * Vs[mm][c * 8 + i];
        }
        __syncthreads();
    }
    float inv = 1.f / l_run;
    #pragma unroll
    for (int i = 0; i < 8; ++i)
        cat[((size_t)b * N_ + n0 + r) * DIM_ + c * 8 + i] = acc[i] * inv;
}

// =====================================================================
// depthwise 3x3 + bias on x_l (channels 64..511 of x), out (B,N,448)
// =====================================================================
__global__ __launch_bounds__(256)
void dwt_kernel(const float* __restrict__ x, const float* __restrict__ w,
                const float* __restrict__ bias, float* __restrict__ out) {
    int idx = blockIdx.x * 256 + threadIdx.x;
    if (idx >= B_ * N_ * DL_) return;
    int c = idx % DL_;
    int n = (idx / DL_) % N_;
    int b = idx / (DL_ * N_);
    int y = n / Wimg, xx = n % Wimg;
    float sum = bias[c];
    #pragma unroll
    for (int ky = 0; ky < 3; ++ky)
        #pragma unroll
        for (int kx = 0; kx < 3; ++kx) {
            int yy = y + ky - 1, x2 = xx + kx - 1;
            if (yy >= 0 && yy < Himg && x2 >= 0 && x2 < Wimg)
                sum += x[((size_t)b * N_ + yy * Wimg + x2) * DIM_ + D0_ + c] * w[c * 9 + ky * 3 + kx];
        }
    out[idx] = sum;
}

// =====================================================================
// "scrambled mean": kvm[b,h,n,d2] = mean_{l2} flat[d2*L + l2],
// flat[l*hd+d] = kvl[b, pixel(l,n), choff + h*hd + d]
// =====================================================================
__global__ __launch_bounds__(256)
void local_mean_kernel(const float* __restrict__ kvl, float* __restrict__ kvm,
                       int L, int nBW, int stride, int dil, int choff) {
    int idx = blockIdx.x * 256 + threadIdx.x;
    if (idx >= B_ * NH_ * 49 * HD_) return;
    int d2 = idx % HD_;
    int n  = (idx / HD_) % 49;
    int h  = (idx / (HD_ * 49)) % NH_;
    int b  = idx / (HD_ * 49 * NH_);
    int wy = n / 7, wx = n % 7;
    float sum = 0.f;
    int f0 = d2 * L;
    for (int l2 = 0; l2 < L; ++l2) {
        int f = f0 + l2;
        int l = f / HD_;
        int d = f - l * HD_;
        int by = l / nBW, bx = l % nBW;
        int Y = by * stride + dil * wy;
        int X = bx * stride + dil * wx;
        if (Y >= Himg) Y = 2 * Himg - 2 - Y;   // reflect
        if (X >= Wimg) X = 2 * Wimg - 2 - X;
        sum += kvl[((size_t)b * N_ + Y * Wimg + X) * DL_ + choff + h * HD_ + d];
    }
    kvm[idx] = sum * (1.0f / (float)L);
}

// =====================================================================
// kv = kvm @ fc_w @ sh_w -> (B*NH, 49, 56). one 64-thread block per (b,h)
// =====================================================================
__global__ __launch_bounds__(64)
void fcsh_kernel(const float* __restrict__ kvm, const float* __restrict__ fcw,
                 const float* __restrict__ shw, float* __restrict__ out) {
    int bh = blockIdx.x;
    __shared__ float kin[49][28];
    __shared__ float tmp[49][28];
    __shared__ float fw[28 * 28];
    __shared__ float sw[28 * 56];
    int t = threadIdx.x;
    for (int i = t; i < 49 * 28; i += 64) kin[i / 28][i % 28] = kvm[bh * 49 * 28 + i];
    for (int i = t; i < 28 * 28; i += 64) fw[i] = fcw[i];
    for (int i = t; i < 28 * 56; i += 64) sw[i] = shw[i];
    __syncthreads();
    for (int i = t; i < 49 * 28; i += 64) {
        int rr = i / 28, j = i % 28;
        float s = 0.f;
        for (int k = 0; k < 28; ++k) s += kin[rr][k] * fw[k * 28 + j];
        tmp[rr][j] = s;
    }
    __syncthreads();
    for (int i = t; i < 49 * 56; i += 64) {
        int rr = i / 56, j = i % 56;
        float s = 0.f;
        for (int k = 0; k < 28; ++k) s += tmp[rr][k] * sw[k * 56 + j];
        out[bh * 49 * 56 + i] = s;
    }
}

// =====================================================================
// v_ + depthwise3x3(v_img 7x7) + bias -> vc (B*NH, 49, 28)
// =====================================================================
__global__ __launch_bounds__(256)
void vconv_kernel(const float* __restrict__ kvsh, const float* __restrict__ w,
                  const float* __restrict__ bias, float* __restrict__ vc) {
    int idx = blockIdx.x * 256 + threadIdx.x;
    if (idx >= B_ * NH_ * 49 * HD_) return;
    int d  = idx % HD_;
    int n  = (idx / HD_) % 49;
    int bh = idx / (HD_ * 49);
    int h  = bh % NH_;
    int y = n / 7, xx = n % 7;
    int c = h * HD_ + d;
    float sum = kvsh[(bh * 49 + n) * 56 + 28 + d] + bias[c];
    #pragma unroll
    for (int ky = 0; ky < 3; ++ky)
        #pragma unroll
        for (int kx = 0; kx < 3; ++kx) {
            int yy = y + ky - 1, x2 = xx + kx - 1;
            if (yy >= 0 && yy < 7 && x2 >= 0 && x2 < 7)
                sum += kvsh[(bh * 49 + yy * 7 + x2) * 56 + 28 + d] * w[c * 9 + ky * 3 + kx];
        }
    vc[idx] = sum;
}

// =====================================================================
// local attention: 49 keys, hd=28.  one thread per q-row.
// grid (N/256, B*NH); k in kvsh cols 0..27; v in vc.
// =====================================================================
__global__ __launch_bounds__(256)
void attn_local_kernel(const float* __restrict__ q, const float* __restrict__ kvsh,
                       const float* __restrict__ vc, float* __restrict__ cat,
                       int qcoloff, int outcoloff) {
    const int bh = blockIdx.y;
    const int b = bh / NH_, h = bh % NH_;
    const int n = blockIdx.x * 256 + threadIdx.x;
    __shared__ float Ks[49][28];
    __shared__ float Vsh[49][28];
    const int t = threadIdx.x;
    for (int i = t; i < 49 * 28; i += 256) {
        int rr = i / 28, d = i % 28;
        Ks[rr][d]  = kvsh[(bh * 49 + rr) * 56 + d];
        Vsh[rr][d] = vc[(bh * 49 + rr) * 28 + d];
    }
    __syncthreads();
    float qr[28];
    const float* qp = q + ((size_t)b * N_ + n) * DIM_ + qcoloff + h * 56;
    #pragma unroll
    for (int d = 0; d < 28; ++d) qr[d] = qp[d];
    const float scale = 0.1889822365046136f;   // 28^-0.5
    // pass 1: max
    float mx = -1e30f;
    for (int k = 0; k < 49; ++k) {
        float s = 0.f;
        #pragma unroll
        for (int d = 0; d < 28; ++d) s += qr[d] * Ks[k][d];
        mx = fmaxf(mx, s * scale);
    }
    // pass 2: exp + weighted accumulate
    float l = 0.f;
    float acc[28] = {};
    for (int k = 0; k < 49; ++k) {
        float s = 0.f;
        #pragma unroll
        for (int d = 0; d < 28; ++d) s += qr[d] * Ks[k][d];
        float p = __expf(s * scale - mx);
        l += p;
        #pragma unroll
        for (int d = 0; d < 28; ++d) acc[d] += p * Vsh[k][d];
    }
    float inv = 1.f / l;
    float* op = cat + ((size_t)b * N_ + n) * DIM_ + outcoloff + h * HD_;
    #pragma unroll
    for (int d = 0; d < 28; ++d) op[d] = acc[d] * inv;
}

// =====================================================================
extern "C" void kernel_launch(void* const* d_in, const int* in_sizes, int n_in,
                              void* d_out, int out_size, void* d_ws, size_t ws_size,
                              hipStream_t stream) {
    const float* x      = (const float*)d_in[0];
    const float* Wq     = (const float*)d_in[1];
    const float* Wkv_g  = (const float*)d_in[2];
    const float* sr_w   = (const float*)d_in[3];
    const float* sr_b   = (const float*)d_in[4];
    const float* ln_g   = (const float*)d_in[5];
    const float* ln_b   = (const float*)d_in[6];
    const float* lcg_w  = (const float*)d_in[7];
    const float* lcg_b  = (const float*)d_in[8];
    const float* kvl_dw = (const float*)d_in[9];
    const float* kvl_db = (const float*)d_in[10];
    const float* kvl_pw = (const float*)d_in[11];
    const float* kvl_pb = (const float*)d_in[12];
    const float* fc1_w  = (const float*)d_in[13];
    const float* sh1_w  = (const float*)d_in[14];
    const float* lc1_w  = (const float*)d_in[15];
    const float* lc1_b  = (const float*)d_in[16];
    const float* fc2_w  = (const float*)d_in[17];
    const float* sh2_w  = (const float*)d_in[18];
    const float* lc2_w  = (const float*)d_in[19];
    const float* lc2_b  = (const float*)d_in[20];
    const float* proj_w = (const float*)d_in[21];
    const float* proj_b = (const float*)d_in[22];
    float* out = (float*)d_out;
    float* ws  = (float*)d_ws;

    // workspace layout (floats)
    size_t off = 0;
    float* q    = ws + off; off += (size_t)B_ * N_ * DIM_;     // 12,845,056
    float* buf1 = ws + off; off += (size_t)B_ * N_ * DIM_;     // dwt, later cat
    float* kvl  = ws + off; off += (size_t)B_ * N_ * DL_;
    float* kg   = ws + off; off += (size_t)B_ * NR_ * 64;
    float* vg   = ws + off; off += (size_t)B_ * NR_ * 64;
    float* vg2  = ws + off; off += (size_t)B_ * NR_ * 64;
    float* kvm1 = ws + off; off += (size_t)B_ * NH_ * 49 * HD_;
    float* kvm2 = ws + off; off += (size_t)B_ * NH_ * 49 * HD_;
    float* kv1  = ws + off; off += (size_t)B_ * NH_ * 49 * 56;
    float* kv2  = ws + off; off += (size_t)B_ * NH_ * 49 * 56;
    float* v1c  = ws + off; off += (size_t)B_ * NH_ * 49 * HD_;
    float* v2c  = ws + off; off += (size_t)B_ * NH_ * 49 * HD_;
    float* dwt = buf1;
    float* cat = buf1;

    const int M = B_ * N_;   // 25088

    // 1. q = x @ Wq
    gemm_kernel<false, false><<<dim3(M / 64, DIM_ / 64), 256, 0, stream>>>(
        x, DIM_, Wq, nullptr, q, DIM_, M, DIM_, DIM_);

    // 2. depthwise on x_l -> dwt (B,N,448)
    dwt_kernel<<<(B_ * N_ * DL_) / 256, 256, 0, stream>>>(x, kvl_dw, kvl_db, dwt);

    // 3. pointwise: kvl = dwt @ pw^T + pb  (pw is [co][ci] -> BT layout)
    gemm_kernel<true, true><<<dim3(M / 64, DL_ / 64), 256, 0, stream>>>(
        dwt, DL_, kvl_pw, kvl_pb, kvl, DL_, M, DL_, DL_);

    // 4. global branch: sr conv + LN + kv
    srlnkv_kernel<<<B_ * NR_, 64, 0, stream>>>(x, sr_w, sr_b, ln_g, ln_b, Wkv_g, kg, vg);

    // 5. vg2 = vg + depthwise(vg)
    lcg_kernel<<<(B_ * NR_ * 64) / 256, 256, 0, stream>>>(vg, lcg_w, lcg_b, vg2);

    // 6. global flash attention -> cat cols [0,64)   (buf1 now free: dwt consumed)
    attn_global_kernel<<<dim3(N_ / 32, B_), 256, 0, stream>>>(q, kg, vg2, cat);

    // 7. scrambled means
    {
        int tot = B_ * NH_ * 49 * HD_;
        int blocks = (tot + 255) / 256;
        local_mean_kernel<<<blocks, 256, 0, stream>>>(kvl, kvm1, 256, 16, 7, 1, 0);
        local_mean_kernel<<<blocks, 256, 0, stream>>>(kvl, kvm2, 81, 9, 13, 2, 224);
    }

    // 8. fc @ sh
    fcsh_kernel<<<B_ * NH_, 64, 0, stream>>>(kvm1, fc1_w, sh1_w, kv1);
    fcsh_kernel<<<B_ * NH_, 64, 0, stream>>>(kvm2, fc2_w, sh2_w, kv2);

    // 9. v local conv
    {
        int tot = B_ * NH_ * 49 * HD_;
        int blocks = (tot + 255) / 256;
        vconv_kernel<<<blocks, 256, 0, stream>>>(kv1, lc1_w, lc1_b, v1c);
        vconv_kernel<<<blocks, 256, 0, stream>>>(kv2, lc2_w, lc2_b, v2c);
    }

    // 10. local attention -> cat cols [64,288) and [288,512)
    attn_local_kernel<<<dim3(N_ / 256, B_ * NH_), 256, 0, stream>>>(
        q, kv1, v1c, cat, D0_, D0_);
    attn_local_kernel<<<dim3(N_ / 256, B_ * NH_), 256, 0, stream>>>(
        q, kv2, v2c, cat, D0_ + HD_, D0_ + 224);

    // 11. out = cat @ proj_w + proj_b
    gemm_kernel<false, true><<<dim3(M / 64, DIM_ / 64), 256, 0, stream>>>(
        cat, DIM_, proj_w, proj_b, out, DIM_, M, DIM_, DIM_);
}

// Round 2
// 1237.497 us; speedup vs baseline: 2.3537x; 2.3537x over previous
//
#include <hip/hip_runtime.h>
#include <hip/hip_bf16.h>
#include <math.h>

// ---- problem constants ----
static constexpr int B_    = 2;
static constexpr int N_    = 12544;   // 112*112
static constexpr int DIM_  = 512;
static constexpr int D0_   = 64;
static constexpr int DL_   = 448;
static constexpr int Himg  = 112;
static constexpr int Wimg  = 112;
static constexpr int HS_   = 56;
static constexpr int NR_   = 3136;    // 56*56
static constexpr int NH_   = 8;
static constexpr int HD_   = 28;

typedef __attribute__((ext_vector_type(8))) short short8_t;
typedef __attribute__((ext_vector_type(4))) float float4v;
typedef __attribute__((ext_vector_type(4))) unsigned uint4v;

// round-to-nearest-even f32 -> bf16, pack two into u32 (lo, hi)
static __device__ inline unsigned pack_bf16(float lo, float hi) {
    unsigned a = __builtin_bit_cast(unsigned, lo);
    unsigned b = __builtin_bit_cast(unsigned, hi);
    a = (a + 0x7FFFu + ((a >> 16) & 1u)) >> 16;
    b = (b + 0x7FFFu + ((b >> 16) & 1u)) >> 16;
    return a | (b << 16);
}

// =====================================================================
// Generic tiled fp32 GEMM: C[M,N] = A[M,K] @ W (+bias)
// BT=false: W row-major [K][N]; BT=true: W is [N][K] (transposed access)
// =====================================================================
template<bool BT, bool HASBIAS>
__global__ __launch_bounds__(256)
void gemm_kernel(const float* __restrict__ A, int lda,
                 const float* __restrict__ W,
                 const float* __restrict__ bias,
                 float* __restrict__ C, int ldc,
                 int M, int Nn, int K) {
    constexpr int BM = 64, BN = 64, BK = 16;
    __shared__ float As[BK][BM];
    __shared__ float Bs[BK][BN];
    const int bm = blockIdx.x * BM;
    const int bn = blockIdx.y * BN;
    const int t  = threadIdx.x;
    const int tx = t % 16, ty = t / 16;
    float acc[4][4] = {};
    for (int k0 = 0; k0 < K; k0 += BK) {
        #pragma unroll
        for (int i = 0; i < 4; ++i) {
            int k = t % BK;
            int m = t / BK + i * 16;
            As[k][m] = A[(size_t)(bm + m) * lda + k0 + k];
        }
        if (!BT) {
            #pragma unroll
            for (int i = 0; i < 4; ++i) {
                int n = t % BN;
                int k = t / BN + i * 4;
                Bs[k][n] = W[(size_t)(k0 + k) * Nn + bn + n];
            }
        } else {
            #pragma unroll
            for (int i = 0; i < 4; ++i) {
                int k = t % BK;
                int n = t / BK + i * 16;
                Bs[k][n] = W[(size_t)(bn + n) * K + k0 + k];
            }
        }
        __syncthreads();
        #pragma unroll
        for (int kk = 0; kk < BK; ++kk) {
            float a[4], b[4];
            #pragma unroll
            for (int i = 0; i < 4; ++i) a[i] = As[kk][ty * 4 + i];
            #pragma unroll
            for (int j = 0; j < 4; ++j) b[j] = Bs[kk][tx * 4 + j];
            #pragma unroll
            for (int i = 0; i < 4; ++i)
                #pragma unroll
                for (int j = 0; j < 4; ++j)
                    acc[i][j] += a[i] * b[j];
        }
        __syncthreads();
    }
    #pragma unroll
    for (int i = 0; i < 4; ++i) {
        int m = bm + ty * 4 + i;
        #pragma unroll
        for (int j = 0; j < 4; ++j) {
            int n = bn + tx * 4 + j;
            float v = acc[i][j];
            if (HASBIAS) v += bias[n];
            C[(size_t)m * ldc + n] = v;
        }
    }
}

// =====================================================================
// sr-conv (2x2 stride2, 64->64) + LayerNorm(64) + kv GEMM (64->128)
// =====================================================================
__global__ __launch_bounds__(64)
void srlnkv_kernel(const float* __restrict__ x,
                   const float* __restrict__ sr_w, const float* __restrict__ sr_b,
                   const float* __restrict__ ln_g, const float* __restrict__ ln_b,
                   const float* __restrict__ wkv,
                   float* __restrict__ kg, float* __restrict__ vg) {
    const int pos = blockIdx.x;              // b*NR + n
    const int b = pos / NR_, n = pos % NR_;
    const int y = n / HS_, xx = n % HS_;
    const int o = threadIdx.x;               // 0..63
    __shared__ float xs[4][64];
    __shared__ float lnv_s[64];
    #pragma unroll
    for (int tap = 0; tap < 4; ++tap) {
        int ky = tap / 2, kx = tap % 2;
        xs[tap][o] = x[((size_t)b * N_ + (2 * y + ky) * Wimg + 2 * xx + kx) * DIM_ + o];
    }
    __syncthreads();
    float sum = sr_b[o];
    for (int i = 0; i < 64; ++i) {
        const float* w = sr_w + o * 256 + i * 4;
        sum += xs[0][i] * w[0] + xs[1][i] * w[1] + xs[2][i] * w[2] + xs[3][i] * w[3];
    }
    float m = sum;
    #pragma unroll
    for (int off = 1; off < 64; off <<= 1) m += __shfl_xor(m, off);
    m *= (1.0f / 64.0f);
    float d = sum - m;
    float v = d * d;
    #pragma unroll
    for (int off = 1; off < 64; off <<= 1) v += __shfl_xor(v, off);
    v *= (1.0f / 64.0f);
    float lnv = d * rsqrtf(v + 1e-5f) * ln_g[o] + ln_b[o];
    lnv_s[o] = lnv;
    __syncthreads();
    float s0 = 0.f, s1 = 0.f;
    for (int i = 0; i < 64; ++i) {
        float lv = lnv_s[i];
        s0 += lv * wkv[i * 128 + o];
        s1 += lv * wkv[i * 128 + o + 64];
    }
    kg[((size_t)b * NR_ + n) * 64 + o] = s0;
    vg[((size_t)b * NR_ + n) * 64 + o] = s1;
}

// =====================================================================
// depthwise 3x3 + bias on v_g image; vg2 = vg + conv
// =====================================================================
__global__ __launch_bounds__(256)
void lcg_kernel(const float* __restrict__ vg, const float* __restrict__ w,
                const float* __restrict__ bias, float* __restrict__ vg2) {
    int idx = blockIdx.x * 256 + threadIdx.x;
    if (idx >= B_ * NR_ * 64) return;
    int c = idx % 64;
    int n = (idx / 64) % NR_;
    int b = idx / (64 * NR_);
    int y = n / HS_, xx = n % HS_;
    float sum = vg[idx] + bias[c];
    #pragma unroll
    for (int ky = 0; ky < 3; ++ky)
        #pragma unroll
        for (int kx = 0; kx < 3; ++kx) {
            int yy = y + ky - 1, x2 = xx + kx - 1;
            if (yy >= 0 && yy < HS_ && x2 >= 0 && x2 < HS_)
                sum += vg[((size_t)b * NR_ + yy * HS_ + x2) * 64 + c] * w[c * 9 + ky * 3 + kx];
        }
    vg2[idx] = sum;
}

// =====================================================================
// Global-branch flash attention with bf16 MFMA (16x16x32).
// Block: 128 threads (2 waves), 32 q-rows/block (16 per wave), KV tile 64.
// Scores computed transposed: S^T = mfma(A=K_tile, B=Q^T) so each lane
// holds all scores of ONE q-row (l&15). P re-laid-out via per-wave LDS.
// V staged transposed (Vt[d][kk], stride 72 shorts) for B-frag b128 reads.
// =====================================================================
__global__ __launch_bounds__(128)
void attn_global_mfma(const float* __restrict__ q,
                      const float* __restrict__ kg,
                      const float* __restrict__ vg,
                      float* __restrict__ cat) {
    __shared__ __align__(16) unsigned Ku[64 * 36];        // K[kcol][d] bf16, 72-short rows
    __shared__ __align__(16) unsigned Vtu[64 * 36];       // Vt[d][kk]  bf16, 72-short rows
    __shared__ __align__(16) unsigned Pu[2 * 16 * 36];    // per-wave P[qrow][kcol] bf16
    const int b   = blockIdx.y;
    const int q0  = blockIdx.x * 32;
    const int tid = threadIdx.x;
    const int w   = tid >> 6;       // wave 0/1
    const int l   = tid & 63;
    const int l15 = l & 15;
    const int g   = l >> 4;         // 0..3

    // ---- load Q fragments (B-operand of the score MFMA) ----
    // B[k=d][j=qrow]: lane holds qrow = l&15, d = g*8 + jj + 32*dc
    short8_t qf[2];
    {
        const float* qrow = q + ((size_t)b * N_ + q0 + w * 16 + l15) * DIM_;
        #pragma unroll
        for (int dc = 0; dc < 2; ++dc) {
            const float4v* p4 = (const float4v*)(qrow + g * 8 + 32 * dc);
            float4v x0 = p4[0], x1 = p4[1];
            uint4v uv;
            uv[0] = pack_bf16(x0[0], x0[1]);
            uv[1] = pack_bf16(x0[2], x0[3]);
            uv[2] = pack_bf16(x1[0], x1[1]);
            uv[3] = pack_bf16(x1[2], x1[3]);
            qf[dc] = __builtin_bit_cast(short8_t, uv);
        }
    }

    float4v o[4];
    #pragma unroll
    for (int i = 0; i < 4; ++i) o[i] = (float4v){0.f, 0.f, 0.f, 0.f};
    float m_run = -3.0e38f, l_run = 0.f;

    const int kcolK = tid >> 1, dhK = tid & 1;   // K staging: 32 d per thread
    const int kkp   = tid >> 2, dq  = tid & 3;   // V staging: rows 2kkp,2kkp+1; 16 d

    for (int t = 0; t < 49; ++t) {
        const int k0 = t * 64;
        // ---- stage K tile (64 kcols x 64 d) as bf16 ----
        {
            const float* src = kg + ((size_t)b * NR_ + k0 + kcolK) * 64 + dhK * 32;
            unsigned* dst = Ku + kcolK * 36 + dhK * 16;
            #pragma unroll
            for (int c4 = 0; c4 < 8; ++c4) {
                float4v v = ((const float4v*)src)[c4];
                dst[c4 * 2]     = pack_bf16(v[0], v[1]);
                dst[c4 * 2 + 1] = pack_bf16(v[2], v[3]);
            }
        }
        // ---- stage V transposed: Vt[d][kk] ----
        {
            const float* s0 = vg + ((size_t)b * NR_ + k0 + 2 * kkp) * 64 + dq * 16;
            const float* s1 = s0 + 64;
            #pragma unroll
            for (int c4 = 0; c4 < 4; ++c4) {
                float4v a  = ((const float4v*)s0)[c4];
                float4v bb = ((const float4v*)s1)[c4];
                #pragma unroll
                for (int e = 0; e < 4; ++e)
                    Vtu[(dq * 16 + c4 * 4 + e) * 36 + kkp] = pack_bf16(a[e], bb[e]);
            }
        }
        __syncthreads();

        // ---- scores: S^T chunks, 4 x (16 kcols x 16 qrows) ----
        float4v sc[4];
        const char* Kb = (const char*)Ku;
        #pragma unroll
        for (int c = 0; c < 4; ++c) {
            float4v acc = (float4v){0.f, 0.f, 0.f, 0.f};
            #pragma unroll
            for (int dc = 0; dc < 2; ++dc) {
                short8_t ak = *(const short8_t*)(Kb + (c * 16 + l15) * 144 + (g + 4 * dc) * 16);
                acc = __builtin_amdgcn_mfma_f32_16x16x32_bf16(ak, qf[dc], acc, 0, 0, 0);
            }
            sc[c] = acc;
        }
        // lane now holds scores for qrow=l15 at kcols 16c + 4g + r

        // ---- online softmax ----
        float tmax = -3.0e38f;
        #pragma unroll
        for (int c = 0; c < 4; ++c)
            #pragma unroll
            for (int r = 0; r < 4; ++r) {
                sc[c][r] *= 0.125f;
                tmax = fmaxf(tmax, sc[c][r]);
            }
        tmax = fmaxf(tmax, __shfl_xor(tmax, 16));
        tmax = fmaxf(tmax, __shfl_xor(tmax, 32));
        float m_new = fmaxf(m_run, tmax);
        float corr = __expf(m_run - m_new);
        float p[4][4];
        float ladd = 0.f;
        #pragma unroll
        for (int c = 0; c < 4; ++c)
            #pragma unroll
            for (int r = 0; r < 4; ++r) {
                float pe = __expf(sc[c][r] - m_new);
                p[c][r] = pe;
                ladd += pe;
            }
        ladd += __shfl_xor(ladd, 16);
        ladd += __shfl_xor(ladd, 32);
        l_run = l_run * corr + ladd;
        m_run = m_new;

        // ---- write P (bf16) to per-wave LDS for A-frag re-layout ----
        {
            unsigned* Pw = Pu + w * (16 * 36) + l15 * 36;
            #pragma unroll
            for (int c = 0; c < 4; ++c) {
                Pw[8 * c + 2 * g]     = pack_bf16(p[c][0], p[c][1]);
                Pw[8 * c + 2 * g + 1] = pack_bf16(p[c][2], p[c][3]);
            }
        }

        // ---- rescale O (O rows are qrow = g*4+r) ----
        float co[4];
        #pragma unroll
        for (int r = 0; r < 4; ++r) co[r] = __shfl(corr, g * 4 + r);
        #pragma unroll
        for (int dc = 0; dc < 4; ++dc)
            #pragma unroll
            for (int r = 0; r < 4; ++r) o[dc][r] *= co[r];

        // ---- PV: O += P @ V ----
        {
            const char* Pb = (const char*)(Pu + w * (16 * 36));
            const char* Vb = (const char*)Vtu;
            #pragma unroll
            for (int kkc = 0; kkc < 2; ++kkc) {
                short8_t ap = *(const short8_t*)(Pb + l15 * 144 + (g + 4 * kkc) * 16);
                #pragma unroll
                for (int dc = 0; dc < 4; ++dc) {
                    short8_t bv = *(const short8_t*)(Vb + (dc * 16 + l15) * 144 + (g + 4 * kkc) * 16);
                    o[dc] = __builtin_amdgcn_mfma_f32_16x16x32_bf16(ap, bv, o[dc], 0, 0, 0);
                }
            }
        }
        __syncthreads();
    }

    // ---- epilogue: normalize and store ----
    float inv[4];
    #pragma unroll
    for (int r = 0; r < 4; ++r) inv[r] = 1.0f / __shfl(l_run, g * 4 + r);
    #pragma unroll
    for (int dc = 0; dc < 4; ++dc)
        #pragma unroll
        for (int r = 0; r < 4; ++r) {
            int row = q0 + w * 16 + g * 4 + r;
            cat[((size_t)b * N_ + row) * DIM_ + dc * 16 + l15] = o[dc][r] * inv[r];
        }
}

// =====================================================================
// depthwise 3x3 + bias on x_l (channels 64..511 of x), out (B,N,448)
// =====================================================================
__global__ __launch_bounds__(256)
void dwt_kernel(const float* __restrict__ x, const float* __restrict__ w,
                const float* __restrict__ bias, float* __restrict__ out) {
    int idx = blockIdx.x * 256 + threadIdx.x;
    if (idx >= B_ * N_ * DL_) return;
    int c = idx % DL_;
    int n = (idx / DL_) % N_;
    int b = idx / (DL_ * N_);
    int y = n / Wimg, xx = n % Wimg;
    float sum = bias[c];
    #pragma unroll
    for (int ky = 0; ky < 3; ++ky)
        #pragma unroll
        for (int kx = 0; kx < 3; ++kx) {
            int yy = y + ky - 1, x2 = xx + kx - 1;
            if (yy >= 0 && yy < Himg && x2 >= 0 && x2 < Wimg)
                sum += x[((size_t)b * N_ + yy * Wimg + x2) * DIM_ + D0_ + c] * w[c * 9 + ky * 3 + kx];
        }
    out[idx] = sum;
}

// =====================================================================
// "scrambled mean"
// =====================================================================
__global__ __launch_bounds__(256)
void local_mean_kernel(const float* __restrict__ kvl, float* __restrict__ kvm,
                       int L, int nBW, int stride, int dil, int choff) {
    int idx = blockIdx.x * 256 + threadIdx.x;
    if (idx >= B_ * NH_ * 49 * HD_) return;
    int d2 = idx % HD_;
    int n  = (idx / HD_) % 49;
    int h  = (idx / (HD_ * 49)) % NH_;
    int b  = idx / (HD_ * 49 * NH_);
    int wy = n / 7, wx = n % 7;
    float sum = 0.f;
    int f0 = d2 * L;
    for (int l2 = 0; l2 < L; ++l2) {
        int f = f0 + l2;
        int l = f / HD_;
        int d = f - l * HD_;
        int by = l / nBW, bx = l % nBW;
        int Y = by * stride + dil * wy;
        int X = bx * stride + dil * wx;
        if (Y >= Himg) Y = 2 * Himg - 2 - Y;   // reflect
        if (X >= Wimg) X = 2 * Wimg - 2 - X;
        sum += kvl[((size_t)b * N_ + Y * Wimg + X) * DL_ + choff + h * HD_ + d];
    }
    kvm[idx] = sum * (1.0f / (float)L);
}

// =====================================================================
// kv = kvm @ fc_w @ sh_w -> (B*NH, 49, 56)
// =====================================================================
__global__ __launch_bounds__(64)
void fcsh_kernel(const float* __restrict__ kvm, const float* __restrict__ fcw,
                 const float* __restrict__ shw, float* __restrict__ out) {
    int bh = blockIdx.x;
    __shared__ float kin[49][28];
    __shared__ float tmp[49][28];
    __shared__ float fw[28 * 28];
    __shared__ float sw[28 * 56];
    int t = threadIdx.x;
    for (int i = t; i < 49 * 28; i += 64) kin[i / 28][i % 28] = kvm[bh * 49 * 28 + i];
    for (int i = t; i < 28 * 28; i += 64) fw[i] = fcw[i];
    for (int i = t; i < 28 * 56; i += 64) sw[i] = shw[i];
    __syncthreads();
    for (int i = t; i < 49 * 28; i += 64) {
        int rr = i / 28, j = i % 28;
        float s = 0.f;
        for (int k = 0; k < 28; ++k) s += kin[rr][k] * fw[k * 28 + j];
        tmp[rr][j] = s;
    }
    __syncthreads();
    for (int i = t; i < 49 * 56; i += 64) {
        int rr = i / 56, j = i % 56;
        float s = 0.f;
        for (int k = 0; k < 28; ++k) s += tmp[rr][k] * sw[k * 56 + j];
        out[bh * 49 * 56 + i] = s;
    }
}

// =====================================================================
// v_ + depthwise3x3(v_img 7x7) + bias -> vc (B*NH, 49, 28)
// =====================================================================
__global__ __launch_bounds__(256)
void vconv_kernel(const float* __restrict__ kvsh, const float* __restrict__ w,
                  const float* __restrict__ bias, float* __restrict__ vc) {
    int idx = blockIdx.x * 256 + threadIdx.x;
    if (idx >= B_ * NH_ * 49 * HD_) return;
    int d  = idx % HD_;
    int n  = (idx / HD_) % 49;
    int bh = idx / (HD_ * 49);
    int h  = bh % NH_;
    int y = n / 7, xx = n % 7;
    int c = h * HD_ + d;
    float sum = kvsh[(bh * 49 + n) * 56 + 28 + d] + bias[c];
    #pragma unroll
    for (int ky = 0; ky < 3; ++ky)
        #pragma unroll
        for (int kx = 0; kx < 3; ++kx) {
            int yy = y + ky - 1, x2 = xx + kx - 1;
            if (yy >= 0 && yy < 7 && x2 >= 0 && x2 < 7)
                sum += kvsh[(bh * 49 + yy * 7 + x2) * 56 + 28 + d] * w[c * 9 + ky * 3 + kx];
        }
    vc[idx] = sum;
}

// =====================================================================
// local attention: 49 keys, hd=28. one thread per q-row.
// =====================================================================
__global__ __launch_bounds__(256)
void attn_local_kernel(const float* __restrict__ q, const float* __restrict__ kvsh,
                       const float* __restrict__ vc, float* __restrict__ cat,
                       int qcoloff, int outcoloff) {
    const int bh = blockIdx.y;
    const int b = bh / NH_, h = bh % NH_;
    const int n = blockIdx.x * 256 + threadIdx.x;
    __shared__ float Ks[49][28];
    __shared__ float Vsh[49][28];
    const int t = threadIdx.x;
    for (int i = t; i < 49 * 28; i += 256) {
        int rr = i / 28, d = i % 28;
        Ks[rr][d]  = kvsh[(bh * 49 + rr) * 56 + d];
        Vsh[rr][d] = vc[(bh * 49 + rr) * 28 + d];
    }
    __syncthreads();
    float qr[28];
    const float* qp = q + ((size_t)b * N_ + n) * DIM_ + qcoloff + h * 56;
    #pragma unroll
    for (int d = 0; d < 28; ++d) qr[d] = qp[d];
    const float scale = 0.1889822365046136f;   // 28^-0.5
    float mx = -1e30f;
    for (int k = 0; k < 49; ++k) {
        float s = 0.f;
        #pragma unroll
        for (int d = 0; d < 28; ++d) s += qr[d] * Ks[k][d];
        mx = fmaxf(mx, s * scale);
    }
    float l = 0.f;
    float acc[28] = {};
    for (int k = 0; k < 49; ++k) {
        float s = 0.f;
        #pragma unroll
        for (int d = 0; d < 28; ++d) s += qr[d] * Ks[k][d];
        float p = __expf(s * scale - mx);
        l += p;
        #pragma unroll
        for (int d = 0; d < 28; ++d) acc[d] += p * Vsh[k][d];
    }
    float inv = 1.f / l;
    float* op = cat + ((size_t)b * N_ + n) * DIM_ + outcoloff + h * HD_;
    #pragma unroll
    for (int d = 0; d < 28; ++d) op[d] = acc[d] * inv;
}

// =====================================================================
extern "C" void kernel_launch(void* const* d_in, const int* in_sizes, int n_in,
                              void* d_out, int out_size, void* d_ws, size_t ws_size,
                              hipStream_t stream) {
    const float* x      = (const float*)d_in[0];
    const float* Wq     = (const float*)d_in[1];
    const float* Wkv_g  = (const float*)d_in[2];
    const float* sr_w   = (const float*)d_in[3];
    const float* sr_b   = (const float*)d_in[4];
    const float* ln_g   = (const float*)d_in[5];
    const float* ln_b   = (const float*)d_in[6];
    const float* lcg_w  = (const float*)d_in[7];
    const float* lcg_b  = (const float*)d_in[8];
    const float* kvl_dw = (const float*)d_in[9];
    const float* kvl_db = (const float*)d_in[10];
    const float* kvl_pw = (const float*)d_in[11];
    const float* kvl_pb = (const float*)d_in[12];
    const float* fc1_w  = (const float*)d_in[13];
    const float* sh1_w  = (const float*)d_in[14];
    const float* lc1_w  = (const float*)d_in[15];
    const float* lc1_b  = (const float*)d_in[16];
    const float* fc2_w  = (const float*)d_in[17];
    const float* sh2_w  = (const float*)d_in[18];
    const float* lc2_w  = (const float*)d_in[19];
    const float* lc2_b  = (const float*)d_in[20];
    const float* proj_w = (const float*)d_in[21];
    const float* proj_b = (const float*)d_in[22];
    float* out = (float*)d_out;
    float* ws  = (float*)d_ws;

    // workspace layout (floats)
    size_t off = 0;
    float* q    = ws + off; off += (size_t)B_ * N_ * DIM_;
    float* buf1 = ws + off; off += (size_t)B_ * N_ * DIM_;     // dwt, later cat
    float* kvl  = ws + off; off += (size_t)B_ * N_ * DL_;
    float* kg   = ws + off; off += (size_t)B_ * NR_ * 64;
    float* vg   = ws + off; off += (size_t)B_ * NR_ * 64;
    float* vg2  = ws + off; off += (size_t)B_ * NR_ * 64;
    float* kvm1 = ws + off; off += (size_t)B_ * NH_ * 49 * HD_;
    float* kvm2 = ws + off; off += (size_t)B_ * NH_ * 49 * HD_;
    float* kv1  = ws + off; off += (size_t)B_ * NH_ * 49 * 56;
    float* kv2  = ws + off; off += (size_t)B_ * NH_ * 49 * 56;
    float* v1c  = ws + off; off += (size_t)B_ * NH_ * 49 * HD_;
    float* v2c  = ws + off; off += (size_t)B_ * NH_ * 49 * HD_;
    float* dwt = buf1;
    float* cat = buf1;

    const int M = B_ * N_;   // 25088

    // 1. q = x @ Wq
    gemm_kernel<false, false><<<dim3(M / 64, DIM_ / 64), 256, 0, stream>>>(
        x, DIM_, Wq, nullptr, q, DIM_, M, DIM_, DIM_);

    // 2. depthwise on x_l -> dwt (B,N,448)
    dwt_kernel<<<(B_ * N_ * DL_) / 256, 256, 0, stream>>>(x, kvl_dw, kvl_db, dwt);

    // 3. pointwise: kvl = dwt @ pw^T + pb
    gemm_kernel<true, true><<<dim3(M / 64, DL_ / 64), 256, 0, stream>>>(
        dwt, DL_, kvl_pw, kvl_pb, kvl, DL_, M, DL_, DL_);

    // 4. global branch: sr conv + LN + kv
    srlnkv_kernel<<<B_ * NR_, 64, 0, stream>>>(x, sr_w, sr_b, ln_g, ln_b, Wkv_g, kg, vg);

    // 5. vg2 = vg + depthwise(vg)
    lcg_kernel<<<(B_ * NR_ * 64) / 256, 256, 0, stream>>>(vg, lcg_w, lcg_b, vg2);

    // 6. global flash attention (bf16 MFMA) -> cat cols [0,64)
    attn_global_mfma<<<dim3(N_ / 32, B_), 128, 0, stream>>>(q, kg, vg2, cat);

    // 7. scrambled means
    {
        int tot = B_ * NH_ * 49 * HD_;
        int blocks = (tot + 255) / 256;
        local_mean_kernel<<<blocks, 256, 0, stream>>>(kvl, kvm1, 256, 16, 7, 1, 0);
        local_mean_kernel<<<blocks, 256, 0, stream>>>(kvl, kvm2, 81, 9, 13, 2, 224);
    }

    // 8. fc @ sh
    fcsh_kernel<<<B_ * NH_, 64, 0, stream>>>(kvm1, fc1_w, sh1_w, kv1);
    fcsh_kernel<<<B_ * NH_, 64, 0, stream>>>(kvm2, fc2_w, sh2_w, kv2);

    // 9. v local conv
    {
        int tot = B_ * NH_ * 49 * HD_;
        int blocks = (tot + 255) / 256;
        vconv_kernel<<<blocks, 256, 0, stream>>>(kv1, lc1_w, lc1_b, v1c);
        vconv_kernel<<<blocks, 256, 0, stream>>>(kv2, lc2_w, lc2_b, v2c);
    }

    // 10. local attention -> cat cols [64,288) and [288,512)
    attn_local_kernel<<<dim3(N_ / 256, B_ * NH_), 256, 0, stream>>>(
        q, kv1, v1c, cat, D0_, D0_);
    attn_local_kernel<<<dim3(N_ / 256, B_ * NH_), 256, 0, stream>>>(
        q, kv2, v2c, cat, D0_ + HD_, D0_ + 224);

    // 11. out = cat @ proj_w + proj_b
    gemm_kernel<false, true><<<dim3(M / 64, DIM_ / 64), 256, 0, stream>>>(
        cat, DIM_, proj_w, proj_b, out, DIM_, M, DIM_, DIM_);
}

// Round 3
// 685.218 us; speedup vs baseline: 4.2508x; 1.8060x over previous
//
#include <hip/hip_runtime.h>
#include <hip/hip_bf16.h>
#include <math.h>
#include <stdint.h>

// ---- problem constants ----
static constexpr int B_    = 2;
static constexpr int N_    = 12544;   // 112*112
static constexpr int DIM_  = 512;
static constexpr int D0_   = 64;
static constexpr int DL_   = 448;
static constexpr int Himg  = 112;
static constexpr int Wimg  = 112;
static constexpr int HS_   = 56;
static constexpr int NR_   = 3136;    // 56*56
static constexpr int NH_   = 8;
static constexpr int HD_   = 28;

typedef unsigned short ushort_t;
typedef __attribute__((ext_vector_type(8))) short short8_t;
typedef __attribute__((ext_vector_type(4))) float float4v;
typedef __attribute__((ext_vector_type(4))) unsigned uint4v;

// round-to-nearest-even f32 -> bf16
static __device__ inline ushort_t bf16r(float x) {
    unsigned u = __builtin_bit_cast(unsigned, x);
    u = (u + 0x7FFFu + ((u >> 16) & 1u)) >> 16;
    return (ushort_t)u;
}
// pack two f32 -> u32 of 2 bf16 (lo, hi)
static __device__ inline unsigned pack_bf16(float lo, float hi) {
    unsigned a = __builtin_bit_cast(unsigned, lo);
    unsigned b = __builtin_bit_cast(unsigned, hi);
    a = (a + 0x7FFFu + ((a >> 16) & 1u)) >> 16;
    b = (b + 0x7FFFu + ((b >> 16) & 1u)) >> 16;
    return a | (b << 16);
}

using gptr_t = const __attribute__((address_space(1))) void*;
using lptr_t = __attribute__((address_space(3))) void*;
static __device__ inline void gload16(const void* g, void* l) {
    __builtin_amdgcn_global_load_lds((gptr_t)(uintptr_t)g, (lptr_t)(uintptr_t)l, 16, 0, 0);
}

// =====================================================================
// bf16 MFMA GEMM: C[M][ldc] (fp32) = A[M][K](bf16) @ Bt[Npad][K](bf16)^T
// 128x128 tile, BK=64, 256 threads (4 waves in 2x2), single-buffer loop.
// LDS linear (global_load_lds), XOR chunk swizzle on SOURCE + frag READ.
// Requires: M % 128 == 0, K % 64 == 0, Npad >= gridDim.y*128 (zero-padded).
// =====================================================================
template<bool HASBIAS>
__global__ __launch_bounds__(256, 2)
void gemm_bf16_kernel(const ushort_t* __restrict__ A,
                      const ushort_t* __restrict__ Bt,
                      const float* __restrict__ bias,
                      float* __restrict__ C,
                      int Nn, int K, int ldc) {
    constexpr int BM = 128, BK = 64;
    __shared__ __align__(16) ushort_t As[BM * BK];
    __shared__ __align__(16) ushort_t Bs[BM * BK];
    const int bm = blockIdx.x * BM;
    const int bn = blockIdx.y * BM;
    const int tid = threadIdx.x;
    const int l15 = tid & 15;
    const int g   = (tid & 63) >> 4;
    const int w   = tid >> 6;
    const int wr  = w >> 1, wc = w & 1;

    float4v acc[4][4];
    #pragma unroll
    for (int m = 0; m < 4; ++m)
        #pragma unroll
        for (int n = 0; n < 4; ++n) acc[m][n] = (float4v){0.f, 0.f, 0.f, 0.f};

    for (int k0 = 0; k0 < K; k0 += BK) {
        // stage both tiles: 1024 16B-chunks each, 4 per thread
        #pragma unroll
        for (int i = 0; i < 4; ++i) {
            int c = i * 256 + tid;
            int r = c >> 3, ch = c & 7;
            int sch = ch ^ (r & 7);                  // pre-swizzled source chunk
            gload16(A  + (size_t)(bm + r) * K + k0 + sch * 8, (void*)(As + c * 8));
            gload16(Bt + (size_t)(bn + r) * K + k0 + sch * 8, (void*)(Bs + c * 8));
        }
        __syncthreads();   // compiler drains vmcnt(0) before barrier

        short8_t af[4][2], bfr[4][2];
        #pragma unroll
        for (int m = 0; m < 4; ++m) {
            int ar = wr * 64 + m * 16 + l15;
            #pragma unroll
            for (int h = 0; h < 2; ++h)
                af[m][h] = *(const short8_t*)((const char*)As + ar * 128 + (((h * 4 + g) ^ (ar & 7)) * 16));
        }
        #pragma unroll
        for (int n = 0; n < 4; ++n) {
            int br = wc * 64 + n * 16 + l15;
            #pragma unroll
            for (int h = 0; h < 2; ++h)
                bfr[n][h] = *(const short8_t*)((const char*)Bs + br * 128 + (((h * 4 + g) ^ (br & 7)) * 16));
        }
        #pragma unroll
        for (int m = 0; m < 4; ++m)
            #pragma unroll
            for (int n = 0; n < 4; ++n) {
                acc[m][n] = __builtin_amdgcn_mfma_f32_16x16x32_bf16(af[m][0], bfr[n][0], acc[m][n], 0, 0, 0);
                acc[m][n] = __builtin_amdgcn_mfma_f32_16x16x32_bf16(af[m][1], bfr[n][1], acc[m][n], 0, 0, 0);
            }
        __syncthreads();
    }

    // epilogue: C/D layout col=l15, row=g*4+j
    #pragma unroll
    for (int n = 0; n < 4; ++n) {
        int ccol = bn + wc * 64 + n * 16 + l15;
        if (ccol < Nn) {
            float bv = HASBIAS ? bias[ccol] : 0.f;
            #pragma unroll
            for (int m = 0; m < 4; ++m) {
                int crow = bm + wr * 64 + m * 16 + g * 4;
                #pragma unroll
                for (int j = 0; j < 4; ++j)
                    C[(size_t)(crow + j) * ldc + ccol] = acc[m][n][j] + bv;
            }
        }
    }
}

// =====================================================================
// weight convert: Wt[Npad][K] bf16 from W (transpose? W[K][Nn] : W[Nn][K])
// rows >= Nn zero-filled
// =====================================================================
__global__ __launch_bounds__(256)
void convw_kernel(const float* __restrict__ W, ushort_t* __restrict__ Wt,
                  int K, int Nn, int transpose) {
    int idx = blockIdx.x * 256 + threadIdx.x;
    int n = idx / K, k = idx % K;
    float v = 0.f;
    if (n < Nn) v = transpose ? W[(size_t)k * Nn + n] : W[(size_t)n * K + k];
    Wt[idx] = bf16r(v);
}

// fp32 -> bf16 bulk convert, 8 elems/thread
__global__ __launch_bounds__(256)
void convx_kernel(const float* __restrict__ in, ushort_t* __restrict__ outp) {
    int i = blockIdx.x * 256 + threadIdx.x;
    const float4v* p = (const float4v*)(in + (size_t)i * 8);
    float4v a = p[0], b = p[1];
    uint4v u;
    u[0] = pack_bf16(a[0], a[1]);
    u[1] = pack_bf16(a[2], a[3]);
    u[2] = pack_bf16(b[0], b[1]);
    u[3] = pack_bf16(b[2], b[3]);
    *(uint4v*)(outp + (size_t)i * 8) = u;
}

// =====================================================================
// sr-conv (2x2 stride2, 64->64) + LayerNorm(64) + kv GEMM (64->128)
// =====================================================================
__global__ __launch_bounds__(64)
void srlnkv_kernel(const float* __restrict__ x,
                   const float* __restrict__ sr_w, const float* __restrict__ sr_b,
                   const float* __restrict__ ln_g, const float* __restrict__ ln_b,
                   const float* __restrict__ wkv,
                   float* __restrict__ kg, float* __restrict__ vg) {
    const int pos = blockIdx.x;              // b*NR + n
    const int b = pos / NR_, n = pos % NR_;
    const int y = n / HS_, xx = n % HS_;
    const int o = threadIdx.x;               // 0..63
    __shared__ float xs[4][64];
    __shared__ float lnv_s[64];
    #pragma unroll
    for (int tap = 0; tap < 4; ++tap) {
        int ky = tap / 2, kx = tap % 2;
        xs[tap][o] = x[((size_t)b * N_ + (2 * y + ky) * Wimg + 2 * xx + kx) * DIM_ + o];
    }
    __syncthreads();
    float sum = sr_b[o];
    for (int i = 0; i < 64; ++i) {
        const float* w = sr_w + o * 256 + i * 4;
        sum += xs[0][i] * w[0] + xs[1][i] * w[1] + xs[2][i] * w[2] + xs[3][i] * w[3];
    }
    float m = sum;
    #pragma unroll
    for (int off = 1; off < 64; off <<= 1) m += __shfl_xor(m, off);
    m *= (1.0f / 64.0f);
    float d = sum - m;
    float v = d * d;
    #pragma unroll
    for (int off = 1; off < 64; off <<= 1) v += __shfl_xor(v, off);
    v *= (1.0f / 64.0f);
    float lnv = d * rsqrtf(v + 1e-5f) * ln_g[o] + ln_b[o];
    lnv_s[o] = lnv;
    __syncthreads();
    float s0 = 0.f, s1 = 0.f;
    for (int i = 0; i < 64; ++i) {
        float lv = lnv_s[i];
        s0 += lv * wkv[i * 128 + o];
        s1 += lv * wkv[i * 128 + o + 64];
    }
    kg[((size_t)b * NR_ + n) * 64 + o] = s0;
    vg[((size_t)b * NR_ + n) * 64 + o] = s1;
}

// =====================================================================
// depthwise 3x3 + bias on v_g image; vg2 = vg + conv
// =====================================================================
__global__ __launch_bounds__(256)
void lcg_kernel(const float* __restrict__ vg, const float* __restrict__ w,
                const float* __restrict__ bias, float* __restrict__ vg2) {
    int idx = blockIdx.x * 256 + threadIdx.x;
    if (idx >= B_ * NR_ * 64) return;
    int c = idx % 64;
    int n = (idx / 64) % NR_;
    int b = idx / (64 * NR_);
    int y = n / HS_, xx = n % HS_;
    float sum = vg[idx] + bias[c];
    #pragma unroll
    for (int ky = 0; ky < 3; ++ky)
        #pragma unroll
        for (int kx = 0; kx < 3; ++kx) {
            int yy = y + ky - 1, x2 = xx + kx - 1;
            if (yy >= 0 && yy < HS_ && x2 >= 0 && x2 < HS_)
                sum += vg[((size_t)b * NR_ + yy * HS_ + x2) * 64 + c] * w[c * 9 + ky * 3 + kx];
        }
    vg2[idx] = sum;
}

// =====================================================================
// Global-branch flash attention with bf16 MFMA (16x16x32).
// =====================================================================
__global__ __launch_bounds__(128)
void attn_global_mfma(const float* __restrict__ q,
                      const float* __restrict__ kg,
                      const float* __restrict__ vg,
                      ushort_t* __restrict__ catb) {
    __shared__ __align__(16) unsigned Ku[64 * 36];        // K[kcol][d] bf16, 72-short rows
    __shared__ __align__(16) unsigned Vtu[64 * 36];       // Vt[d][kk]  bf16, 72-short rows
    __shared__ __align__(16) unsigned Pu[2 * 16 * 36];    // per-wave P[qrow][kcol] bf16
    const int b   = blockIdx.y;
    const int q0  = blockIdx.x * 32;
    const int tid = threadIdx.x;
    const int w   = tid >> 6;       // wave 0/1
    const int l   = tid & 63;
    const int l15 = l & 15;
    const int g   = l >> 4;         // 0..3

    short8_t qf[2];
    {
        const float* qrow = q + ((size_t)b * N_ + q0 + w * 16 + l15) * DIM_;
        #pragma unroll
        for (int dc = 0; dc < 2; ++dc) {
            const float4v* p4 = (const float4v*)(qrow + g * 8 + 32 * dc);
            float4v x0 = p4[0], x1 = p4[1];
            uint4v uv;
            uv[0] = pack_bf16(x0[0], x0[1]);
            uv[1] = pack_bf16(x0[2], x0[3]);
            uv[2] = pack_bf16(x1[0], x1[1]);
            uv[3] = pack_bf16(x1[2], x1[3]);
            qf[dc] = __builtin_bit_cast(short8_t, uv);
        }
    }

    float4v o[4];
    #pragma unroll
    for (int i = 0; i < 4; ++i) o[i] = (float4v){0.f, 0.f, 0.f, 0.f};
    float m_run = -3.0e38f, l_run = 0.f;

    const int kcolK = tid >> 1, dhK = tid & 1;
    const int kkp   = tid >> 2, dq  = tid & 3;

    for (int t = 0; t < 49; ++t) {
        const int k0 = t * 64;
        {
            const float* src = kg + ((size_t)b * NR_ + k0 + kcolK) * 64 + dhK * 32;
            unsigned* dst = Ku + kcolK * 36 + dhK * 16;
            #pragma unroll
            for (int c4 = 0; c4 < 8; ++c4) {
                float4v v = ((const float4v*)src)[c4];
                dst[c4 * 2]     = pack_bf16(v[0], v[1]);
                dst[c4 * 2 + 1] = pack_bf16(v[2], v[3]);
            }
        }
        {
            const float* s0 = vg + ((size_t)b * NR_ + k0 + 2 * kkp) * 64 + dq * 16;
            const float* s1 = s0 + 64;
            #pragma unroll
            for (int c4 = 0; c4 < 4; ++c4) {
                float4v a  = ((const float4v*)s0)[c4];
                float4v bb = ((const float4v*)s1)[c4];
                #pragma unroll
                for (int e = 0; e < 4; ++e)
                    Vtu[(dq * 16 + c4 * 4 + e) * 36 + kkp] = pack_bf16(a[e], bb[e]);
            }
        }
        __syncthreads();

        float4v sc[4];
        const char* Kb = (const char*)Ku;
        #pragma unroll
        for (int c = 0; c < 4; ++c) {
            float4v acc = (float4v){0.f, 0.f, 0.f, 0.f};
            #pragma unroll
            for (int dc = 0; dc < 2; ++dc) {
                short8_t ak = *(const short8_t*)(Kb + (c * 16 + l15) * 144 + (g + 4 * dc) * 16);
                acc = __builtin_amdgcn_mfma_f32_16x16x32_bf16(ak, qf[dc], acc, 0, 0, 0);
            }
            sc[c] = acc;
        }

        float tmax = -3.0e38f;
        #pragma unroll
        for (int c = 0; c < 4; ++c)
            #pragma unroll
            for (int r = 0; r < 4; ++r) {
                sc[c][r] *= 0.125f;
                tmax = fmaxf(tmax, sc[c][r]);
            }
        tmax = fmaxf(tmax, __shfl_xor(tmax, 16));
        tmax = fmaxf(tmax, __shfl_xor(tmax, 32));
        float m_new = fmaxf(m_run, tmax);
        float corr = __expf(m_run - m_new);
        float p[4][4];
        float ladd = 0.f;
        #pragma unroll
        for (int c = 0; c < 4; ++c)
            #pragma unroll
            for (int r = 0; r < 4; ++r) {
                float pe = __expf(sc[c][r] - m_new);
                p[c][r] = pe;
                ladd += pe;
            }
        ladd += __shfl_xor(ladd, 16);
        ladd += __shfl_xor(ladd, 32);
        l_run = l_run * corr + ladd;
        m_run = m_new;

        {
            unsigned* Pw = Pu + w * (16 * 36) + l15 * 36;
            #pragma unroll
            for (int c = 0; c < 4; ++c) {
                Pw[8 * c + 2 * g]     = pack_bf16(p[c][0], p[c][1]);
                Pw[8 * c + 2 * g + 1] = pack_bf16(p[c][2], p[c][3]);
            }
        }

        float co[4];
        #pragma unroll
        for (int r = 0; r < 4; ++r) co[r] = __shfl(corr, g * 4 + r);
        #pragma unroll
        for (int dc = 0; dc < 4; ++dc)
            #pragma unroll
            for (int r = 0; r < 4; ++r) o[dc][r] *= co[r];

        {
            const char* Pb = (const char*)(Pu + w * (16 * 36));
            const char* Vb = (const char*)Vtu;
            #pragma unroll
            for (int kkc = 0; kkc < 2; ++kkc) {
                short8_t ap = *(const short8_t*)(Pb + l15 * 144 + (g + 4 * kkc) * 16);
                #pragma unroll
                for (int dc = 0; dc < 4; ++dc) {
                    short8_t bv = *(const short8_t*)(Vb + (dc * 16 + l15) * 144 + (g + 4 * kkc) * 16);
                    o[dc] = __builtin_amdgcn_mfma_f32_16x16x32_bf16(ap, bv, o[dc], 0, 0, 0);
                }
            }
        }
        __syncthreads();
    }

    float inv[4];
    #pragma unroll
    for (int r = 0; r < 4; ++r) inv[r] = 1.0f / __shfl(l_run, g * 4 + r);
    #pragma unroll
    for (int dc = 0; dc < 4; ++dc)
        #pragma unroll
        for (int r = 0; r < 4; ++r) {
            int row = q0 + w * 16 + g * 4 + r;
            catb[((size_t)b * N_ + row) * DIM_ + dc * 16 + l15] = bf16r(o[dc][r] * inv[r]);
        }
}

// =====================================================================
// depthwise 3x3 + bias on x_l (channels 64..511 of x), out bf16 (B,N,448)
// =====================================================================
__global__ __launch_bounds__(256)
void dwt_kernel(const float* __restrict__ x, const float* __restrict__ w,
                const float* __restrict__ bias, ushort_t* __restrict__ out) {
    int idx = blockIdx.x * 256 + threadIdx.x;
    if (idx >= B_ * N_ * DL_) return;
    int c = idx % DL_;
    int n = (idx / DL_) % N_;
    int b = idx / (DL_ * N_);
    int y = n / Wimg, xx = n % Wimg;
    float sum = bias[c];
    #pragma unroll
    for (int ky = 0; ky < 3; ++ky)
        #pragma unroll
        for (int kx = 0; kx < 3; ++kx) {
            int yy = y + ky - 1, x2 = xx + kx - 1;
            if (yy >= 0 && yy < Himg && x2 >= 0 && x2 < Wimg)
                sum += x[((size_t)b * N_ + yy * Wimg + x2) * DIM_ + D0_ + c] * w[c * 9 + ky * 3 + kx];
        }
    out[idx] = bf16r(sum);
}

// =====================================================================
// "scrambled mean" (reads fp32 kvl)
// =====================================================================
__global__ __launch_bounds__(256)
void local_mean_kernel(const float* __restrict__ kvl, float* __restrict__ kvm,
                       int L, int nBW, int stride, int dil, int choff) {
    int idx = blockIdx.x * 256 + threadIdx.x;
    if (idx >= B_ * NH_ * 49 * HD_) return;
    int d2 = idx % HD_;
    int n  = (idx / HD_) % 49;
    int h  = (idx / (HD_ * 49)) % NH_;
    int b  = idx / (HD_ * 49 * NH_);
    int wy = n / 7, wx = n % 7;
    float sum = 0.f;
    int f0 = d2 * L;
    for (int l2 = 0; l2 < L; ++l2) {
        int f = f0 + l2;
        int l = f / HD_;
        int d = f - l * HD_;
        int by = l / nBW, bx = l % nBW;
        int Y = by * stride + dil * wy;
        int X = bx * stride + dil * wx;
        if (Y >= Himg) Y = 2 * Himg - 2 - Y;   // reflect
        if (X >= Wimg) X = 2 * Wimg - 2 - X;
        sum += kvl[((size_t)b * N_ + Y * Wimg + X) * DL_ + choff + h * HD_ + d];
    }
    kvm[idx] = sum * (1.0f / (float)L);
}

// =====================================================================
// kv = kvm @ fc_w @ sh_w -> (B*NH, 49, 56)
// =====================================================================
__global__ __launch_bounds__(64)
void fcsh_kernel(const float* __restrict__ kvm, const float* __restrict__ fcw,
                 const float* __restrict__ shw, float* __restrict__ out) {
    int bh = blockIdx.x;
    __shared__ float kin[49][28];
    __shared__ float tmp[49][28];
    __shared__ float fw[28 * 28];
    __shared__ float sw[28 * 56];
    int t = threadIdx.x;
    for (int i = t; i < 49 * 28; i += 64) kin[i / 28][i % 28] = kvm[bh * 49 * 28 + i];
    for (int i = t; i < 28 * 28; i += 64) fw[i] = fcw[i];
    for (int i = t; i < 28 * 56; i += 64) sw[i] = shw[i];
    __syncthreads();
    for (int i = t; i < 49 * 28; i += 64) {
        int rr = i / 28, j = i % 28;
        float s = 0.f;
        for (int k = 0; k < 28; ++k) s += kin[rr][k] * fw[k * 28 + j];
        tmp[rr][j] = s;
    }
    __syncthreads();
    for (int i = t; i < 49 * 56; i += 64) {
        int rr = i / 56, j = i % 56;
        float s = 0.f;
        for (int k = 0; k < 28; ++k) s += tmp[rr][k] * sw[k * 56 + j];
        out[bh * 49 * 56 + i] = s;
    }
}

// =====================================================================
// v_ + depthwise3x3(v_img 7x7) + bias -> vc (B*NH, 49, 28)
// =====================================================================
__global__ __launch_bounds__(256)
void vconv_kernel(const float* __restrict__ kvsh, const float* __restrict__ w,
                  const float* __restrict__ bias, float* __restrict__ vc) {
    int idx = blockIdx.x * 256 + threadIdx.x;
    if (idx >= B_ * NH_ * 49 * HD_) return;
    int d  = idx % HD_;
    int n  = (idx / HD_) % 49;
    int bh = idx / (HD_ * 49);
    int h  = bh % NH_;
    int y = n / 7, xx = n % 7;
    int c = h * HD_ + d;
    float sum = kvsh[(bh * 49 + n) * 56 + 28 + d] + bias[c];
    #pragma unroll
    for (int ky = 0; ky < 3; ++ky)
        #pragma unroll
        for (int kx = 0; kx < 3; ++kx) {
            int yy = y + ky - 1, x2 = xx + kx - 1;
            if (yy >= 0 && yy < 7 && x2 >= 0 && x2 < 7)
                sum += kvsh[(bh * 49 + yy * 7 + x2) * 56 + 28 + d] * w[c * 9 + ky * 3 + kx];
        }
    vc[idx] = sum;
}

// =====================================================================
// local attention: 49 keys, hd=28. one thread per q-row. bf16 cat out.
// =====================================================================
__global__ __launch_bounds__(256)
void attn_local_kernel(const float* __restrict__ q, const float* __restrict__ kvsh,
                       const float* __restrict__ vc, ushort_t* __restrict__ catb,
                       int qcoloff, int outcoloff) {
    const int bh = blockIdx.y;
    const int b = bh / NH_, h = bh % NH_;
    const int n = blockIdx.x * 256 + threadIdx.x;
    __shared__ float Ks[49][28];
    __shared__ float Vsh[49][28];
    const int t = threadIdx.x;
    for (int i = t; i < 49 * 28; i += 256) {
        int rr = i / 28, d = i % 28;
        Ks[rr][d]  = kvsh[(bh * 49 + rr) * 56 + d];
        Vsh[rr][d] = vc[(bh * 49 + rr) * 28 + d];
    }
    __syncthreads();
    float qr[28];
    const float* qp = q + ((size_t)b * N_ + n) * DIM_ + qcoloff + h * 56;
    #pragma unroll
    for (int d = 0; d < 28; ++d) qr[d] = qp[d];
    const float scale = 0.1889822365046136f;   // 28^-0.5
    float mx = -1e30f;
    for (int k = 0; k < 49; ++k) {
        float s = 0.f;
        #pragma unroll
        for (int d = 0; d < 28; ++d) s += qr[d] * Ks[k][d];
        mx = fmaxf(mx, s * scale);
    }
    float l = 0.f;
    float acc[28] = {};
    for (int k = 0; k < 49; ++k) {
        float s = 0.f;
        #pragma unroll
        for (int d = 0; d < 28; ++d) s += qr[d] * Ks[k][d];
        float p = __expf(s * scale - mx);
        l += p;
        #pragma unroll
        for (int d = 0; d < 28; ++d) acc[d] += p * Vsh[k][d];
    }
    float inv = 1.f / l;
    ushort_t* op = catb + ((size_t)b * N_ + n) * DIM_ + outcoloff + h * HD_;
    #pragma unroll
    for (int d = 0; d < 28; ++d) op[d] = bf16r(acc[d] * inv);
}

// =====================================================================
extern "C" void kernel_launch(void* const* d_in, const int* in_sizes, int n_in,
                              void* d_out, int out_size, void* d_ws, size_t ws_size,
                              hipStream_t stream) {
    const float* x      = (const float*)d_in[0];
    const float* Wq     = (const float*)d_in[1];
    const float* Wkv_g  = (const float*)d_in[2];
    const float* sr_w   = (const float*)d_in[3];
    const float* sr_b   = (const float*)d_in[4];
    const float* ln_g   = (const float*)d_in[5];
    const float* ln_b   = (const float*)d_in[6];
    const float* lcg_w  = (const float*)d_in[7];
    const float* lcg_b  = (const float*)d_in[8];
    const float* kvl_dw = (const float*)d_in[9];
    const float* kvl_db = (const float*)d_in[10];
    const float* kvl_pw = (const float*)d_in[11];
    const float* kvl_pb = (const float*)d_in[12];
    const float* fc1_w  = (const float*)d_in[13];
    const float* sh1_w  = (const float*)d_in[14];
    const float* lc1_w  = (const float*)d_in[15];
    const float* lc1_b  = (const float*)d_in[16];
    const float* fc2_w  = (const float*)d_in[17];
    const float* sh2_w  = (const float*)d_in[18];
    const float* lc2_w  = (const float*)d_in[19];
    const float* lc2_b  = (const float*)d_in[20];
    const float* proj_w = (const float*)d_in[21];
    const float* proj_b = (const float*)d_in[22];
    float* out = (float*)d_out;
    char* base = (char*)d_ws;

    // ---- workspace layout (256B aligned) ----
    size_t o = 0;
    auto alloc = [&](size_t bytes) -> void* {
        void* p = base + o;
        o = (o + bytes + 255) & ~(size_t)255;
        return p;
    };
    float*    q     = (float*)   alloc((size_t)B_ * N_ * DIM_ * 4);
    float*    kvl   = (float*)   alloc((size_t)B_ * N_ * DL_ * 4);
    ushort_t* xcat  = (ushort_t*)alloc((size_t)B_ * N_ * DIM_ * 2);  // xbf, then cat
    ushort_t* dwtb  = (ushort_t*)alloc((size_t)B_ * N_ * DL_ * 2);
    float*    kg    = (float*)   alloc((size_t)B_ * NR_ * 64 * 4);
    float*    vg    = (float*)   alloc((size_t)B_ * NR_ * 64 * 4);
    float*    vg2   = (float*)   alloc((size_t)B_ * NR_ * 64 * 4);
    ushort_t* wqt   = (ushort_t*)alloc((size_t)512 * 512 * 2);
    ushort_t* pwt   = (ushort_t*)alloc((size_t)512 * 448 * 2);
    ushort_t* projt = (ushort_t*)alloc((size_t)512 * 512 * 2);
    float*    kvm1  = (float*)   alloc((size_t)B_ * NH_ * 49 * HD_ * 4);
    float*    kvm2  = (float*)   alloc((size_t)B_ * NH_ * 49 * HD_ * 4);
    float*    kv1   = (float*)   alloc((size_t)B_ * NH_ * 49 * 56 * 4);
    float*    kv2   = (float*)   alloc((size_t)B_ * NH_ * 49 * 56 * 4);
    float*    v1c   = (float*)   alloc((size_t)B_ * NH_ * 49 * HD_ * 4);
    float*    v2c   = (float*)   alloc((size_t)B_ * NH_ * 49 * HD_ * 4);
    ushort_t* xbf  = xcat;
    ushort_t* catb = xcat;

    const int M = B_ * N_;   // 25088

    // 0. weight converts (tiny)
    convw_kernel<<<512 * 512 / 256, 256, 0, stream>>>(Wq, wqt, 512, 512, 1);
    convw_kernel<<<512 * 448 / 256, 256, 0, stream>>>(kvl_pw, pwt, 448, 448, 0);
    convw_kernel<<<512 * 512 / 256, 256, 0, stream>>>(proj_w, projt, 512, 512, 1);
    // 0b. x -> bf16
    convx_kernel<<<(B_ * N_ * DIM_ / 8) / 256, 256, 0, stream>>>(x, xbf);

    // 1. q = x @ Wq   (bf16 MFMA)
    gemm_bf16_kernel<false><<<dim3(M / 128, 4), 256, 0, stream>>>(
        xbf, wqt, nullptr, q, 512, 512, 512);

    // 2. depthwise on x_l -> dwtb (bf16)
    dwt_kernel<<<(B_ * N_ * DL_) / 256, 256, 0, stream>>>(x, kvl_dw, kvl_db, dwtb);

    // 3. pointwise: kvl = dwtb @ pwt^T + pb
    gemm_bf16_kernel<true><<<dim3(M / 128, 4), 256, 0, stream>>>(
        dwtb, pwt, kvl_pb, kvl, 448, 448, 448);

    // 4. global branch: sr conv + LN + kv
    srlnkv_kernel<<<B_ * NR_, 64, 0, stream>>>(x, sr_w, sr_b, ln_g, ln_b, Wkv_g, kg, vg);

    // 5. vg2 = vg + depthwise(vg)
    lcg_kernel<<<(B_ * NR_ * 64) / 256, 256, 0, stream>>>(vg, lcg_w, lcg_b, vg2);

    // 6. global flash attention (bf16 MFMA) -> catb cols [0,64)
    attn_global_mfma<<<dim3(N_ / 32, B_), 128, 0, stream>>>(q, kg, vg2, catb);

    // 7. scrambled means
    {
        int tot = B_ * NH_ * 49 * HD_;
        int blocks = (tot + 255) / 256;
        local_mean_kernel<<<blocks, 256, 0, stream>>>(kvl, kvm1, 256, 16, 7, 1, 0);
        local_mean_kernel<<<blocks, 256, 0, stream>>>(kvl, kvm2, 81, 9, 13, 2, 224);
    }

    // 8. fc @ sh
    fcsh_kernel<<<B_ * NH_, 64, 0, stream>>>(kvm1, fc1_w, sh1_w, kv1);
    fcsh_kernel<<<B_ * NH_, 64, 0, stream>>>(kvm2, fc2_w, sh2_w, kv2);

    // 9. v local conv
    {
        int tot = B_ * NH_ * 49 * HD_;
        int blocks = (tot + 255) / 256;
        vconv_kernel<<<blocks, 256, 0, stream>>>(kv1, lc1_w, lc1_b, v1c);
        vconv_kernel<<<blocks, 256, 0, stream>>>(kv2, lc2_w, lc2_b, v2c);
    }

    // 10. local attention -> catb cols [64,288) and [288,512)
    attn_local_kernel<<<dim3(N_ / 256, B_ * NH_), 256, 0, stream>>>(
        q, kv1, v1c, catb, D0_, D0_);
    attn_local_kernel<<<dim3(N_ / 256, B_ * NH_), 256, 0, stream>>>(
        q, kv2, v2c, catb, D0_ + HD_, D0_ + 224);

    // 11. out = catb @ projt^T + proj_b
    gemm_bf16_kernel<true><<<dim3(M / 128, 4), 256, 0, stream>>>(
        catb, projt, proj_b, out, 512, 512, 512);
}

// Round 4
// 593.300 us; speedup vs baseline: 4.9093x; 1.1549x over previous
//
#include <hip/hip_runtime.h>
#include <hip/hip_bf16.h>
#include <math.h>
#include <stdint.h>

// ---- problem constants ----
static constexpr int B_    = 2;
static constexpr int N_    = 12544;   // 112*112
static constexpr int DIM_  = 512;
static constexpr int D0_   = 64;
static constexpr int DL_   = 448;
static constexpr int Himg  = 112;
static constexpr int Wimg  = 112;
static constexpr int HS_   = 56;
static constexpr int NR_   = 3136;    // 56*56
static constexpr int NH_   = 8;
static constexpr int HD_   = 28;

typedef unsigned short ushort_t;
typedef __attribute__((ext_vector_type(8))) short short8_t;
typedef __attribute__((ext_vector_type(4))) float float4v;
typedef __attribute__((ext_vector_type(4))) unsigned uint4v;

// round-to-nearest-even f32 -> bf16
static __device__ inline ushort_t bf16r(float x) {
    unsigned u = __builtin_bit_cast(unsigned, x);
    u = (u + 0x7FFFu + ((u >> 16) & 1u)) >> 16;
    return (ushort_t)u;
}
// pack two f32 -> u32 of 2 bf16 (lo, hi)
static __device__ inline unsigned pack_bf16(float lo, float hi) {
    unsigned a = __builtin_bit_cast(unsigned, lo);
    unsigned b = __builtin_bit_cast(unsigned, hi);
    a = (a + 0x7FFFu + ((a >> 16) & 1u)) >> 16;
    b = (b + 0x7FFFu + ((b >> 16) & 1u)) >> 16;
    return a | (b << 16);
}

using gptr_t = const __attribute__((address_space(1))) void*;
using lptr_t = __attribute__((address_space(3))) void*;
static __device__ inline void gload16(const void* g, void* l) {
    __builtin_amdgcn_global_load_lds((gptr_t)(uintptr_t)g, (lptr_t)(uintptr_t)l, 16, 0, 0);
}

// =====================================================================
// bf16 MFMA GEMM: C[M][ldc] (fp32) = A[M][K](bf16) @ Bt[Npad][K](bf16)^T
// 128x128 tile, BK=64, 256 threads (4 waves in 2x2), single-buffer loop.
// =====================================================================
template<bool HASBIAS>
__global__ __launch_bounds__(256, 2)
void gemm_bf16_kernel(const ushort_t* __restrict__ A,
                      const ushort_t* __restrict__ Bt,
                      const float* __restrict__ bias,
                      float* __restrict__ C,
                      int Nn, int K, int ldc) {
    constexpr int BM = 128, BK = 64;
    __shared__ __align__(16) ushort_t As[BM * BK];
    __shared__ __align__(16) ushort_t Bs[BM * BK];
    const int bm = blockIdx.x * BM;
    const int bn = blockIdx.y * BM;
    const int tid = threadIdx.x;
    const int l15 = tid & 15;
    const int g   = (tid & 63) >> 4;
    const int w   = tid >> 6;
    const int wr  = w >> 1, wc = w & 1;

    float4v acc[4][4];
    #pragma unroll
    for (int m = 0; m < 4; ++m)
        #pragma unroll
        for (int n = 0; n < 4; ++n) acc[m][n] = (float4v){0.f, 0.f, 0.f, 0.f};

    for (int k0 = 0; k0 < K; k0 += BK) {
        #pragma unroll
        for (int i = 0; i < 4; ++i) {
            int c = i * 256 + tid;
            int r = c >> 3, ch = c & 7;
            int sch = ch ^ (r & 7);
            gload16(A  + (size_t)(bm + r) * K + k0 + sch * 8, (void*)(As + c * 8));
            gload16(Bt + (size_t)(bn + r) * K + k0 + sch * 8, (void*)(Bs + c * 8));
        }
        __syncthreads();

        short8_t af[4][2], bfr[4][2];
        #pragma unroll
        for (int m = 0; m < 4; ++m) {
            int ar = wr * 64 + m * 16 + l15;
            #pragma unroll
            for (int h = 0; h < 2; ++h)
                af[m][h] = *(const short8_t*)((const char*)As + ar * 128 + (((h * 4 + g) ^ (ar & 7)) * 16));
        }
        #pragma unroll
        for (int n = 0; n < 4; ++n) {
            int br = wc * 64 + n * 16 + l15;
            #pragma unroll
            for (int h = 0; h < 2; ++h)
                bfr[n][h] = *(const short8_t*)((const char*)Bs + br * 128 + (((h * 4 + g) ^ (br & 7)) * 16));
        }
        #pragma unroll
        for (int m = 0; m < 4; ++m)
            #pragma unroll
            for (int n = 0; n < 4; ++n) {
                acc[m][n] = __builtin_amdgcn_mfma_f32_16x16x32_bf16(af[m][0], bfr[n][0], acc[m][n], 0, 0, 0);
                acc[m][n] = __builtin_amdgcn_mfma_f32_16x16x32_bf16(af[m][1], bfr[n][1], acc[m][n], 0, 0, 0);
            }
        __syncthreads();
    }

    #pragma unroll
    for (int n = 0; n < 4; ++n) {
        int ccol = bn + wc * 64 + n * 16 + l15;
        if (ccol < Nn) {
            float bv = HASBIAS ? bias[ccol] : 0.f;
            #pragma unroll
            for (int m = 0; m < 4; ++m) {
                int crow = bm + wr * 64 + m * 16 + g * 4;
                #pragma unroll
                for (int j = 0; j < 4; ++j)
                    C[(size_t)(crow + j) * ldc + ccol] = acc[m][n][j] + bv;
            }
        }
    }
}

// =====================================================================
// weight convert: Wt[Npad][K] bf16 from W (transpose? W[K][Nn] : W[Nn][K])
// =====================================================================
__global__ __launch_bounds__(256)
void convw_kernel(const float* __restrict__ W, ushort_t* __restrict__ Wt,
                  int K, int Nn, int transpose) {
    int idx = blockIdx.x * 256 + threadIdx.x;
    int n = idx / K, k = idx % K;
    float v = 0.f;
    if (n < Nn) v = transpose ? W[(size_t)k * Nn + n] : W[(size_t)n * K + k];
    Wt[idx] = bf16r(v);
}

// fp32 -> bf16 bulk convert, 8 elems/thread
__global__ __launch_bounds__(256)
void convx_kernel(const float* __restrict__ in, ushort_t* __restrict__ outp) {
    int i = blockIdx.x * 256 + threadIdx.x;
    const float4v* p = (const float4v*)(in + (size_t)i * 8);
    float4v a = p[0], b = p[1];
    uint4v u;
    u[0] = pack_bf16(a[0], a[1]);
    u[1] = pack_bf16(a[2], a[3]);
    u[2] = pack_bf16(b[0], b[1]);
    u[3] = pack_bf16(b[2], b[3]);
    *(uint4v*)(outp + (size_t)i * 8) = u;
}

// =====================================================================
// sr-conv (2x2 stride2, 64->64) + LayerNorm(64) + kv GEMM (64->128)
// K output written as bf16 (attention-ready); V stays fp32 (lcg input)
// =====================================================================
__global__ __launch_bounds__(64)
void srlnkv_kernel(const float* __restrict__ x,
                   const float* __restrict__ sr_w, const float* __restrict__ sr_b,
                   const float* __restrict__ ln_g, const float* __restrict__ ln_b,
                   const float* __restrict__ wkv,
                   ushort_t* __restrict__ kgb, float* __restrict__ vg) {
    const int pos = blockIdx.x;              // b*NR + n
    const int b = pos / NR_, n = pos % NR_;
    const int y = n / HS_, xx = n % HS_;
    const int o = threadIdx.x;               // 0..63
    __shared__ float xs[4][64];
    __shared__ float lnv_s[64];
    #pragma unroll
    for (int tap = 0; tap < 4; ++tap) {
        int ky = tap / 2, kx = tap % 2;
        xs[tap][o] = x[((size_t)b * N_ + (2 * y + ky) * Wimg + 2 * xx + kx) * DIM_ + o];
    }
    __syncthreads();
    float sum = sr_b[o];
    for (int i = 0; i < 64; ++i) {
        const float* w = sr_w + o * 256 + i * 4;
        sum += xs[0][i] * w[0] + xs[1][i] * w[1] + xs[2][i] * w[2] + xs[3][i] * w[3];
    }
    float m = sum;
    #pragma unroll
    for (int off = 1; off < 64; off <<= 1) m += __shfl_xor(m, off);
    m *= (1.0f / 64.0f);
    float d = sum - m;
    float v = d * d;
    #pragma unroll
    for (int off = 1; off < 64; off <<= 1) v += __shfl_xor(v, off);
    v *= (1.0f / 64.0f);
    float lnv = d * rsqrtf(v + 1e-5f) * ln_g[o] + ln_b[o];
    lnv_s[o] = lnv;
    __syncthreads();
    float s0 = 0.f, s1 = 0.f;
    for (int i = 0; i < 64; ++i) {
        float lv = lnv_s[i];
        s0 += lv * wkv[i * 128 + o];
        s1 += lv * wkv[i * 128 + o + 64];
    }
    kgb[((size_t)b * NR_ + n) * 64 + o] = bf16r(s0);
    vg[((size_t)b * NR_ + n) * 64 + o] = s1;
}

// =====================================================================
// depthwise 3x3 + bias on v_g image; vg2 = vg + conv (fp32)
// =====================================================================
__global__ __launch_bounds__(256)
void lcg_kernel(const float* __restrict__ vg, const float* __restrict__ w,
                const float* __restrict__ bias, float* __restrict__ vg2) {
    int idx = blockIdx.x * 256 + threadIdx.x;
    if (idx >= B_ * NR_ * 64) return;
    int c = idx % 64;
    int n = (idx / 64) % NR_;
    int b = idx / (64 * NR_);
    int y = n / HS_, xx = n % HS_;
    float sum = vg[idx] + bias[c];
    #pragma unroll
    for (int ky = 0; ky < 3; ++ky)
        #pragma unroll
        for (int kx = 0; kx < 3; ++kx) {
            int yy = y + ky - 1, x2 = xx + kx - 1;
            if (yy >= 0 && yy < HS_ && x2 >= 0 && x2 < HS_)
                sum += vg[((size_t)b * NR_ + yy * HS_ + x2) * 64 + c] * w[c * 9 + ky * 3 + kx];
        }
    vg2[idx] = sum;
}

// =====================================================================
// transpose+convert: vg2 fp32 [B][NR][64] -> vtb bf16 [B][64][NR]
// =====================================================================
__global__ __launch_bounds__(256)
void vtrans_kernel(const float* __restrict__ vg2, ushort_t* __restrict__ vtb) {
    __shared__ float ld[64][65];
    const int b = blockIdx.y, n0 = blockIdx.x * 64, tid = threadIdx.x;
    #pragma unroll
    for (int i = 0; i < 16; ++i) {
        int idx = i * 256 + tid;
        int n = idx >> 6, c = idx & 63;
        ld[n][c] = vg2[((size_t)b * NR_ + n0 + n) * 64 + c];
    }
    __syncthreads();
    #pragma unroll
    for (int i = 0; i < 16; ++i) {
        int idx = i * 256 + tid;
        int d = idx >> 6, nn = idx & 63;
        vtb[(size_t)(b * 64 + d) * NR_ + n0 + nn] = bf16r(ld[nn][d]);
    }
}

// =====================================================================
// Global-branch flash attention, split-K (2 splits), bf16 MFMA.
// 128 threads (2 waves), 32 q-rows/block. K/V pre-converted bf16;
// staging via global_load_lds + XOR both-sides swizzle.
// Outputs unnormalized o + (m,l) per row for the combine pass.
// =====================================================================
__global__ __launch_bounds__(128)
void attn_global_split(const float* __restrict__ q,
                       const ushort_t* __restrict__ kgb,
                       const ushort_t* __restrict__ vtb,
                       float* __restrict__ osp, float* __restrict__ mls) {
    __shared__ __align__(16) ushort_t Ks[64 * 64];
    __shared__ __align__(16) ushort_t Vs[64 * 64];
    __shared__ __align__(16) unsigned Pu[1024];    // 2 waves x 16 rows x 32 u32
    const int split = blockIdx.y & 1;
    const int b     = blockIdx.y >> 1;
    const int q0    = blockIdx.x * 32;
    const int tid   = threadIdx.x;
    const int w     = tid >> 6;
    const int l     = tid & 63;
    const int l15   = l & 15;
    const int g     = l >> 4;
    const int lx    = l15 & 7;

    // Q fragments (B-operand of score MFMA)
    short8_t qf[2];
    {
        const float* qrow = q + ((size_t)b * N_ + q0 + w * 16 + l15) * DIM_;
        #pragma unroll
        for (int dc = 0; dc < 2; ++dc) {
            const float4v* p4 = (const float4v*)(qrow + g * 8 + 32 * dc);
            float4v x0 = p4[0], x1 = p4[1];
            uint4v uv;
            uv[0] = pack_bf16(x0[0], x0[1]);
            uv[1] = pack_bf16(x0[2], x0[3]);
            uv[2] = pack_bf16(x1[0], x1[1]);
            uv[3] = pack_bf16(x1[2], x1[3]);
            qf[dc] = __builtin_bit_cast(short8_t, uv);
        }
    }

    float4v o[4];
    #pragma unroll
    for (int i = 0; i < 4; ++i) o[i] = (float4v){0.f, 0.f, 0.f, 0.f};
    float m_run = -3.0e38f, l_run = 0.f;

    const int t0 = split ? 25 : 0;
    const int t1 = split ? 49 : 25;
    for (int t = t0; t < t1; ++t) {
        const int k0 = t * 64;
        // stage K (64 kcols x 64 d) and Vt (64 d x 64 kk), both bf16
        #pragma unroll
        for (int i = 0; i < 4; ++i) {
            int c = i * 128 + tid;          // 0..511
            int r = c >> 3, ch = c & 7;
            int sch = ch ^ (r & 7);
            gload16(kgb + ((size_t)(b * NR_ + k0 + r) << 6) + sch * 8, (void*)(Ks + c * 8));
            gload16(vtb + (size_t)(b * 64 + r) * NR_ + k0 + sch * 8, (void*)(Vs + c * 8));
        }
        __syncthreads();

        // scores S^T: 4 x mfma(A=K chunk, B=Q^T)
        float4v sc[4];
        #pragma unroll
        for (int c = 0; c < 4; ++c) {
            float4v acc = (float4v){0.f, 0.f, 0.f, 0.f};
            #pragma unroll
            for (int dc = 0; dc < 2; ++dc) {
                int row = c * 16 + l15;
                short8_t ak = *(const short8_t*)((const char*)Ks + row * 128 + (((g + 4 * dc) ^ lx) * 16));
                acc = __builtin_amdgcn_mfma_f32_16x16x32_bf16(ak, qf[dc], acc, 0, 0, 0);
            }
            sc[c] = acc;
        }

        // online softmax (lane holds all 16 scores of qrow l15)
        float tmax = -3.0e38f;
        #pragma unroll
        for (int c = 0; c < 4; ++c)
            #pragma unroll
            for (int r = 0; r < 4; ++r) {
                sc[c][r] *= 0.125f;
                tmax = fmaxf(tmax, sc[c][r]);
            }
        tmax = fmaxf(tmax, __shfl_xor(tmax, 16));
        tmax = fmaxf(tmax, __shfl_xor(tmax, 32));
        float m_new = fmaxf(m_run, tmax);
        float corr = __expf(m_run - m_new);
        float p[4][4];
        float ladd = 0.f;
        #pragma unroll
        for (int c = 0; c < 4; ++c)
            #pragma unroll
            for (int r = 0; r < 4; ++r) {
                float pe = __expf(sc[c][r] - m_new);
                p[c][r] = pe;
                ladd += pe;
            }
        ladd += __shfl_xor(ladd, 16);
        ladd += __shfl_xor(ladd, 32);
        l_run = l_run * corr + ladd;
        m_run = m_new;

        // write P (bf16) to per-wave LDS, chunk-XOR swizzled
        {
            unsigned* Pw = Pu + w * 512 + l15 * 32;
            #pragma unroll
            for (int c = 0; c < 4; ++c) {
                int u32i = 8 * c + 2 * g;
                int usw = (((u32i >> 2) ^ lx) << 2) | (u32i & 3);
                Pw[usw]     = pack_bf16(p[c][0], p[c][1]);
                Pw[usw + 1] = pack_bf16(p[c][2], p[c][3]);
            }
        }

        // rescale O (O rows are qrow = g*4+r)
        float co[4];
        #pragma unroll
        for (int r = 0; r < 4; ++r) co[r] = __shfl(corr, g * 4 + r);
        #pragma unroll
        for (int dc = 0; dc < 4; ++dc)
            #pragma unroll
            for (int r = 0; r < 4; ++r) o[dc][r] *= co[r];

        // PV: O += P @ V
        #pragma unroll
        for (int kkc = 0; kkc < 2; ++kkc) {
            short8_t ap = *(const short8_t*)((const char*)Pu + w * 2048 + l15 * 128 + (((kkc * 4 + g) ^ lx) * 16));
            #pragma unroll
            for (int dc = 0; dc < 4; ++dc) {
                int vrow = dc * 16 + l15;
                short8_t bv = *(const short8_t*)((const char*)Vs + vrow * 128 + (((kkc * 4 + g) ^ lx) * 16));
                o[dc] = __builtin_amdgcn_mfma_f32_16x16x32_bf16(ap, bv, o[dc], 0, 0, 0);
            }
        }
        __syncthreads();
    }

    // store unnormalized o + (m,l)
    const size_t rbase = (size_t)(split * B_ + b) * N_;
    #pragma unroll
    for (int dc = 0; dc < 4; ++dc)
        #pragma unroll
        for (int r = 0; r < 4; ++r) {
            int row = q0 + w * 16 + g * 4 + r;
            osp[(rbase + row) * 64 + dc * 16 + l15] = o[dc][r];
        }
    if (l < 16) {
        int row = q0 + w * 16 + l15;
        mls[(rbase + row) * 2]     = m_run;
        mls[(rbase + row) * 2 + 1] = l_run;
    }
}

// =====================================================================
// combine the 2 splits -> catb cols [0,64)
// =====================================================================
__global__ __launch_bounds__(256)
void attn_combine(const float* __restrict__ osp, const float* __restrict__ mls,
                  ushort_t* __restrict__ catb) {
    int idx = blockIdx.x * 256 + threadIdx.x;   // B*N*64
    int col = idx & 63;
    size_t rn = (size_t)(idx >> 6);             // b*N + row
    size_t base0 = rn, base1 = rn + (size_t)B_ * N_;
    float m0 = mls[base0 * 2], l0 = mls[base0 * 2 + 1];
    float m1 = mls[base1 * 2], l1 = mls[base1 * 2 + 1];
    float m = fmaxf(m0, m1);
    float w0 = __expf(m0 - m), w1 = __expf(m1 - m);
    float linv = 1.f / (l0 * w0 + l1 * w1);
    float v = (osp[base0 * 64 + col] * w0 + osp[base1 * 64 + col] * w1) * linv;
    catb[rn * DIM_ + col] = bf16r(v);
}

// =====================================================================
// depthwise 3x3 + bias on x_l (channels 64..511 of x), out bf16 (B,N,448)
// =====================================================================
__global__ __launch_bounds__(256)
void dwt_kernel(const float* __restrict__ x, const float* __restrict__ w,
                const float* __restrict__ bias, ushort_t* __restrict__ out) {
    int idx = blockIdx.x * 256 + threadIdx.x;
    if (idx >= B_ * N_ * DL_) return;
    int c = idx % DL_;
    int n = (idx / DL_) % N_;
    int b = idx / (DL_ * N_);
    int y = n / Wimg, xx = n % Wimg;
    float sum = bias[c];
    #pragma unroll
    for (int ky = 0; ky < 3; ++ky)
        #pragma unroll
        for (int kx = 0; kx < 3; ++kx) {
            int yy = y + ky - 1, x2 = xx + kx - 1;
            if (yy >= 0 && yy < Himg && x2 >= 0 && x2 < Wimg)
                sum += x[((size_t)b * N_ + yy * Wimg + x2) * DIM_ + D0_ + c] * w[c * 9 + ky * 3 + kx];
        }
    out[idx] = bf16r(sum);
}

// =====================================================================
// "scrambled mean" (reads fp32 kvl)
// =====================================================================
__global__ __launch_bounds__(256)
void local_mean_kernel(const float* __restrict__ kvl, float* __restrict__ kvm,
                       int L, int nBW, int stride, int dil, int choff) {
    int idx = blockIdx.x * 256 + threadIdx.x;
    if (idx >= B_ * NH_ * 49 * HD_) return;
    int d2 = idx % HD_;
    int n  = (idx / HD_) % 49;
    int h  = (idx / (HD_ * 49)) % NH_;
    int b  = idx / (HD_ * 49 * NH_);
    int wy = n / 7, wx = n % 7;
    float sum = 0.f;
    int f0 = d2 * L;
    for (int l2 = 0; l2 < L; ++l2) {
        int f = f0 + l2;
        int l = f / HD_;
        int d = f - l * HD_;
        int by = l / nBW, bx = l % nBW;
        int Y = by * stride + dil * wy;
        int X = bx * stride + dil * wx;
        if (Y >= Himg) Y = 2 * Himg - 2 - Y;   // reflect
        if (X >= Wimg) X = 2 * Wimg - 2 - X;
        sum += kvl[((size_t)b * N_ + Y * Wimg + X) * DL_ + choff + h * HD_ + d];
    }
    kvm[idx] = sum * (1.0f / (float)L);
}

// =====================================================================
// kv = kvm @ fc_w @ sh_w -> (B*NH, 49, 56)
// =====================================================================
__global__ __launch_bounds__(64)
void fcsh_kernel(const float* __restrict__ kvm, const float* __restrict__ fcw,
                 const float* __restrict__ shw, float* __restrict__ out) {
    int bh = blockIdx.x;
    __shared__ float kin[49][28];
    __shared__ float tmp[49][28];
    __shared__ float fw[28 * 28];
    __shared__ float sw[28 * 56];
    int t = threadIdx.x;
    for (int i = t; i < 49 * 28; i += 64) kin[i / 28][i % 28] = kvm[bh * 49 * 28 + i];
    for (int i = t; i < 28 * 28; i += 64) fw[i] = fcw[i];
    for (int i = t; i < 28 * 56; i += 64) sw[i] = shw[i];
    __syncthreads();
    for (int i = t; i < 49 * 28; i += 64) {
        int rr = i / 28, j = i % 28;
        float s = 0.f;
        for (int k = 0; k < 28; ++k) s += kin[rr][k] * fw[k * 28 + j];
        tmp[rr][j] = s;
    }
    __syncthreads();
    for (int i = t; i < 49 * 56; i += 64) {
        int rr = i / 56, j = i % 56;
        float s = 0.f;
        for (int k = 0; k < 28; ++k) s += tmp[rr][k] * sw[k * 56 + j];
        out[bh * 49 * 56 + i] = s;
    }
}

// =====================================================================
// v_ + depthwise3x3(v_img 7x7) + bias -> vc (B*NH, 49, 28)
// =====================================================================
__global__ __launch_bounds__(256)
void vconv_kernel(const float* __restrict__ kvsh, const float* __restrict__ w,
                  const float* __restrict__ bias, float* __restrict__ vc) {
    int idx = blockIdx.x * 256 + threadIdx.x;
    if (idx >= B_ * NH_ * 49 * HD_) return;
    int d  = idx % HD_;
    int n  = (idx / HD_) % 49;
    int bh = idx / (HD_ * 49);
    int h  = bh % NH_;
    int y = n / 7, xx = n % 7;
    int c = h * HD_ + d;
    float sum = kvsh[(bh * 49 + n) * 56 + 28 + d] + bias[c];
    #pragma unroll
    for (int ky = 0; ky < 3; ++ky)
        #pragma unroll
        for (int kx = 0; kx < 3; ++kx) {
            int yy = y + ky - 1, x2 = xx + kx - 1;
            if (yy >= 0 && yy < 7 && x2 >= 0 && x2 < 7)
                sum += kvsh[(bh * 49 + yy * 7 + x2) * 56 + 28 + d] * w[c * 9 + ky * 3 + kx];
        }
    vc[idx] = sum;
}

// =====================================================================
// local attention: 49 keys, hd=28. one thread per q-row.
// =====================================================================
__global__ __launch_bounds__(256)
void attn_local_kernel(const float* __restrict__ q, const float* __restrict__ kvsh,
                       const float* __restrict__ vc, ushort_t* __restrict__ catb,
                       int qcoloff, int outcoloff) {
    const int bh = blockIdx.y;
    const int b = bh / NH_, h = bh % NH_;
    const int n = blockIdx.x * 256 + threadIdx.x;
    __shared__ float Ks[49][28];
    __shared__ float Vsh[49][28];
    const int t = threadIdx.x;
    for (int i = t; i < 49 * 28; i += 256) {
        int rr = i / 28, d = i % 28;
        Ks[rr][d]  = kvsh[(bh * 49 + rr) * 56 + d];
        Vsh[rr][d] = vc[(bh * 49 + rr) * 28 + d];
    }
    __syncthreads();
    float qr[28];
    {
        const float4v* qp4 = (const float4v*)(q + ((size_t)b * N_ + n) * DIM_ + qcoloff + h * 56);
        #pragma unroll
        for (int i = 0; i < 7; ++i) {
            float4v v = qp4[i];
            qr[i * 4] = v[0]; qr[i * 4 + 1] = v[1]; qr[i * 4 + 2] = v[2]; qr[i * 4 + 3] = v[3];
        }
    }
    const float scale = 0.1889822365046136f;   // 28^-0.5
    float mx = -1e30f;
    for (int k = 0; k < 49; ++k) {
        float s = 0.f;
        #pragma unroll
        for (int d = 0; d < 28; ++d) s += qr[d] * Ks[k][d];
        mx = fmaxf(mx, s * scale);
    }
    float l = 0.f;
    float acc[28] = {};
    for (int k = 0; k < 49; ++k) {
        float s = 0.f;
        #pragma unroll
        for (int d = 0; d < 28; ++d) s += qr[d] * Ks[k][d];
        float p = __expf(s * scale - mx);
        l += p;
        #pragma unroll
        for (int d = 0; d < 28; ++d) acc[d] += p * Vsh[k][d];
    }
    float inv = 1.f / l;
    ushort_t* op = catb + ((size_t)b * N_ + n) * DIM_ + outcoloff + h * HD_;
    #pragma unroll
    for (int d = 0; d < 28; ++d) op[d] = bf16r(acc[d] * inv);
}

// =====================================================================
extern "C" void kernel_launch(void* const* d_in, const int* in_sizes, int n_in,
                              void* d_out, int out_size, void* d_ws, size_t ws_size,
                              hipStream_t stream) {
    const float* x      = (const float*)d_in[0];
    const float* Wq     = (const float*)d_in[1];
    const float* Wkv_g  = (const float*)d_in[2];
    const float* sr_w   = (const float*)d_in[3];
    const float* sr_b   = (const float*)d_in[4];
    const float* ln_g   = (const float*)d_in[5];
    const float* ln_b   = (const float*)d_in[6];
    const float* lcg_w  = (const float*)d_in[7];
    const float* lcg_b  = (const float*)d_in[8];
    const float* kvl_dw = (const float*)d_in[9];
    const float* kvl_db = (const float*)d_in[10];
    const float* kvl_pw = (const float*)d_in[11];
    const float* kvl_pb = (const float*)d_in[12];
    const float* fc1_w  = (const float*)d_in[13];
    const float* sh1_w  = (const float*)d_in[14];
    const float* lc1_w  = (const float*)d_in[15];
    const float* lc1_b  = (const float*)d_in[16];
    const float* fc2_w  = (const float*)d_in[17];
    const float* sh2_w  = (const float*)d_in[18];
    const float* lc2_w  = (const float*)d_in[19];
    const float* lc2_b  = (const float*)d_in[20];
    const float* proj_w = (const float*)d_in[21];
    const float* proj_b = (const float*)d_in[22];
    float* out = (float*)d_out;
    char* base = (char*)d_ws;

    // ---- workspace layout (256B aligned) ----
    size_t o = 0;
    auto alloc = [&](size_t bytes) -> void* {
        void* p = base + o;
        o = (o + bytes + 255) & ~(size_t)255;
        return p;
    };
    float*    q     = (float*)   alloc((size_t)B_ * N_ * DIM_ * 4);
    float*    kvl   = (float*)   alloc((size_t)B_ * N_ * DL_ * 4);   // later osp+mls
    ushort_t* xcat  = (ushort_t*)alloc((size_t)B_ * N_ * DIM_ * 2);  // xbf, then cat
    ushort_t* dwtb  = (ushort_t*)alloc((size_t)B_ * N_ * DL_ * 2);
    ushort_t* kgb   = (ushort_t*)alloc((size_t)B_ * NR_ * 64 * 2);
    float*    vg    = (float*)   alloc((size_t)B_ * NR_ * 64 * 4);
    float*    vg2   = (float*)   alloc((size_t)B_ * NR_ * 64 * 4);
    ushort_t* vtb   = (ushort_t*)alloc((size_t)B_ * 64 * NR_ * 2);
    ushort_t* wqt   = (ushort_t*)alloc((size_t)512 * 512 * 2);
    ushort_t* pwt   = (ushort_t*)alloc((size_t)512 * 448 * 2);
    ushort_t* projt = (ushort_t*)alloc((size_t)512 * 512 * 2);
    float*    kvm1  = (float*)   alloc((size_t)B_ * NH_ * 49 * HD_ * 4);
    float*    kvm2  = (float*)   alloc((size_t)B_ * NH_ * 49 * HD_ * 4);
    float*    kv1   = (float*)   alloc((size_t)B_ * NH_ * 49 * 56 * 4);
    float*    kv2   = (float*)   alloc((size_t)B_ * NH_ * 49 * 56 * 4);
    float*    v1c   = (float*)   alloc((size_t)B_ * NH_ * 49 * HD_ * 4);
    float*    v2c   = (float*)   alloc((size_t)B_ * NH_ * 49 * HD_ * 4);
    ushort_t* xbf  = xcat;
    ushort_t* catb = xcat;
    // osp/mls alias kvl (consumed by local_mean before attention runs)
    float* osp = kvl;                                   // 2*B*N*64 floats
    float* mls = kvl + (size_t)2 * B_ * N_ * 64;        // 2*B*N*2 floats

    const int M = B_ * N_;   // 25088

    // 0. weight converts + x -> bf16
    convw_kernel<<<512 * 512 / 256, 256, 0, stream>>>(Wq, wqt, 512, 512, 1);
    convw_kernel<<<512 * 448 / 256, 256, 0, stream>>>(kvl_pw, pwt, 448, 448, 0);
    convw_kernel<<<512 * 512 / 256, 256, 0, stream>>>(proj_w, projt, 512, 512, 1);
    convx_kernel<<<(B_ * N_ * DIM_ / 8) / 256, 256, 0, stream>>>(x, xbf);

    // 1. q = x @ Wq   (bf16 MFMA)
    gemm_bf16_kernel<false><<<dim3(M / 128, 4), 256, 0, stream>>>(
        xbf, wqt, nullptr, q, 512, 512, 512);

    // 2. depthwise on x_l -> dwtb (bf16)
    dwt_kernel<<<(B_ * N_ * DL_) / 256, 256, 0, stream>>>(x, kvl_dw, kvl_db, dwtb);

    // 3. pointwise: kvl = dwtb @ pwt^T + pb
    gemm_bf16_kernel<true><<<dim3(M / 128, 4), 256, 0, stream>>>(
        dwtb, pwt, kvl_pb, kvl, 448, 448, 448);

    // 4. global branch: sr conv + LN + kv (K as bf16)
    srlnkv_kernel<<<B_ * NR_, 64, 0, stream>>>(x, sr_w, sr_b, ln_g, ln_b, Wkv_g, kgb, vg);

    // 5. vg2 = vg + depthwise(vg); then transpose+convert to vtb
    lcg_kernel<<<(B_ * NR_ * 64) / 256, 256, 0, stream>>>(vg, lcg_w, lcg_b, vg2);
    vtrans_kernel<<<dim3(NR_ / 64, B_), 256, 0, stream>>>(vg2, vtb);

    // 7-9. local branch pipeline (consumes kvl BEFORE osp aliases it)
    {
        int tot = B_ * NH_ * 49 * HD_;
        int blocks = (tot + 255) / 256;
        local_mean_kernel<<<blocks, 256, 0, stream>>>(kvl, kvm1, 256, 16, 7, 1, 0);
        local_mean_kernel<<<blocks, 256, 0, stream>>>(kvl, kvm2, 81, 9, 13, 2, 224);
        fcsh_kernel<<<B_ * NH_, 64, 0, stream>>>(kvm1, fc1_w, sh1_w, kv1);
        fcsh_kernel<<<B_ * NH_, 64, 0, stream>>>(kvm2, fc2_w, sh2_w, kv2);
        vconv_kernel<<<blocks, 256, 0, stream>>>(kv1, lc1_w, lc1_b, v1c);
        vconv_kernel<<<blocks, 256, 0, stream>>>(kv2, lc2_w, lc2_b, v2c);
    }

    // 6. global flash attention, split-K=2 -> combine into catb cols [0,64)
    attn_global_split<<<dim3(N_ / 32, B_ * 2), 128, 0, stream>>>(q, kgb, vtb, osp, mls);
    attn_combine<<<(B_ * N_ * 64) / 256, 256, 0, stream>>>(osp, mls, catb);

    // 10. local attention -> catb cols [64,288) and [288,512)
    attn_local_kernel<<<dim3(N_ / 256, B_ * NH_), 256, 0, stream>>>(
        q, kv1, v1c, catb, D0_, D0_);
    attn_local_kernel<<<dim3(N_ / 256, B_ * NH_), 256, 0, stream>>>(
        q, kv2, v2c, catb, D0_ + HD_, D0_ + 224);

    // 11. out = catb @ projt^T + proj_b
    gemm_bf16_kernel<true><<<dim3(M / 128, 4), 256, 0, stream>>>(
        catb, projt, proj_b, out, 512, 512, 512);
}

// Round 5
// 531.372 us; speedup vs baseline: 5.4815x; 1.1165x over previous
//
#include <hip/hip_runtime.h>
#include <hip/hip_bf16.h>
#include <math.h>
#include <stdint.h>

// ---- problem constants ----
static constexpr int B_    = 2;
static constexpr int N_    = 12544;   // 112*112
static constexpr int DIM_  = 512;
static constexpr int D0_   = 64;
static constexpr int DL_   = 448;
static constexpr int Himg  = 112;
static constexpr int Wimg  = 112;
static constexpr int HS_   = 56;
static constexpr int NR_   = 3136;    // 56*56
static constexpr int NH_   = 8;
static constexpr int HD_   = 28;

typedef unsigned short ushort_t;
typedef __attribute__((ext_vector_type(8))) short short8_t;
typedef __attribute__((ext_vector_type(4))) float float4v;
typedef __attribute__((ext_vector_type(4))) unsigned uint4v;
typedef __attribute__((ext_vector_type(2))) unsigned uint2v;

// round-to-nearest-even f32 -> bf16
static __device__ inline ushort_t bf16r(float x) {
    unsigned u = __builtin_bit_cast(unsigned, x);
    u = (u + 0x7FFFu + ((u >> 16) & 1u)) >> 16;
    return (ushort_t)u;
}
// pack two f32 -> u32 of 2 bf16 (lo, hi)
static __device__ inline unsigned pack_bf16(float lo, float hi) {
    unsigned a = __builtin_bit_cast(unsigned, lo);
    unsigned b = __builtin_bit_cast(unsigned, hi);
    a = (a + 0x7FFFu + ((a >> 16) & 1u)) >> 16;
    b = (b + 0x7FFFu + ((b >> 16) & 1u)) >> 16;
    return a | (b << 16);
}

using gptr_t = const __attribute__((address_space(1))) void*;
using lptr_t = __attribute__((address_space(3))) void*;
static __device__ inline void gload16(const void* g, void* l) {
    __builtin_amdgcn_global_load_lds((gptr_t)(uintptr_t)g, (lptr_t)(uintptr_t)l, 16, 0, 0);
}

// =====================================================================
// bf16 MFMA GEMM: C[M][ldc] (fp32) = A[M][K](bf16) @ Bt[Npad][K](bf16)^T
// 128x128 tile, BK=64, 256 threads (4 waves in 2x2), single-buffer loop.
// =====================================================================
template<bool HASBIAS>
__global__ __launch_bounds__(256, 2)
void gemm_bf16_kernel(const ushort_t* __restrict__ A,
                      const ushort_t* __restrict__ Bt,
                      const float* __restrict__ bias,
                      float* __restrict__ C,
                      int Nn, int K, int ldc) {
    constexpr int BM = 128, BK = 64;
    __shared__ __align__(16) ushort_t As[BM * BK];
    __shared__ __align__(16) ushort_t Bs[BM * BK];
    const int bm = blockIdx.x * BM;
    const int bn = blockIdx.y * BM;
    const int tid = threadIdx.x;
    const int l15 = tid & 15;
    const int g   = (tid & 63) >> 4;
    const int w   = tid >> 6;
    const int wr  = w >> 1, wc = w & 1;

    float4v acc[4][4];
    #pragma unroll
    for (int m = 0; m < 4; ++m)
        #pragma unroll
        for (int n = 0; n < 4; ++n) acc[m][n] = (float4v){0.f, 0.f, 0.f, 0.f};

    for (int k0 = 0; k0 < K; k0 += BK) {
        #pragma unroll
        for (int i = 0; i < 4; ++i) {
            int c = i * 256 + tid;
            int r = c >> 3, ch = c & 7;
            int sch = ch ^ (r & 7);
            gload16(A  + (size_t)(bm + r) * K + k0 + sch * 8, (void*)(As + c * 8));
            gload16(Bt + (size_t)(bn + r) * K + k0 + sch * 8, (void*)(Bs + c * 8));
        }
        __syncthreads();

        short8_t af[4][2], bfr[4][2];
        #pragma unroll
        for (int m = 0; m < 4; ++m) {
            int ar = wr * 64 + m * 16 + l15;
            #pragma unroll
            for (int h = 0; h < 2; ++h)
                af[m][h] = *(const short8_t*)((const char*)As + ar * 128 + (((h * 4 + g) ^ (ar & 7)) * 16));
        }
        #pragma unroll
        for (int n = 0; n < 4; ++n) {
            int br = wc * 64 + n * 16 + l15;
            #pragma unroll
            for (int h = 0; h < 2; ++h)
                bfr[n][h] = *(const short8_t*)((const char*)Bs + br * 128 + (((h * 4 + g) ^ (br & 7)) * 16));
        }
        #pragma unroll
        for (int m = 0; m < 4; ++m)
            #pragma unroll
            for (int n = 0; n < 4; ++n) {
                acc[m][n] = __builtin_amdgcn_mfma_f32_16x16x32_bf16(af[m][0], bfr[n][0], acc[m][n], 0, 0, 0);
                acc[m][n] = __builtin_amdgcn_mfma_f32_16x16x32_bf16(af[m][1], bfr[n][1], acc[m][n], 0, 0, 0);
            }
        __syncthreads();
    }

    #pragma unroll
    for (int n = 0; n < 4; ++n) {
        int ccol = bn + wc * 64 + n * 16 + l15;
        if (ccol < Nn) {
            float bv = HASBIAS ? bias[ccol] : 0.f;
            #pragma unroll
            for (int m = 0; m < 4; ++m) {
                int crow = bm + wr * 64 + m * 16 + g * 4;
                #pragma unroll
                for (int j = 0; j < 4; ++j)
                    C[(size_t)(crow + j) * ldc + ccol] = acc[m][n][j] + bv;
            }
        }
    }
}

// =====================================================================
// weight convert: Wt[Npad][K] bf16 from W (transpose? W[K][Nn] : W[Nn][K])
// =====================================================================
__global__ __launch_bounds__(256)
void convw_kernel(const float* __restrict__ W, ushort_t* __restrict__ Wt,
                  int K, int Nn, int transpose) {
    int idx = blockIdx.x * 256 + threadIdx.x;
    int n = idx / K, k = idx % K;
    float v = 0.f;
    if (n < Nn) v = transpose ? W[(size_t)k * Nn + n] : W[(size_t)n * K + k];
    Wt[idx] = bf16r(v);
}

// fp32 -> bf16 bulk convert, 8 elems/thread
__global__ __launch_bounds__(256)
void convx_kernel(const float* __restrict__ in, ushort_t* __restrict__ outp) {
    int i = blockIdx.x * 256 + threadIdx.x;
    const float4v* p = (const float4v*)(in + (size_t)i * 8);
    float4v a = p[0], b = p[1];
    uint4v u;
    u[0] = pack_bf16(a[0], a[1]);
    u[1] = pack_bf16(a[2], a[3]);
    u[2] = pack_bf16(b[0], b[1]);
    u[3] = pack_bf16(b[2], b[3]);
    *(uint4v*)(outp + (size_t)i * 8) = u;
}

// =====================================================================
// sr-conv (2x2 stride2, 64->64) + LayerNorm(64) + kv GEMM (64->128)
// K output written as bf16 (attention-ready); V stays fp32 (lcg input)
// =====================================================================
__global__ __launch_bounds__(64)
void srlnkv_kernel(const float* __restrict__ x,
                   const float* __restrict__ sr_w, const float* __restrict__ sr_b,
                   const float* __restrict__ ln_g, const float* __restrict__ ln_b,
                   const float* __restrict__ wkv,
                   ushort_t* __restrict__ kgb, float* __restrict__ vg) {
    const int pos = blockIdx.x;              // b*NR + n
    const int b = pos / NR_, n = pos % NR_;
    const int y = n / HS_, xx = n % HS_;
    const int o = threadIdx.x;               // 0..63
    __shared__ float xs[4][64];
    __shared__ float lnv_s[64];
    #pragma unroll
    for (int tap = 0; tap < 4; ++tap) {
        int ky = tap / 2, kx = tap % 2;
        xs[tap][o] = x[((size_t)b * N_ + (2 * y + ky) * Wimg + 2 * xx + kx) * DIM_ + o];
    }
    __syncthreads();
    float sum = sr_b[o];
    for (int i = 0; i < 64; ++i) {
        const float* w = sr_w + o * 256 + i * 4;
        sum += xs[0][i] * w[0] + xs[1][i] * w[1] + xs[2][i] * w[2] + xs[3][i] * w[3];
    }
    float m = sum;
    #pragma unroll
    for (int off = 1; off < 64; off <<= 1) m += __shfl_xor(m, off);
    m *= (1.0f / 64.0f);
    float d = sum - m;
    float v = d * d;
    #pragma unroll
    for (int off = 1; off < 64; off <<= 1) v += __shfl_xor(v, off);
    v *= (1.0f / 64.0f);
    float lnv = d * rsqrtf(v + 1e-5f) * ln_g[o] + ln_b[o];
    lnv_s[o] = lnv;
    __syncthreads();
    float s0 = 0.f, s1 = 0.f;
    for (int i = 0; i < 64; ++i) {
        float lv = lnv_s[i];
        s0 += lv * wkv[i * 128 + o];
        s1 += lv * wkv[i * 128 + o + 64];
    }
    kgb[((size_t)b * NR_ + n) * 64 + o] = bf16r(s0);
    vg[((size_t)b * NR_ + n) * 64 + o] = s1;
}

// =====================================================================
// depthwise 3x3 + bias on v_g image; vg2 = vg + conv (fp32)
// =====================================================================
__global__ __launch_bounds__(256)
void lcg_kernel(const float* __restrict__ vg, const float* __restrict__ w,
                const float* __restrict__ bias, float* __restrict__ vg2) {
    int idx = blockIdx.x * 256 + threadIdx.x;
    if (idx >= B_ * NR_ * 64) return;
    int c = idx % 64;
    int n = (idx / 64) % NR_;
    int b = idx / (64 * NR_);
    int y = n / HS_, xx = n % HS_;
    float sum = vg[idx] + bias[c];
    #pragma unroll
    for (int ky = 0; ky < 3; ++ky)
        #pragma unroll
        for (int kx = 0; kx < 3; ++kx) {
            int yy = y + ky - 1, x2 = xx + kx - 1;
            if (yy >= 0 && yy < HS_ && x2 >= 0 && x2 < HS_)
                sum += vg[((size_t)b * NR_ + yy * HS_ + x2) * 64 + c] * w[c * 9 + ky * 3 + kx];
        }
    vg2[idx] = sum;
}

// =====================================================================
// transpose+convert: vg2 fp32 [B][NR][64] -> vtb bf16 [B][64][NR]
// =====================================================================
__global__ __launch_bounds__(256)
void vtrans_kernel(const float* __restrict__ vg2, ushort_t* __restrict__ vtb) {
    __shared__ float ld[64][65];
    const int b = blockIdx.y, n0 = blockIdx.x * 64, tid = threadIdx.x;
    #pragma unroll
    for (int i = 0; i < 16; ++i) {
        int idx = i * 256 + tid;
        int n = idx >> 6, c = idx & 63;
        ld[n][c] = vg2[((size_t)b * NR_ + n0 + n) * 64 + c];
    }
    __syncthreads();
    #pragma unroll
    for (int i = 0; i < 16; ++i) {
        int idx = i * 256 + tid;
        int d = idx >> 6, nn = idx & 63;
        vtb[(size_t)(b * 64 + d) * NR_ + n0 + nn] = bf16r(ld[nn][d]);
    }
}

// =====================================================================
// Global-branch flash attention, split-K (2 splits), bf16 MFMA.
// =====================================================================
__global__ __launch_bounds__(128)
void attn_global_split(const float* __restrict__ q,
                       const ushort_t* __restrict__ kgb,
                       const ushort_t* __restrict__ vtb,
                       float* __restrict__ osp, float* __restrict__ mls) {
    __shared__ __align__(16) ushort_t Ks[64 * 64];
    __shared__ __align__(16) ushort_t Vs[64 * 64];
    __shared__ __align__(16) unsigned Pu[1024];    // 2 waves x 16 rows x 32 u32
    const int split = blockIdx.y & 1;
    const int b     = blockIdx.y >> 1;
    const int q0    = blockIdx.x * 32;
    const int tid   = threadIdx.x;
    const int w     = tid >> 6;
    const int l     = tid & 63;
    const int l15   = l & 15;
    const int g     = l >> 4;
    const int lx    = l15 & 7;

    short8_t qf[2];
    {
        const float* qrow = q + ((size_t)b * N_ + q0 + w * 16 + l15) * DIM_;
        #pragma unroll
        for (int dc = 0; dc < 2; ++dc) {
            const float4v* p4 = (const float4v*)(qrow + g * 8 + 32 * dc);
            float4v x0 = p4[0], x1 = p4[1];
            uint4v uv;
            uv[0] = pack_bf16(x0[0], x0[1]);
            uv[1] = pack_bf16(x0[2], x0[3]);
            uv[2] = pack_bf16(x1[0], x1[1]);
            uv[3] = pack_bf16(x1[2], x1[3]);
            qf[dc] = __builtin_bit_cast(short8_t, uv);
        }
    }

    float4v o[4];
    #pragma unroll
    for (int i = 0; i < 4; ++i) o[i] = (float4v){0.f, 0.f, 0.f, 0.f};
    float m_run = -3.0e38f, l_run = 0.f;

    const int t0 = split ? 25 : 0;
    const int t1 = split ? 49 : 25;
    for (int t = t0; t < t1; ++t) {
        const int k0 = t * 64;
        #pragma unroll
        for (int i = 0; i < 4; ++i) {
            int c = i * 128 + tid;          // 0..511
            int r = c >> 3, ch = c & 7;
            int sch = ch ^ (r & 7);
            gload16(kgb + ((size_t)(b * NR_ + k0 + r) << 6) + sch * 8, (void*)(Ks + c * 8));
            gload16(vtb + (size_t)(b * 64 + r) * NR_ + k0 + sch * 8, (void*)(Vs + c * 8));
        }
        __syncthreads();

        float4v sc[4];
        #pragma unroll
        for (int c = 0; c < 4; ++c) {
            float4v acc = (float4v){0.f, 0.f, 0.f, 0.f};
            #pragma unroll
            for (int dc = 0; dc < 2; ++dc) {
                int row = c * 16 + l15;
                short8_t ak = *(const short8_t*)((const char*)Ks + row * 128 + (((g + 4 * dc) ^ lx) * 16));
                acc = __builtin_amdgcn_mfma_f32_16x16x32_bf16(ak, qf[dc], acc, 0, 0, 0);
            }
            sc[c] = acc;
        }

        float tmax = -3.0e38f;
        #pragma unroll
        for (int c = 0; c < 4; ++c)
            #pragma unroll
            for (int r = 0; r < 4; ++r) {
                sc[c][r] *= 0.125f;
                tmax = fmaxf(tmax, sc[c][r]);
            }
        tmax = fmaxf(tmax, __shfl_xor(tmax, 16));
        tmax = fmaxf(tmax, __shfl_xor(tmax, 32));
        float m_new = fmaxf(m_run, tmax);
        float corr = __expf(m_run - m_new);
        float p[4][4];
        float ladd = 0.f;
        #pragma unroll
        for (int c = 0; c < 4; ++c)
            #pragma unroll
            for (int r = 0; r < 4; ++r) {
                float pe = __expf(sc[c][r] - m_new);
                p[c][r] = pe;
                ladd += pe;
            }
        ladd += __shfl_xor(ladd, 16);
        ladd += __shfl_xor(ladd, 32);
        l_run = l_run * corr + ladd;
        m_run = m_new;

        {
            unsigned* Pw = Pu + w * 512 + l15 * 32;
            #pragma unroll
            for (int c = 0; c < 4; ++c) {
                int u32i = 8 * c + 2 * g;
                int usw = (((u32i >> 2) ^ lx) << 2) | (u32i & 3);
                Pw[usw]     = pack_bf16(p[c][0], p[c][1]);
                Pw[usw + 1] = pack_bf16(p[c][2], p[c][3]);
            }
        }

        float co[4];
        #pragma unroll
        for (int r = 0; r < 4; ++r) co[r] = __shfl(corr, g * 4 + r);
        #pragma unroll
        for (int dc = 0; dc < 4; ++dc)
            #pragma unroll
            for (int r = 0; r < 4; ++r) o[dc][r] *= co[r];

        #pragma unroll
        for (int kkc = 0; kkc < 2; ++kkc) {
            short8_t ap = *(const short8_t*)((const char*)Pu + w * 2048 + l15 * 128 + (((kkc * 4 + g) ^ lx) * 16));
            #pragma unroll
            for (int dc = 0; dc < 4; ++dc) {
                int vrow = dc * 16 + l15;
                short8_t bv = *(const short8_t*)((const char*)Vs + vrow * 128 + (((kkc * 4 + g) ^ lx) * 16));
                o[dc] = __builtin_amdgcn_mfma_f32_16x16x32_bf16(ap, bv, o[dc], 0, 0, 0);
            }
        }
        __syncthreads();
    }

    const size_t rbase = (size_t)(split * B_ + b) * N_;
    #pragma unroll
    for (int dc = 0; dc < 4; ++dc)
        #pragma unroll
        for (int r = 0; r < 4; ++r) {
            int row = q0 + w * 16 + g * 4 + r;
            osp[(rbase + row) * 64 + dc * 16 + l15] = o[dc][r];
        }
    if (l < 16) {
        int row = q0 + w * 16 + l15;
        mls[(rbase + row) * 2]     = m_run;
        mls[(rbase + row) * 2 + 1] = l_run;
    }
}

// =====================================================================
// combine the 2 splits -> catb cols [0,64)
// =====================================================================
__global__ __launch_bounds__(256)
void attn_combine(const float* __restrict__ osp, const float* __restrict__ mls,
                  ushort_t* __restrict__ catb) {
    int idx = blockIdx.x * 256 + threadIdx.x;   // B*N*64
    int col = idx & 63;
    size_t rn = (size_t)(idx >> 6);             // b*N + row
    size_t base0 = rn, base1 = rn + (size_t)B_ * N_;
    float m0 = mls[base0 * 2], l0 = mls[base0 * 2 + 1];
    float m1 = mls[base1 * 2], l1 = mls[base1 * 2 + 1];
    float m = fmaxf(m0, m1);
    float w0 = __expf(m0 - m), w1 = __expf(m1 - m);
    float linv = 1.f / (l0 * w0 + l1 * w1);
    float v = (osp[base0 * 64 + col] * w0 + osp[base1 * 64 + col] * w1) * linv;
    catb[rn * DIM_ + col] = bf16r(v);
}

// =====================================================================
// depthwise 3x3 + bias on x_l, vectorized: 4 channels x 4 y-rows / thread
// out bf16 (B,N,448). idx = ((b*28 + yg)*112 + xx)*112 + c4
// =====================================================================
__global__ __launch_bounds__(256)
void dwt_kernel(const float* __restrict__ x, const float* __restrict__ w,
                const float* __restrict__ bias, ushort_t* __restrict__ out) {
    int idx = blockIdx.x * 256 + threadIdx.x;
    int c4 = idx % 112;
    int t1 = idx / 112;
    int xx = t1 % 112;
    int t2 = t1 / 112;
    int yg = t2 % 28;
    int b  = t2 / 28;
    int c0 = c4 * 4;
    int y0 = yg * 4;

    // weights: w4[kt][j] = w[(c0+j)*9 + kt]
    float4v w4[9];
    #pragma unroll
    for (int kt = 0; kt < 9; ++kt) {
        w4[kt][0] = w[(c0 + 0) * 9 + kt];
        w4[kt][1] = w[(c0 + 1) * 9 + kt];
        w4[kt][2] = w[(c0 + 2) * 9 + kt];
        w4[kt][3] = w[(c0 + 3) * 9 + kt];
    }
    float4v bv = *(const float4v*)(bias + c0);
    float4v acc[4];
    #pragma unroll
    for (int o2 = 0; o2 < 4; ++o2) acc[o2] = bv;

    #pragma unroll
    for (int yy = 0; yy < 6; ++yy) {
        int Y = y0 - 1 + yy;
        if (Y < 0 || Y >= Himg) continue;
        #pragma unroll
        for (int xt = 0; xt < 3; ++xt) {
            int X = xx - 1 + xt;
            if (X < 0 || X >= Wimg) continue;
            float4v v = *(const float4v*)(x + ((size_t)b * N_ + Y * Wimg + X) * DIM_ + D0_ + c0);
            constexpr int olo_t[6] = {0, 0, 0, 1, 2, 3};
            constexpr int ohi_t[6] = {0, 1, 2, 3, 3, 3};
            #pragma unroll
            for (int o2 = olo_t[yy]; o2 <= ohi_t[yy]; ++o2) {
                float4v wv = w4[(yy - o2) * 3 + xt];
                acc[o2][0] += v[0] * wv[0];
                acc[o2][1] += v[1] * wv[1];
                acc[o2][2] += v[2] * wv[2];
                acc[o2][3] += v[3] * wv[3];
            }
        }
    }
    #pragma unroll
    for (int o2 = 0; o2 < 4; ++o2) {
        uint2v pk;
        pk[0] = pack_bf16(acc[o2][0], acc[o2][1]);
        pk[1] = pack_bf16(acc[o2][2], acc[o2][3]);
        *(uint2v*)(out + ((size_t)b * N_ + (y0 + o2) * Wimg + xx) * DL_ + c0) = pk;
    }
}

// =====================================================================
// "scrambled mean" (reads fp32 kvl)
// =====================================================================
__global__ __launch_bounds__(256)
void local_mean_kernel(const float* __restrict__ kvl, float* __restrict__ kvm,
                       int L, int nBW, int stride, int dil, int choff) {
    int idx = blockIdx.x * 256 + threadIdx.x;
    if (idx >= B_ * NH_ * 49 * HD_) return;
    int d2 = idx % HD_;
    int n  = (idx / HD_) % 49;
    int h  = (idx / (HD_ * 49)) % NH_;
    int b  = idx / (HD_ * 49 * NH_);
    int wy = n / 7, wx = n % 7;
    float sum = 0.f;
    int f0 = d2 * L;
    for (int l2 = 0; l2 < L; ++l2) {
        int f = f0 + l2;
        int l = f / HD_;
        int d = f - l * HD_;
        int by = l / nBW, bx = l % nBW;
        int Y = by * stride + dil * wy;
        int X = bx * stride + dil * wx;
        if (Y >= Himg) Y = 2 * Himg - 2 - Y;   // reflect
        if (X >= Wimg) X = 2 * Wimg - 2 - X;
        sum += kvl[((size_t)b * N_ + Y * Wimg + X) * DL_ + choff + h * HD_ + d];
    }
    kvm[idx] = sum * (1.0f / (float)L);
}

// =====================================================================
// kv = kvm @ fc_w @ sh_w -> (B*NH, 49, 56)
// =====================================================================
__global__ __launch_bounds__(64)
void fcsh_kernel(const float* __restrict__ kvm, const float* __restrict__ fcw,
                 const float* __restrict__ shw, float* __restrict__ out) {
    int bh = blockIdx.x;
    __shared__ float kin[49][28];
    __shared__ float tmp[49][28];
    __shared__ float fw[28 * 28];
    __shared__ float sw[28 * 56];
    int t = threadIdx.x;
    for (int i = t; i < 49 * 28; i += 64) kin[i / 28][i % 28] = kvm[bh * 49 * 28 + i];
    for (int i = t; i < 28 * 28; i += 64) fw[i] = fcw[i];
    for (int i = t; i < 28 * 56; i += 64) sw[i] = shw[i];
    __syncthreads();
    for (int i = t; i < 49 * 28; i += 64) {
        int rr = i / 28, j = i % 28;
        float s = 0.f;
        for (int k = 0; k < 28; ++k) s += kin[rr][k] * fw[k * 28 + j];
        tmp[rr][j] = s;
    }
    __syncthreads();
    for (int i = t; i < 49 * 56; i += 64) {
        int rr = i / 56, j = i % 56;
        float s = 0.f;
        for (int k = 0; k < 28; ++k) s += tmp[rr][k] * sw[k * 56 + j];
        out[bh * 49 * 56 + i] = s;
    }
}

// =====================================================================
// v_ + depthwise3x3(v_img 7x7) + bias -> vc (B*NH, 49, 28)
// =====================================================================
__global__ __launch_bounds__(256)
void vconv_kernel(const float* __restrict__ kvsh, const float* __restrict__ w,
                  const float* __restrict__ bias, float* __restrict__ vc) {
    int idx = blockIdx.x * 256 + threadIdx.x;
    if (idx >= B_ * NH_ * 49 * HD_) return;
    int d  = idx % HD_;
    int n  = (idx / HD_) % 49;
    int bh = idx / (HD_ * 49);
    int h  = bh % NH_;
    int y = n / 7, xx = n % 7;
    int c = h * HD_ + d;
    float sum = kvsh[(bh * 49 + n) * 56 + 28 + d] + bias[c];
    #pragma unroll
    for (int ky = 0; ky < 3; ++ky)
        #pragma unroll
        for (int kx = 0; kx < 3; ++kx) {
            int yy = y + ky - 1, x2 = xx + kx - 1;
            if (yy >= 0 && yy < 7 && x2 >= 0 && x2 < 7)
                sum += kvsh[(bh * 49 + yy * 7 + x2) * 56 + 28 + d] * w[c * 9 + ky * 3 + kx];
        }
    vc[idx] = sum;
}

// =====================================================================
// local attention: 49 keys, hd=28. one thread per q-row.
// =====================================================================
__global__ __launch_bounds__(256)
void attn_local_kernel(const float* __restrict__ q, const float* __restrict__ kvsh,
                       const float* __restrict__ vc, ushort_t* __restrict__ catb,
                       int qcoloff, int outcoloff) {
    const int bh = blockIdx.y;
    const int b = bh / NH_, h = bh % NH_;
    const int n = blockIdx.x * 256 + threadIdx.x;
    __shared__ float Ks[49][28];
    __shared__ float Vsh[49][28];
    const int t = threadIdx.x;
    for (int i = t; i < 49 * 28; i += 256) {
        int rr = i / 28, d = i % 28;
        Ks[rr][d]  = kvsh[(bh * 49 + rr) * 56 + d];
        Vsh[rr][d] = vc[(bh * 49 + rr) * 28 + d];
    }
    __syncthreads();
    float qr[28];
    {
        const float4v* qp4 = (const float4v*)(q + ((size_t)b * N_ + n) * DIM_ + qcoloff + h * 56);
        #pragma unroll
        for (int i = 0; i < 7; ++i) {
            float4v v = qp4[i];
            qr[i * 4] = v[0]; qr[i * 4 + 1] = v[1]; qr[i * 4 + 2] = v[2]; qr[i * 4 + 3] = v[3];
        }
    }
    const float scale = 0.1889822365046136f;   // 28^-0.5
    float mx = -1e30f;
    for (int k = 0; k < 49; ++k) {
        float s = 0.f;
        #pragma unroll
        for (int d = 0; d < 28; ++d) s += qr[d] * Ks[k][d];
        mx = fmaxf(mx, s * scale);
    }
    float l = 0.f;
    float acc[28] = {};
    for (int k = 0; k < 49; ++k) {
        float s = 0.f;
        #pragma unroll
        for (int d = 0; d < 28; ++d) s += qr[d] * Ks[k][d];
        float p = __expf(s * scale - mx);
        l += p;
        #pragma unroll
        for (int d = 0; d < 28; ++d) acc[d] += p * Vsh[k][d];
    }
    float inv = 1.f / l;
    ushort_t* op = catb + ((size_t)b * N_ + n) * DIM_ + outcoloff + h * HD_;
    #pragma unroll
    for (int d = 0; d < 28; ++d) op[d] = bf16r(acc[d] * inv);
}

// =====================================================================
extern "C" void kernel_launch(void* const* d_in, const int* in_sizes, int n_in,
                              void* d_out, int out_size, void* d_ws, size_t ws_size,
                              hipStream_t stream) {
    const float* x      = (const float*)d_in[0];
    const float* Wq     = (const float*)d_in[1];
    const float* Wkv_g  = (const float*)d_in[2];
    const float* sr_w   = (const float*)d_in[3];
    const float* sr_b   = (const float*)d_in[4];
    const float* ln_g   = (const float*)d_in[5];
    const float* ln_b   = (const float*)d_in[6];
    const float* lcg_w  = (const float*)d_in[7];
    const float* lcg_b  = (const float*)d_in[8];
    const float* kvl_dw = (const float*)d_in[9];
    const float* kvl_db = (const float*)d_in[10];
    const float* kvl_pw = (const float*)d_in[11];
    const float* kvl_pb = (const float*)d_in[12];
    const float* fc1_w  = (const float*)d_in[13];
    const float* sh1_w  = (const float*)d_in[14];
    const float* lc1_w  = (const float*)d_in[15];
    const float* lc1_b  = (const float*)d_in[16];
    const float* fc2_w  = (const float*)d_in[17];
    const float* sh2_w  = (const float*)d_in[18];
    const float* lc2_w  = (const float*)d_in[19];
    const float* lc2_b  = (const float*)d_in[20];
    const float* proj_w = (const float*)d_in[21];
    const float* proj_b = (const float*)d_in[22];
    float* out = (float*)d_out;
    char* base = (char*)d_ws;

    // ---- workspace layout (256B aligned) ----
    size_t o = 0;
    auto alloc = [&](size_t bytes) -> void* {
        void* p = base + o;
        o = (o + bytes + 255) & ~(size_t)255;
        return p;
    };
    float*    q     = (float*)   alloc((size_t)B_ * N_ * DIM_ * 4);
    float*    kvl   = (float*)   alloc((size_t)B_ * N_ * DL_ * 4);   // later osp+mls
    ushort_t* xcat  = (ushort_t*)alloc((size_t)B_ * N_ * DIM_ * 2);  // xbf, then cat
    ushort_t* dwtb  = (ushort_t*)alloc((size_t)B_ * N_ * DL_ * 2);
    ushort_t* kgb   = (ushort_t*)alloc((size_t)B_ * NR_ * 64 * 2);
    float*    vg    = (float*)   alloc((size_t)B_ * NR_ * 64 * 4);
    float*    vg2   = (float*)   alloc((size_t)B_ * NR_ * 64 * 4);
    ushort_t* vtb   = (ushort_t*)alloc((size_t)B_ * 64 * NR_ * 2);
    ushort_t* wqt   = (ushort_t*)alloc((size_t)512 * 512 * 2);
    ushort_t* pwt   = (ushort_t*)alloc((size_t)512 * 448 * 2);
    ushort_t* projt = (ushort_t*)alloc((size_t)512 * 512 * 2);
    float*    kvm1  = (float*)   alloc((size_t)B_ * NH_ * 49 * HD_ * 4);
    float*    kvm2  = (float*)   alloc((size_t)B_ * NH_ * 49 * HD_ * 4);
    float*    kv1   = (float*)   alloc((size_t)B_ * NH_ * 49 * 56 * 4);
    float*    kv2   = (float*)   alloc((size_t)B_ * NH_ * 49 * 56 * 4);
    float*    v1c   = (float*)   alloc((size_t)B_ * NH_ * 49 * HD_ * 4);
    float*    v2c   = (float*)   alloc((size_t)B_ * NH_ * 49 * HD_ * 4);
    ushort_t* xbf  = xcat;
    ushort_t* catb = xcat;
    float* osp = kvl;                                   // 2*B*N*64 floats
    float* mls = kvl + (size_t)2 * B_ * N_ * 64;        // 2*B*N*2 floats

    const int M = B_ * N_;   // 25088

    // 0. weight converts + x -> bf16
    convw_kernel<<<512 * 512 / 256, 256, 0, stream>>>(Wq, wqt, 512, 512, 1);
    convw_kernel<<<512 * 448 / 256, 256, 0, stream>>>(kvl_pw, pwt, 448, 448, 0);
    convw_kernel<<<512 * 512 / 256, 256, 0, stream>>>(proj_w, projt, 512, 512, 1);
    convx_kernel<<<(B_ * N_ * DIM_ / 8) / 256, 256, 0, stream>>>(x, xbf);

    // 1. q = x @ Wq   (bf16 MFMA)
    gemm_bf16_kernel<false><<<dim3(M / 128, 4), 256, 0, stream>>>(
        xbf, wqt, nullptr, q, 512, 512, 512);

    // 2. depthwise on x_l -> dwtb (bf16), 4ch x 4row per thread
    dwt_kernel<<<(B_ * 28 * 112 * 112) / 256, 256, 0, stream>>>(x, kvl_dw, kvl_db, dwtb);

    // 3. pointwise: kvl = dwtb @ pwt^T + pb
    gemm_bf16_kernel<true><<<dim3(M / 128, 4), 256, 0, stream>>>(
        dwtb, pwt, kvl_pb, kvl, 448, 448, 448);

    // 4. global branch: sr conv + LN + kv (K as bf16)
    srlnkv_kernel<<<B_ * NR_, 64, 0, stream>>>(x, sr_w, sr_b, ln_g, ln_b, Wkv_g, kgb, vg);

    // 5. vg2 = vg + depthwise(vg); then transpose+convert to vtb
    lcg_kernel<<<(B_ * NR_ * 64) / 256, 256, 0, stream>>>(vg, lcg_w, lcg_b, vg2);
    vtrans_kernel<<<dim3(NR_ / 64, B_), 256, 0, stream>>>(vg2, vtb);

    // 7-9. local branch pipeline (consumes kvl BEFORE osp aliases it)
    {
        int tot = B_ * NH_ * 49 * HD_;
        int blocks = (tot + 255) / 256;
        local_mean_kernel<<<blocks, 256, 0, stream>>>(kvl, kvm1, 256, 16, 7, 1, 0);
        local_mean_kernel<<<blocks, 256, 0, stream>>>(kvl, kvm2, 81, 9, 13, 2, 224);
        fcsh_kernel<<<B_ * NH_, 64, 0, stream>>>(kvm1, fc1_w, sh1_w, kv1);
        fcsh_kernel<<<B_ * NH_, 64, 0, stream>>>(kvm2, fc2_w, sh2_w, kv2);
        vconv_kernel<<<blocks, 256, 0, stream>>>(kv1, lc1_w, lc1_b, v1c);
        vconv_kernel<<<blocks, 256, 0, stream>>>(kv2, lc2_w, lc2_b, v2c);
    }

    // 6. global flash attention, split-K=2 -> combine into catb cols [0,64)
    attn_global_split<<<dim3(N_ / 32, B_ * 2), 128, 0, stream>>>(q, kgb, vtb, osp, mls);
    attn_combine<<<(B_ * N_ * 64) / 256, 256, 0, stream>>>(osp, mls, catb);

    // 10. local attention -> catb cols [64,288) and [288,512)
    attn_local_kernel<<<dim3(N_ / 256, B_ * NH_), 256, 0, stream>>>(
        q, kv1, v1c, catb, D0_, D0_);
    attn_local_kernel<<<dim3(N_ / 256, B_ * NH_), 256, 0, stream>>>(
        q, kv2, v2c, catb, D0_ + HD_, D0_ + 224);

    // 11. out = catb @ projt^T + proj_b
    gemm_bf16_kernel<true><<<dim3(M / 128, 4), 256, 0, stream>>>(
        catb, projt, proj_b, out, 512, 512, 512);
}

// Round 6
// 436.825 us; speedup vs baseline: 6.6679x; 1.2164x over previous
//
#include <hip/hip_runtime.h>
#include <hip/hip_bf16.h>
#include <math.h>
#include <stdint.h>

// ---- problem constants ----
static constexpr int B_    = 2;
static constexpr int N_    = 12544;   // 112*112
static constexpr int DIM_  = 512;
static constexpr int D0_   = 64;
static constexpr int DL_   = 448;
static constexpr int Himg  = 112;
static constexpr int Wimg  = 112;
static constexpr int HS_   = 56;
static constexpr int NR_   = 3136;    // 56*56
static constexpr int NH_   = 8;
static constexpr int HD_   = 28;

typedef unsigned short ushort_t;
typedef __attribute__((ext_vector_type(8))) short short8_t;
typedef __attribute__((ext_vector_type(4))) float float4v;
typedef __attribute__((ext_vector_type(4))) unsigned uint4v;
typedef __attribute__((ext_vector_type(2))) unsigned uint2v;

// round-to-nearest-even f32 -> bf16
static __device__ inline ushort_t bf16r(float x) {
    unsigned u = __builtin_bit_cast(unsigned, x);
    u = (u + 0x7FFFu + ((u >> 16) & 1u)) >> 16;
    return (ushort_t)u;
}
// pack two f32 -> u32 of 2 bf16 (lo, hi)
static __device__ inline unsigned pack_bf16(float lo, float hi) {
    unsigned a = __builtin_bit_cast(unsigned, lo);
    unsigned b = __builtin_bit_cast(unsigned, hi);
    a = (a + 0x7FFFu + ((a >> 16) & 1u)) >> 16;
    b = (b + 0x7FFFu + ((b >> 16) & 1u)) >> 16;
    return a | (b << 16);
}

using gptr_t = const __attribute__((address_space(1))) void*;
using lptr_t = __attribute__((address_space(3))) void*;
static __device__ inline void gload16(const void* g, void* l) {
    __builtin_amdgcn_global_load_lds((gptr_t)(uintptr_t)g, (lptr_t)(uintptr_t)l, 16, 0, 0);
}

// =====================================================================
// bf16 MFMA GEMM: C[M][ldc] (fp32) = A[M][K](bf16) @ Bt[Npad][K](bf16)^T
// 128x128 tile, BK=64, 256 threads (4 waves in 2x2), single-buffer loop.
// =====================================================================
template<bool HASBIAS>
__global__ __launch_bounds__(256, 2)
void gemm_bf16_kernel(const ushort_t* __restrict__ A,
                      const ushort_t* __restrict__ Bt,
                      const float* __restrict__ bias,
                      float* __restrict__ C,
                      int Nn, int K, int ldc) {
    constexpr int BM = 128, BK = 64;
    __shared__ __align__(16) ushort_t As[BM * BK];
    __shared__ __align__(16) ushort_t Bs[BM * BK];
    const int bm = blockIdx.x * BM;
    const int bn = blockIdx.y * BM;
    const int tid = threadIdx.x;
    const int l15 = tid & 15;
    const int g   = (tid & 63) >> 4;
    const int w   = tid >> 6;
    const int wr  = w >> 1, wc = w & 1;

    float4v acc[4][4];
    #pragma unroll
    for (int m = 0; m < 4; ++m)
        #pragma unroll
        for (int n = 0; n < 4; ++n) acc[m][n] = (float4v){0.f, 0.f, 0.f, 0.f};

    for (int k0 = 0; k0 < K; k0 += BK) {
        #pragma unroll
        for (int i = 0; i < 4; ++i) {
            int c = i * 256 + tid;
            int r = c >> 3, ch = c & 7;
            int sch = ch ^ (r & 7);
            gload16(A  + (size_t)(bm + r) * K + k0 + sch * 8, (void*)(As + c * 8));
            gload16(Bt + (size_t)(bn + r) * K + k0 + sch * 8, (void*)(Bs + c * 8));
        }
        __syncthreads();

        short8_t af[4][2], bfr[4][2];
        #pragma unroll
        for (int m = 0; m < 4; ++m) {
            int ar = wr * 64 + m * 16 + l15;
            #pragma unroll
            for (int h = 0; h < 2; ++h)
                af[m][h] = *(const short8_t*)((const char*)As + ar * 128 + (((h * 4 + g) ^ (ar & 7)) * 16));
        }
        #pragma unroll
        for (int n = 0; n < 4; ++n) {
            int br = wc * 64 + n * 16 + l15;
            #pragma unroll
            for (int h = 0; h < 2; ++h)
                bfr[n][h] = *(const short8_t*)((const char*)Bs + br * 128 + (((h * 4 + g) ^ (br & 7)) * 16));
        }
        #pragma unroll
        for (int m = 0; m < 4; ++m)
            #pragma unroll
            for (int n = 0; n < 4; ++n) {
                acc[m][n] = __builtin_amdgcn_mfma_f32_16x16x32_bf16(af[m][0], bfr[n][0], acc[m][n], 0, 0, 0);
                acc[m][n] = __builtin_amdgcn_mfma_f32_16x16x32_bf16(af[m][1], bfr[n][1], acc[m][n], 0, 0, 0);
            }
        __syncthreads();
    }

    #pragma unroll
    for (int n = 0; n < 4; ++n) {
        int ccol = bn + wc * 64 + n * 16 + l15;
        if (ccol < Nn) {
            float bv = HASBIAS ? bias[ccol] : 0.f;
            #pragma unroll
            for (int m = 0; m < 4; ++m) {
                int crow = bm + wr * 64 + m * 16 + g * 4;
                #pragma unroll
                for (int j = 0; j < 4; ++j)
                    C[(size_t)(crow + j) * ldc + ccol] = acc[m][n][j] + bv;
            }
        }
    }
}

// =====================================================================
// weight convert: Wt[Npad][K] bf16 from W (transpose? W[K][Nn] : W[Nn][K])
// =====================================================================
__global__ __launch_bounds__(256)
void convw_kernel(const float* __restrict__ W, ushort_t* __restrict__ Wt,
                  int K, int Nn, int transpose) {
    int idx = blockIdx.x * 256 + threadIdx.x;
    int n = idx / K, k = idx % K;
    float v = 0.f;
    if (n < Nn) v = transpose ? W[(size_t)k * Nn + n] : W[(size_t)n * K + k];
    Wt[idx] = bf16r(v);
}

// fp32 -> bf16 bulk convert, 8 elems/thread
__global__ __launch_bounds__(256)
void convx_kernel(const float* __restrict__ in, ushort_t* __restrict__ outp) {
    int i = blockIdx.x * 256 + threadIdx.x;
    const float4v* p = (const float4v*)(in + (size_t)i * 8);
    float4v a = p[0], b = p[1];
    uint4v u;
    u[0] = pack_bf16(a[0], a[1]);
    u[1] = pack_bf16(a[2], a[3]);
    u[2] = pack_bf16(b[0], b[1]);
    u[3] = pack_bf16(b[2], b[3]);
    *(uint4v*)(outp + (size_t)i * 8) = u;
}

// =====================================================================
// sr-conv (2x2 stride2, 64->64) + LayerNorm(64) + kv GEMM (64->128)
// =====================================================================
__global__ __launch_bounds__(64)
void srlnkv_kernel(const float* __restrict__ x,
                   const float* __restrict__ sr_w, const float* __restrict__ sr_b,
                   const float* __restrict__ ln_g, const float* __restrict__ ln_b,
                   const float* __restrict__ wkv,
                   ushort_t* __restrict__ kgb, float* __restrict__ vg) {
    const int pos = blockIdx.x;              // b*NR + n
    const int b = pos / NR_, n = pos % NR_;
    const int y = n / HS_, xx = n % HS_;
    const int o = threadIdx.x;               // 0..63
    __shared__ float xs[4][64];
    __shared__ float lnv_s[64];
    #pragma unroll
    for (int tap = 0; tap < 4; ++tap) {
        int ky = tap / 2, kx = tap % 2;
        xs[tap][o] = x[((size_t)b * N_ + (2 * y + ky) * Wimg + 2 * xx + kx) * DIM_ + o];
    }
    __syncthreads();
    float sum = sr_b[o];
    for (int i = 0; i < 64; ++i) {
        const float* w = sr_w + o * 256 + i * 4;
        sum += xs[0][i] * w[0] + xs[1][i] * w[1] + xs[2][i] * w[2] + xs[3][i] * w[3];
    }
    float m = sum;
    #pragma unroll
    for (int off = 1; off < 64; off <<= 1) m += __shfl_xor(m, off);
    m *= (1.0f / 64.0f);
    float d = sum - m;
    float v = d * d;
    #pragma unroll
    for (int off = 1; off < 64; off <<= 1) v += __shfl_xor(v, off);
    v *= (1.0f / 64.0f);
    float lnv = d * rsqrtf(v + 1e-5f) * ln_g[o] + ln_b[o];
    lnv_s[o] = lnv;
    __syncthreads();
    float s0 = 0.f, s1 = 0.f;
    for (int i = 0; i < 64; ++i) {
        float lv = lnv_s[i];
        s0 += lv * wkv[i * 128 + o];
        s1 += lv * wkv[i * 128 + o + 64];
    }
    kgb[((size_t)b * NR_ + n) * 64 + o] = bf16r(s0);
    vg[((size_t)b * NR_ + n) * 64 + o] = s1;
}

// =====================================================================
// depthwise 3x3 + bias on v_g image; vg2 = vg + conv (fp32)
// =====================================================================
__global__ __launch_bounds__(256)
void lcg_kernel(const float* __restrict__ vg, const float* __restrict__ w,
                const float* __restrict__ bias, float* __restrict__ vg2) {
    int idx = blockIdx.x * 256 + threadIdx.x;
    if (idx >= B_ * NR_ * 64) return;
    int c = idx % 64;
    int n = (idx / 64) % NR_;
    int b = idx / (64 * NR_);
    int y = n / HS_, xx = n % HS_;
    float sum = vg[idx] + bias[c];
    #pragma unroll
    for (int ky = 0; ky < 3; ++ky)
        #pragma unroll
        for (int kx = 0; kx < 3; ++kx) {
            int yy = y + ky - 1, x2 = xx + kx - 1;
            if (yy >= 0 && yy < HS_ && x2 >= 0 && x2 < HS_)
                sum += vg[((size_t)b * NR_ + yy * HS_ + x2) * 64 + c] * w[c * 9 + ky * 3 + kx];
        }
    vg2[idx] = sum;
}

// =====================================================================
// transpose+convert: vg2 fp32 [B][NR][64] -> vtb bf16 [B][64][NR]
// =====================================================================
__global__ __launch_bounds__(256)
void vtrans_kernel(const float* __restrict__ vg2, ushort_t* __restrict__ vtb) {
    __shared__ float ld[64][65];
    const int b = blockIdx.y, n0 = blockIdx.x * 64, tid = threadIdx.x;
    #pragma unroll
    for (int i = 0; i < 16; ++i) {
        int idx = i * 256 + tid;
        int n = idx >> 6, c = idx & 63;
        ld[n][c] = vg2[((size_t)b * NR_ + n0 + n) * 64 + c];
    }
    __syncthreads();
    #pragma unroll
    for (int i = 0; i < 16; ++i) {
        int idx = i * 256 + tid;
        int d = idx >> 6, nn = idx & 63;
        vtb[(size_t)(b * 64 + d) * NR_ + n0 + nn] = bf16r(ld[nn][d]);
    }
}

// =====================================================================
// Global-branch flash attention, split-K (2 splits), bf16 MFMA.
// =====================================================================
__global__ __launch_bounds__(128)
void attn_global_split(const float* __restrict__ q,
                       const ushort_t* __restrict__ kgb,
                       const ushort_t* __restrict__ vtb,
                       float* __restrict__ osp, float* __restrict__ mls) {
    __shared__ __align__(16) ushort_t Ks[64 * 64];
    __shared__ __align__(16) ushort_t Vs[64 * 64];
    __shared__ __align__(16) unsigned Pu[1024];    // 2 waves x 16 rows x 32 u32
    const int split = blockIdx.y & 1;
    const int b     = blockIdx.y >> 1;
    const int q0    = blockIdx.x * 32;
    const int tid   = threadIdx.x;
    const int w     = tid >> 6;
    const int l     = tid & 63;
    const int l15   = l & 15;
    const int g     = l >> 4;
    const int lx    = l15 & 7;

    short8_t qf[2];
    {
        const float* qrow = q + ((size_t)b * N_ + q0 + w * 16 + l15) * DIM_;
        #pragma unroll
        for (int dc = 0; dc < 2; ++dc) {
            const float4v* p4 = (const float4v*)(qrow + g * 8 + 32 * dc);
            float4v x0 = p4[0], x1 = p4[1];
            uint4v uv;
            uv[0] = pack_bf16(x0[0], x0[1]);
            uv[1] = pack_bf16(x0[2], x0[3]);
            uv[2] = pack_bf16(x1[0], x1[1]);
            uv[3] = pack_bf16(x1[2], x1[3]);
            qf[dc] = __builtin_bit_cast(short8_t, uv);
        }
    }

    float4v o[4];
    #pragma unroll
    for (int i = 0; i < 4; ++i) o[i] = (float4v){0.f, 0.f, 0.f, 0.f};
    float m_run = -3.0e38f, l_run = 0.f;

    const int t0 = split ? 25 : 0;
    const int t1 = split ? 49 : 25;
    for (int t = t0; t < t1; ++t) {
        const int k0 = t * 64;
        #pragma unroll
        for (int i = 0; i < 4; ++i) {
            int c = i * 128 + tid;          // 0..511
            int r = c >> 3, ch = c & 7;
            int sch = ch ^ (r & 7);
            gload16(kgb + ((size_t)(b * NR_ + k0 + r) << 6) + sch * 8, (void*)(Ks + c * 8));
            gload16(vtb + (size_t)(b * 64 + r) * NR_ + k0 + sch * 8, (void*)(Vs + c * 8));
        }
        __syncthreads();

        float4v sc[4];
        #pragma unroll
        for (int c = 0; c < 4; ++c) {
            float4v acc = (float4v){0.f, 0.f, 0.f, 0.f};
            #pragma unroll
            for (int dc = 0; dc < 2; ++dc) {
                int row = c * 16 + l15;
                short8_t ak = *(const short8_t*)((const char*)Ks + row * 128 + (((g + 4 * dc) ^ lx) * 16));
                acc = __builtin_amdgcn_mfma_f32_16x16x32_bf16(ak, qf[dc], acc, 0, 0, 0);
            }
            sc[c] = acc;
        }

        float tmax = -3.0e38f;
        #pragma unroll
        for (int c = 0; c < 4; ++c)
            #pragma unroll
            for (int r = 0; r < 4; ++r) {
                sc[c][r] *= 0.125f;
                tmax = fmaxf(tmax, sc[c][r]);
            }
        tmax = fmaxf(tmax, __shfl_xor(tmax, 16));
        tmax = fmaxf(tmax, __shfl_xor(tmax, 32));
        float m_new = fmaxf(m_run, tmax);
        float corr = __expf(m_run - m_new);
        float p[4][4];
        float ladd = 0.f;
        #pragma unroll
        for (int c = 0; c < 4; ++c)
            #pragma unroll
            for (int r = 0; r < 4; ++r) {
                float pe = __expf(sc[c][r] - m_new);
                p[c][r] = pe;
                ladd += pe;
            }
        ladd += __shfl_xor(ladd, 16);
        ladd += __shfl_xor(ladd, 32);
        l_run = l_run * corr + ladd;
        m_run = m_new;

        {
            unsigned* Pw = Pu + w * 512 + l15 * 32;
            #pragma unroll
            for (int c = 0; c < 4; ++c) {
                int u32i = 8 * c + 2 * g;
                int usw = (((u32i >> 2) ^ lx) << 2) | (u32i & 3);
                Pw[usw]     = pack_bf16(p[c][0], p[c][1]);
                Pw[usw + 1] = pack_bf16(p[c][2], p[c][3]);
            }
        }

        float co[4];
        #pragma unroll
        for (int r = 0; r < 4; ++r) co[r] = __shfl(corr, g * 4 + r);
        #pragma unroll
        for (int dc = 0; dc < 4; ++dc)
            #pragma unroll
            for (int r = 0; r < 4; ++r) o[dc][r] *= co[r];

        #pragma unroll
        for (int kkc = 0; kkc < 2; ++kkc) {
            short8_t ap = *(const short8_t*)((const char*)Pu + w * 2048 + l15 * 128 + (((kkc * 4 + g) ^ lx) * 16));
            #pragma unroll
            for (int dc = 0; dc < 4; ++dc) {
                int vrow = dc * 16 + l15;
                short8_t bv = *(const short8_t*)((const char*)Vs + vrow * 128 + (((kkc * 4 + g) ^ lx) * 16));
                o[dc] = __builtin_amdgcn_mfma_f32_16x16x32_bf16(ap, bv, o[dc], 0, 0, 0);
            }
        }
        __syncthreads();
    }

    const size_t rbase = (size_t)(split * B_ + b) * N_;
    #pragma unroll
    for (int dc = 0; dc < 4; ++dc)
        #pragma unroll
        for (int r = 0; r < 4; ++r) {
            int row = q0 + w * 16 + g * 4 + r;
            osp[(rbase + row) * 64 + dc * 16 + l15] = o[dc][r];
        }
    if (l < 16) {
        int row = q0 + w * 16 + l15;
        mls[(rbase + row) * 2]     = m_run;
        mls[(rbase + row) * 2 + 1] = l_run;
    }
}

// =====================================================================
// combine the 2 splits -> catb cols [0,64)
// =====================================================================
__global__ __launch_bounds__(256)
void attn_combine(const float* __restrict__ osp, const float* __restrict__ mls,
                  ushort_t* __restrict__ catb) {
    int idx = blockIdx.x * 256 + threadIdx.x;   // B*N*64
    int col = idx & 63;
    size_t rn = (size_t)(idx >> 6);             // b*N + row
    size_t base0 = rn, base1 = rn + (size_t)B_ * N_;
    float m0 = mls[base0 * 2], l0 = mls[base0 * 2 + 1];
    float m1 = mls[base1 * 2], l1 = mls[base1 * 2 + 1];
    float m = fmaxf(m0, m1);
    float w0 = __expf(m0 - m), w1 = __expf(m1 - m);
    float linv = 1.f / (l0 * w0 + l1 * w1);
    float v = (osp[base0 * 64 + col] * w0 + osp[base1 * 64 + col] * w1) * linv;
    catb[rn * DIM_ + col] = bf16r(v);
}

// =====================================================================
// depthwise 3x3 + bias on x_l, vectorized: 4 channels x 4 y-rows / thread
// =====================================================================
__global__ __launch_bounds__(256)
void dwt_kernel(const float* __restrict__ x, const float* __restrict__ w,
                const float* __restrict__ bias, ushort_t* __restrict__ out) {
    int idx = blockIdx.x * 256 + threadIdx.x;
    int c4 = idx % 112;
    int t1 = idx / 112;
    int xx = t1 % 112;
    int t2 = t1 / 112;
    int yg = t2 % 28;
    int b  = t2 / 28;
    int c0 = c4 * 4;
    int y0 = yg * 4;

    float4v w4[9];
    #pragma unroll
    for (int kt = 0; kt < 9; ++kt) {
        w4[kt][0] = w[(c0 + 0) * 9 + kt];
        w4[kt][1] = w[(c0 + 1) * 9 + kt];
        w4[kt][2] = w[(c0 + 2) * 9 + kt];
        w4[kt][3] = w[(c0 + 3) * 9 + kt];
    }
    float4v bv = *(const float4v*)(bias + c0);
    float4v acc[4];
    #pragma unroll
    for (int o2 = 0; o2 < 4; ++o2) acc[o2] = bv;

    #pragma unroll
    for (int yy = 0; yy < 6; ++yy) {
        int Y = y0 - 1 + yy;
        if (Y < 0 || Y >= Himg) continue;
        #pragma unroll
        for (int xt = 0; xt < 3; ++xt) {
            int X = xx - 1 + xt;
            if (X < 0 || X >= Wimg) continue;
            float4v v = *(const float4v*)(x + ((size_t)b * N_ + Y * Wimg + X) * DIM_ + D0_ + c0);
            constexpr int olo_t[6] = {0, 0, 0, 1, 2, 3};
            constexpr int ohi_t[6] = {0, 1, 2, 3, 3, 3};
            #pragma unroll
            for (int o2 = olo_t[yy]; o2 <= ohi_t[yy]; ++o2) {
                float4v wv = w4[(yy - o2) * 3 + xt];
                acc[o2][0] += v[0] * wv[0];
                acc[o2][1] += v[1] * wv[1];
                acc[o2][2] += v[2] * wv[2];
                acc[o2][3] += v[3] * wv[3];
            }
        }
    }
    #pragma unroll
    for (int o2 = 0; o2 < 4; ++o2) {
        uint2v pk;
        pk[0] = pack_bf16(acc[o2][0], acc[o2][1]);
        pk[1] = pack_bf16(acc[o2][2], acc[o2][3]);
        *(uint2v*)(out + ((size_t)b * N_ + (y0 + o2) * Wimg + xx) * DL_ + c0) = pk;
    }
}

// =====================================================================
// "scrambled mean", block-parallel: one block per (b,h,n).
// Thread t = pixel l reads 28 contiguous channels (7 x float4);
// partials split across <=2 output bins (bin = f/L, f = l*28+d);
// 28 gather-threads sum partials in ascending-f order (deterministic).
// =====================================================================
template<int L, int NBW, int STRIDE, int DIL, int CHOFF>
__global__ void local_mean2_kernel(const float* __restrict__ kvl,
                                   float* __restrict__ kvm) {
    __shared__ float slo[L], shi[L];
    const int blk = blockIdx.x;                  // b*NH*49 + h*49 + n
    const int n = blk % 49;
    const int h = (blk / 49) % NH_;
    const int b = blk / (49 * NH_);
    const int wy = n / 7, wx = n % 7;
    const int t = threadIdx.x;

    if (t < L) {
        const int by = t / NBW, bx = t % NBW;
        int Y = by * STRIDE + DIL * wy;
        int X = bx * STRIDE + DIL * wx;
        if (Y >= Himg) Y = 2 * Himg - 2 - Y;     // reflect
        if (X >= Wimg) X = 2 * Wimg - 2 - X;
        const float* src = kvl + ((size_t)b * N_ + Y * Wimg + X) * DL_ + CHOFF + h * HD_;
        float v[28];
        #pragma unroll
        for (int i = 0; i < 7; ++i) {
            float4v q4 = ((const float4v*)src)[i];
            v[i * 4] = q4[0]; v[i * 4 + 1] = q4[1]; v[i * 4 + 2] = q4[2]; v[i * 4 + 3] = q4[3];
        }
        const int f0 = t * HD_;
        const int bin0 = f0 / L;
        const int nlo = min(HD_, (bin0 + 1) * L - f0);   // elems in bin0
        float s0 = 0.f, s1 = 0.f;
        #pragma unroll
        for (int j = 0; j < HD_; ++j) {
            if (j < nlo) s0 += v[j]; else s1 += v[j];
        }
        slo[t] = s0;
        shi[t] = s1;
    }
    __syncthreads();
    if (t < HD_) {
        const int t_lo = (t * L) / HD_;
        const int t_hi = min(L - 1, (t * L + L - 1) / HD_);
        float sum = 0.f;
        for (int u = t_lo; u <= t_hi; ++u) {
            int f0 = u * HD_;
            int b0 = f0 / L;
            int b1 = (f0 + HD_ - 1) / L;
            if (b0 == t) sum += slo[u];
            if (b1 == t && b1 != b0) sum += shi[u];
        }
        kvm[(size_t)blk * HD_ + t] = sum * (1.0f / (float)L);
    }
}

// =====================================================================
// kv = kvm @ fc_w @ sh_w -> (B*NH, 49, 56)
// =====================================================================
__global__ __launch_bounds__(64)
void fcsh_kernel(const float* __restrict__ kvm, const float* __restrict__ fcw,
                 const float* __restrict__ shw, float* __restrict__ out) {
    int bh = blockIdx.x;
    __shared__ float kin[49][28];
    __shared__ float tmp[49][28];
    __shared__ float fw[28 * 28];
    __shared__ float sw[28 * 56];
    int t = threadIdx.x;
    for (int i = t; i < 49 * 28; i += 64) kin[i / 28][i % 28] = kvm[bh * 49 * 28 + i];
    for (int i = t; i < 28 * 28; i += 64) fw[i] = fcw[i];
    for (int i = t; i < 28 * 56; i += 64) sw[i] = shw[i];
    __syncthreads();
    for (int i = t; i < 49 * 28; i += 64) {
        int rr = i / 28, j = i % 28;
        float s = 0.f;
        for (int k = 0; k < 28; ++k) s += kin[rr][k] * fw[k * 28 + j];
        tmp[rr][j] = s;
    }
    __syncthreads();
    for (int i = t; i < 49 * 56; i += 64) {
        int rr = i / 56, j = i % 56;
        float s = 0.f;
        for (int k = 0; k < 28; ++k) s += tmp[rr][k] * sw[k * 56 + j];
        out[bh * 49 * 56 + i] = s;
    }
}

// =====================================================================
// v_ + depthwise3x3(v_img 7x7) + bias -> vc (B*NH, 49, 28)
// =====================================================================
__global__ __launch_bounds__(256)
void vconv_kernel(const float* __restrict__ kvsh, const float* __restrict__ w,
                  const float* __restrict__ bias, float* __restrict__ vc) {
    int idx = blockIdx.x * 256 + threadIdx.x;
    if (idx >= B_ * NH_ * 49 * HD_) return;
    int d  = idx % HD_;
    int n  = (idx / HD_) % 49;
    int bh = idx / (HD_ * 49);
    int h  = bh % NH_;
    int y = n / 7, xx = n % 7;
    int c = h * HD_ + d;
    float sum = kvsh[(bh * 49 + n) * 56 + 28 + d] + bias[c];
    #pragma unroll
    for (int ky = 0; ky < 3; ++ky)
        #pragma unroll
        for (int kx = 0; kx < 3; ++kx) {
            int yy = y + ky - 1, x2 = xx + kx - 1;
            if (yy >= 0 && yy < 7 && x2 >= 0 && x2 < 7)
                sum += kvsh[(bh * 49 + yy * 7 + x2) * 56 + 28 + d] * w[c * 9 + ky * 3 + kx];
        }
    vc[idx] = sum;
}

// =====================================================================
// local attention: 49 keys, hd=28. one thread per q-row.
// =====================================================================
__global__ __launch_bounds__(256)
void attn_local_kernel(const float* __restrict__ q, const float* __restrict__ kvsh,
                       const float* __restrict__ vc, ushort_t* __restrict__ catb,
                       int qcoloff, int outcoloff) {
    const int bh = blockIdx.y;
    const int b = bh / NH_, h = bh % NH_;
    const int n = blockIdx.x * 256 + threadIdx.x;
    __shared__ float Ks[49][28];
    __shared__ float Vsh[49][28];
    const int t = threadIdx.x;
    for (int i = t; i < 49 * 28; i += 256) {
        int rr = i / 28, d = i % 28;
        Ks[rr][d]  = kvsh[(bh * 49 + rr) * 56 + d];
        Vsh[rr][d] = vc[(bh * 49 + rr) * 28 + d];
    }
    __syncthreads();
    float qr[28];
    {
        const float4v* qp4 = (const float4v*)(q + ((size_t)b * N_ + n) * DIM_ + qcoloff + h * 56);
        #pragma unroll
        for (int i = 0; i < 7; ++i) {
            float4v v = qp4[i];
            qr[i * 4] = v[0]; qr[i * 4 + 1] = v[1]; qr[i * 4 + 2] = v[2]; qr[i * 4 + 3] = v[3];
        }
    }
    const float scale = 0.1889822365046136f;   // 28^-0.5
    float mx = -1e30f;
    for (int k = 0; k < 49; ++k) {
        float s = 0.f;
        #pragma unroll
        for (int d = 0; d < 28; ++d) s += qr[d] * Ks[k][d];
        mx = fmaxf(mx, s * scale);
    }
    float l = 0.f;
    float acc[28] = {};
    for (int k = 0; k < 49; ++k) {
        float s = 0.f;
        #pragma unroll
        for (int d = 0; d < 28; ++d) s += qr[d] * Ks[k][d];
        float p = __expf(s * scale - mx);
        l += p;
        #pragma unroll
        for (int d = 0; d < 28; ++d) acc[d] += p * Vsh[k][d];
    }
    float inv = 1.f / l;
    ushort_t* op = catb + ((size_t)b * N_ + n) * DIM_ + outcoloff + h * HD_;
    #pragma unroll
    for (int d = 0; d < 28; ++d) op[d] = bf16r(acc[d] * inv);
}

// =====================================================================
extern "C" void kernel_launch(void* const* d_in, const int* in_sizes, int n_in,
                              void* d_out, int out_size, void* d_ws, size_t ws_size,
                              hipStream_t stream) {
    const float* x      = (const float*)d_in[0];
    const float* Wq     = (const float*)d_in[1];
    const float* Wkv_g  = (const float*)d_in[2];
    const float* sr_w   = (const float*)d_in[3];
    const float* sr_b   = (const float*)d_in[4];
    const float* ln_g   = (const float*)d_in[5];
    const float* ln_b   = (const float*)d_in[6];
    const float* lcg_w  = (const float*)d_in[7];
    const float* lcg_b  = (const float*)d_in[8];
    const float* kvl_dw = (const float*)d_in[9];
    const float* kvl_db = (const float*)d_in[10];
    const float* kvl_pw = (const float*)d_in[11];
    const float* kvl_pb = (const float*)d_in[12];
    const float* fc1_w  = (const float*)d_in[13];
    const float* sh1_w  = (const float*)d_in[14];
    const float* lc1_w  = (const float*)d_in[15];
    const float* lc1_b  = (const float*)d_in[16];
    const float* fc2_w  = (const float*)d_in[17];
    const float* sh2_w  = (const float*)d_in[18];
    const float* lc2_w  = (const float*)d_in[19];
    const float* lc2_b  = (const float*)d_in[20];
    const float* proj_w = (const float*)d_in[21];
    const float* proj_b = (const float*)d_in[22];
    float* out = (float*)d_out;
    char* base = (char*)d_ws;

    // ---- workspace layout (256B aligned) ----
    size_t o = 0;
    auto alloc = [&](size_t bytes) -> void* {
        void* p = base + o;
        o = (o + bytes + 255) & ~(size_t)255;
        return p;
    };
    float*    q     = (float*)   alloc((size_t)B_ * N_ * DIM_ * 4);
    float*    kvl   = (float*)   alloc((size_t)B_ * N_ * DL_ * 4);   // later osp+mls
    ushort_t* xcat  = (ushort_t*)alloc((size_t)B_ * N_ * DIM_ * 2);  // xbf, then cat
    ushort_t* dwtb  = (ushort_t*)alloc((size_t)B_ * N_ * DL_ * 2);
    ushort_t* kgb   = (ushort_t*)alloc((size_t)B_ * NR_ * 64 * 2);
    float*    vg    = (float*)   alloc((size_t)B_ * NR_ * 64 * 4);
    float*    vg2   = (float*)   alloc((size_t)B_ * NR_ * 64 * 4);
    ushort_t* vtb   = (ushort_t*)alloc((size_t)B_ * 64 * NR_ * 2);
    ushort_t* wqt   = (ushort_t*)alloc((size_t)512 * 512 * 2);
    ushort_t* pwt   = (ushort_t*)alloc((size_t)512 * 448 * 2);
    ushort_t* projt = (ushort_t*)alloc((size_t)512 * 512 * 2);
    float*    kvm1  = (float*)   alloc((size_t)B_ * NH_ * 49 * HD_ * 4);
    float*    kvm2  = (float*)   alloc((size_t)B_ * NH_ * 49 * HD_ * 4);
    float*    kv1   = (float*)   alloc((size_t)B_ * NH_ * 49 * 56 * 4);
    float*    kv2   = (float*)   alloc((size_t)B_ * NH_ * 49 * 56 * 4);
    float*    v1c   = (float*)   alloc((size_t)B_ * NH_ * 49 * HD_ * 4);
    float*    v2c   = (float*)   alloc((size_t)B_ * NH_ * 49 * HD_ * 4);
    ushort_t* xbf  = xcat;
    ushort_t* catb = xcat;
    float* osp = kvl;                                   // 2*B*N*64 floats
    float* mls = kvl + (size_t)2 * B_ * N_ * 64;        // 2*B*N*2 floats

    const int M = B_ * N_;   // 25088

    // 0. weight converts + x -> bf16
    convw_kernel<<<512 * 512 / 256, 256, 0, stream>>>(Wq, wqt, 512, 512, 1);
    convw_kernel<<<512 * 448 / 256, 256, 0, stream>>>(kvl_pw, pwt, 448, 448, 0);
    convw_kernel<<<512 * 512 / 256, 256, 0, stream>>>(proj_w, projt, 512, 512, 1);
    convx_kernel<<<(B_ * N_ * DIM_ / 8) / 256, 256, 0, stream>>>(x, xbf);

    // 1. q = x @ Wq   (bf16 MFMA)
    gemm_bf16_kernel<false><<<dim3(M / 128, 4), 256, 0, stream>>>(
        xbf, wqt, nullptr, q, 512, 512, 512);

    // 2. depthwise on x_l -> dwtb (bf16), 4ch x 4row per thread
    dwt_kernel<<<(B_ * 28 * 112 * 112) / 256, 256, 0, stream>>>(x, kvl_dw, kvl_db, dwtb);

    // 3. pointwise: kvl = dwtb @ pwt^T + pb
    gemm_bf16_kernel<true><<<dim3(M / 128, 4), 256, 0, stream>>>(
        dwtb, pwt, kvl_pb, kvl, 448, 448, 448);

    // 4. global branch: sr conv + LN + kv (K as bf16)
    srlnkv_kernel<<<B_ * NR_, 64, 0, stream>>>(x, sr_w, sr_b, ln_g, ln_b, Wkv_g, kgb, vg);

    // 5. vg2 = vg + depthwise(vg); then transpose+convert to vtb
    lcg_kernel<<<(B_ * NR_ * 64) / 256, 256, 0, stream>>>(vg, lcg_w, lcg_b, vg2);
    vtrans_kernel<<<dim3(NR_ / 64, B_), 256, 0, stream>>>(vg2, vtb);

    // 7-9. local branch pipeline (consumes kvl BEFORE osp aliases it)
    {
        local_mean2_kernel<256, 16, 7, 1, 0><<<B_ * NH_ * 49, 256, 0, stream>>>(kvl, kvm1);
        local_mean2_kernel<81, 9, 13, 2, 224><<<B_ * NH_ * 49, 128, 0, stream>>>(kvl, kvm2);
        fcsh_kernel<<<B_ * NH_, 64, 0, stream>>>(kvm1, fc1_w, sh1_w, kv1);
        fcsh_kernel<<<B_ * NH_, 64, 0, stream>>>(kvm2, fc2_w, sh2_w, kv2);
        int tot = B_ * NH_ * 49 * HD_;
        int blocks = (tot + 255) / 256;
        vconv_kernel<<<blocks, 256, 0, stream>>>(kv1, lc1_w, lc1_b, v1c);
        vconv_kernel<<<blocks, 256, 0, stream>>>(kv2, lc2_w, lc2_b, v2c);
    }

    // 6. global flash attention, split-K=2 -> combine into catb cols [0,64)
    attn_global_split<<<dim3(N_ / 32, B_ * 2), 128, 0, stream>>>(q, kgb, vtb, osp, mls);
    attn_combine<<<(B_ * N_ * 64) / 256, 256, 0, stream>>>(osp, mls, catb);

    // 10. local attention -> catb cols [64,288) and [288,512)
    attn_local_kernel<<<dim3(N_ / 256, B_ * NH_), 256, 0, stream>>>(
        q, kv1, v1c, catb, D0_, D0_);
    attn_local_kernel<<<dim3(N_ / 256, B_ * NH_), 256, 0, stream>>>(
        q, kv2, v2c, catb, D0_ + HD_, D0_ + 224);

    // 11. out = catb @ projt^T + proj_b
    gemm_bf16_kernel<true><<<dim3(M / 128, 4), 256, 0, stream>>>(
        catb, projt, proj_b, out, 512, 512, 512);
}

// Round 7
// 424.920 us; speedup vs baseline: 6.8547x; 1.0280x over previous
//
#include <hip/hip_runtime.h>
#include <hip/hip_bf16.h>
#include <math.h>
#include <stdint.h>

// ---- problem constants ----
static constexpr int B_    = 2;
static constexpr int N_    = 12544;   // 112*112
static constexpr int DIM_  = 512;
static constexpr int D0_   = 64;
static constexpr int DL_   = 448;
static constexpr int Himg  = 112;
static constexpr int Wimg  = 112;
static constexpr int HS_   = 56;
static constexpr int NR_   = 3136;    // 56*56
static constexpr int NH_   = 8;
static constexpr int HD_   = 28;
static constexpr int NSPLIT = 4;

typedef unsigned short ushort_t;
typedef __attribute__((ext_vector_type(8))) short short8_t;
typedef __attribute__((ext_vector_type(4))) float float4v;
typedef __attribute__((ext_vector_type(4))) unsigned uint4v;
typedef __attribute__((ext_vector_type(2))) unsigned uint2v;

// round-to-nearest-even f32 -> bf16
static __device__ inline ushort_t bf16r(float x) {
    unsigned u = __builtin_bit_cast(unsigned, x);
    u = (u + 0x7FFFu + ((u >> 16) & 1u)) >> 16;
    return (ushort_t)u;
}
// pack two f32 -> u32 of 2 bf16 (lo, hi)
static __device__ inline unsigned pack_bf16(float lo, float hi) {
    unsigned a = __builtin_bit_cast(unsigned, lo);
    unsigned b = __builtin_bit_cast(unsigned, hi);
    a = (a + 0x7FFFu + ((a >> 16) & 1u)) >> 16;
    b = (b + 0x7FFFu + ((b >> 16) & 1u)) >> 16;
    return a | (b << 16);
}

using gptr_t = const __attribute__((address_space(1))) void*;
using lptr_t = __attribute__((address_space(3))) void*;
static __device__ inline void gload16(const void* g, void* l) {
    __builtin_amdgcn_global_load_lds((gptr_t)(uintptr_t)g, (lptr_t)(uintptr_t)l, 16, 0, 0);
}

// =====================================================================
// bf16 MFMA GEMM: C[M][ldc] (fp32) = A[M][K](bf16) @ Bt[Npad][K](bf16)^T
// 128x128 tile, BK=64, 256 threads (4 waves in 2x2), single-buffer loop.
// =====================================================================
template<bool HASBIAS>
__global__ __launch_bounds__(256, 2)
void gemm_bf16_kernel(const ushort_t* __restrict__ A,
                      const ushort_t* __restrict__ Bt,
                      const float* __restrict__ bias,
                      float* __restrict__ C,
                      int Nn, int K, int ldc) {
    constexpr int BM = 128, BK = 64;
    __shared__ __align__(16) ushort_t As[BM * BK];
    __shared__ __align__(16) ushort_t Bs[BM * BK];
    const int bm = blockIdx.x * BM;
    const int bn = blockIdx.y * BM;
    const int tid = threadIdx.x;
    const int l15 = tid & 15;
    const int g   = (tid & 63) >> 4;
    const int w   = tid >> 6;
    const int wr  = w >> 1, wc = w & 1;

    float4v acc[4][4];
    #pragma unroll
    for (int m = 0; m < 4; ++m)
        #pragma unroll
        for (int n = 0; n < 4; ++n) acc[m][n] = (float4v){0.f, 0.f, 0.f, 0.f};

    for (int k0 = 0; k0 < K; k0 += BK) {
        #pragma unroll
        for (int i = 0; i < 4; ++i) {
            int c = i * 256 + tid;
            int r = c >> 3, ch = c & 7;
            int sch = ch ^ (r & 7);
            gload16(A  + (size_t)(bm + r) * K + k0 + sch * 8, (void*)(As + c * 8));
            gload16(Bt + (size_t)(bn + r) * K + k0 + sch * 8, (void*)(Bs + c * 8));
        }
        __syncthreads();

        short8_t af[4][2], bfr[4][2];
        #pragma unroll
        for (int m = 0; m < 4; ++m) {
            int ar = wr * 64 + m * 16 + l15;
            #pragma unroll
            for (int h = 0; h < 2; ++h)
                af[m][h] = *(const short8_t*)((const char*)As + ar * 128 + (((h * 4 + g) ^ (ar & 7)) * 16));
        }
        #pragma unroll
        for (int n = 0; n < 4; ++n) {
            int br = wc * 64 + n * 16 + l15;
            #pragma unroll
            for (int h = 0; h < 2; ++h)
                bfr[n][h] = *(const short8_t*)((const char*)Bs + br * 128 + (((h * 4 + g) ^ (br & 7)) * 16));
        }
        #pragma unroll
        for (int m = 0; m < 4; ++m)
            #pragma unroll
            for (int n = 0; n < 4; ++n) {
                acc[m][n] = __builtin_amdgcn_mfma_f32_16x16x32_bf16(af[m][0], bfr[n][0], acc[m][n], 0, 0, 0);
                acc[m][n] = __builtin_amdgcn_mfma_f32_16x16x32_bf16(af[m][1], bfr[n][1], acc[m][n], 0, 0, 0);
            }
        __syncthreads();
    }

    #pragma unroll
    for (int n = 0; n < 4; ++n) {
        int ccol = bn + wc * 64 + n * 16 + l15;
        if (ccol < Nn) {
            float bv = HASBIAS ? bias[ccol] : 0.f;
            #pragma unroll
            for (int m = 0; m < 4; ++m) {
                int crow = bm + wr * 64 + m * 16 + g * 4;
                #pragma unroll
                for (int j = 0; j < 4; ++j)
                    C[(size_t)(crow + j) * ldc + ccol] = acc[m][n][j] + bv;
            }
        }
    }
}

// =====================================================================
// weight convert: Wt[Npad][K] bf16 from W (transpose? W[K][Nn] : W[Nn][K])
// =====================================================================
__global__ __launch_bounds__(256)
void convw_kernel(const float* __restrict__ W, ushort_t* __restrict__ Wt,
                  int K, int Nn, int transpose) {
    int idx = blockIdx.x * 256 + threadIdx.x;
    int n = idx / K, k = idx % K;
    float v = 0.f;
    if (n < Nn) v = transpose ? W[(size_t)k * Nn + n] : W[(size_t)n * K + k];
    Wt[idx] = bf16r(v);
}

// fp32 -> bf16 bulk convert, 8 elems/thread
__global__ __launch_bounds__(256)
void convx_kernel(const float* __restrict__ in, ushort_t* __restrict__ outp) {
    int i = blockIdx.x * 256 + threadIdx.x;
    const float4v* p = (const float4v*)(in + (size_t)i * 8);
    float4v a = p[0], b = p[1];
    uint4v u;
    u[0] = pack_bf16(a[0], a[1]);
    u[1] = pack_bf16(a[2], a[3]);
    u[2] = pack_bf16(b[0], b[1]);
    u[3] = pack_bf16(b[2], b[3]);
    *(uint4v*)(outp + (size_t)i * 8) = u;
}

// =====================================================================
// sr-conv (2x2 stride2, 64->64) + LayerNorm(64) + kv GEMM (64->128)
// =====================================================================
__global__ __launch_bounds__(64)
void srlnkv_kernel(const float* __restrict__ x,
                   const float* __restrict__ sr_w, const float* __restrict__ sr_b,
                   const float* __restrict__ ln_g, const float* __restrict__ ln_b,
                   const float* __restrict__ wkv,
                   ushort_t* __restrict__ kgb, float* __restrict__ vg) {
    const int pos = blockIdx.x;              // b*NR + n
    const int b = pos / NR_, n = pos % NR_;
    const int y = n / HS_, xx = n % HS_;
    const int o = threadIdx.x;               // 0..63
    __shared__ float xs[4][64];
    __shared__ float lnv_s[64];
    #pragma unroll
    for (int tap = 0; tap < 4; ++tap) {
        int ky = tap / 2, kx = tap % 2;
        xs[tap][o] = x[((size_t)b * N_ + (2 * y + ky) * Wimg + 2 * xx + kx) * DIM_ + o];
    }
    __syncthreads();
    float sum = sr_b[o];
    for (int i = 0; i < 64; ++i) {
        const float* w = sr_w + o * 256 + i * 4;
        sum += xs[0][i] * w[0] + xs[1][i] * w[1] + xs[2][i] * w[2] + xs[3][i] * w[3];
    }
    float m = sum;
    #pragma unroll
    for (int off = 1; off < 64; off <<= 1) m += __shfl_xor(m, off);
    m *= (1.0f / 64.0f);
    float d = sum - m;
    float v = d * d;
    #pragma unroll
    for (int off = 1; off < 64; off <<= 1) v += __shfl_xor(v, off);
    v *= (1.0f / 64.0f);
    float lnv = d * rsqrtf(v + 1e-5f) * ln_g[o] + ln_b[o];
    lnv_s[o] = lnv;
    __syncthreads();
    float s0 = 0.f, s1 = 0.f;
    for (int i = 0; i < 64; ++i) {
        float lv = lnv_s[i];
        s0 += lv * wkv[i * 128 + o];
        s1 += lv * wkv[i * 128 + o + 64];
    }
    kgb[((size_t)b * NR_ + n) * 64 + o] = bf16r(s0);
    vg[((size_t)b * NR_ + n) * 64 + o] = s1;
}

// =====================================================================
// depthwise 3x3 + bias on v_g image; vg2 = vg + conv (fp32)
// =====================================================================
__global__ __launch_bounds__(256)
void lcg_kernel(const float* __restrict__ vg, const float* __restrict__ w,
                const float* __restrict__ bias, float* __restrict__ vg2) {
    int idx = blockIdx.x * 256 + threadIdx.x;
    if (idx >= B_ * NR_ * 64) return;
    int c = idx % 64;
    int n = (idx / 64) % NR_;
    int b = idx / (64 * NR_);
    int y = n / HS_, xx = n % HS_;
    float sum = vg[idx] + bias[c];
    #pragma unroll
    for (int ky = 0; ky < 3; ++ky)
        #pragma unroll
        for (int kx = 0; kx < 3; ++kx) {
            int yy = y + ky - 1, x2 = xx + kx - 1;
            if (yy >= 0 && yy < HS_ && x2 >= 0 && x2 < HS_)
                sum += vg[((size_t)b * NR_ + yy * HS_ + x2) * 64 + c] * w[c * 9 + ky * 3 + kx];
        }
    vg2[idx] = sum;
}

// =====================================================================
// transpose+convert: vg2 fp32 [B][NR][64] -> vtb bf16 [B][64][NR]
// =====================================================================
__global__ __launch_bounds__(256)
void vtrans_kernel(const float* __restrict__ vg2, ushort_t* __restrict__ vtb) {
    __shared__ float ld[64][65];
    const int b = blockIdx.y, n0 = blockIdx.x * 64, tid = threadIdx.x;
    #pragma unroll
    for (int i = 0; i < 16; ++i) {
        int idx = i * 256 + tid;
        int n = idx >> 6, c = idx & 63;
        ld[n][c] = vg2[((size_t)b * NR_ + n0 + n) * 64 + c];
    }
    __syncthreads();
    #pragma unroll
    for (int i = 0; i < 16; ++i) {
        int idx = i * 256 + tid;
        int d = idx >> 6, nn = idx & 63;
        vtb[(size_t)(b * 64 + d) * NR_ + n0 + nn] = bf16r(ld[nn][d]);
    }
}

// =====================================================================
// Global-branch flash attention, split-K (4 splits), bf16 MFMA.
// Q pre-scaled by 2^-3 (exact); defer-max rescale (THR=8).
// =====================================================================
__global__ __launch_bounds__(128)
void attn_global_split(const float* __restrict__ q,
                       const ushort_t* __restrict__ kgb,
                       const ushort_t* __restrict__ vtb,
                       float* __restrict__ osp, float* __restrict__ mls) {
    __shared__ __align__(16) ushort_t Ks[64 * 64];
    __shared__ __align__(16) ushort_t Vs[64 * 64];
    __shared__ __align__(16) unsigned Pu[1024];    // 2 waves x 16 rows x 32 u32
    const int split = blockIdx.y & 3;
    const int b     = blockIdx.y >> 2;
    const int q0    = blockIdx.x * 32;
    const int tid   = threadIdx.x;
    const int w     = tid >> 6;
    const int l     = tid & 63;
    const int l15   = l & 15;
    const int g     = l >> 4;
    const int lx    = l15 & 7;

    // Q fragments pre-scaled by 0.125 (power-of-2: exact wrt bf16 RNE)
    short8_t qf[2];
    {
        const float* qrow = q + ((size_t)b * N_ + q0 + w * 16 + l15) * DIM_;
        #pragma unroll
        for (int dc = 0; dc < 2; ++dc) {
            const float4v* p4 = (const float4v*)(qrow + g * 8 + 32 * dc);
            float4v x0 = p4[0], x1 = p4[1];
            uint4v uv;
            uv[0] = pack_bf16(x0[0] * 0.125f, x0[1] * 0.125f);
            uv[1] = pack_bf16(x0[2] * 0.125f, x0[3] * 0.125f);
            uv[2] = pack_bf16(x1[0] * 0.125f, x1[1] * 0.125f);
            uv[3] = pack_bf16(x1[2] * 0.125f, x1[3] * 0.125f);
            qf[dc] = __builtin_bit_cast(short8_t, uv);
        }
    }

    float4v o[4];
    #pragma unroll
    for (int i = 0; i < 4; ++i) o[i] = (float4v){0.f, 0.f, 0.f, 0.f};
    float m_run = -3.0e38f, l_run = 0.f;

    const int t0 = split ? split * 12 + 1 : 0;
    const int t1 = split * 12 + 13;
    for (int t = t0; t < t1; ++t) {
        const int k0 = t * 64;
        #pragma unroll
        for (int i = 0; i < 4; ++i) {
            int c = i * 128 + tid;          // 0..511
            int r = c >> 3, ch = c & 7;
            int sch = ch ^ (r & 7);
            gload16(kgb + ((size_t)(b * NR_ + k0 + r) << 6) + sch * 8, (void*)(Ks + c * 8));
            gload16(vtb + (size_t)(b * 64 + r) * NR_ + k0 + sch * 8, (void*)(Vs + c * 8));
        }
        __syncthreads();

        float4v sc[4];
        #pragma unroll
        for (int c = 0; c < 4; ++c) {
            float4v acc = (float4v){0.f, 0.f, 0.f, 0.f};
            #pragma unroll
            for (int dc = 0; dc < 2; ++dc) {
                int row = c * 16 + l15;
                short8_t ak = *(const short8_t*)((const char*)Ks + row * 128 + (((g + 4 * dc) ^ lx) * 16));
                acc = __builtin_amdgcn_mfma_f32_16x16x32_bf16(ak, qf[dc], acc, 0, 0, 0);
            }
            sc[c] = acc;
        }

        // row max (lane holds all 16 scores of qrow l15; reduce across g-lanes)
        float tmax = fmaxf(fmaxf(fmaxf(sc[0][0], sc[0][1]), fmaxf(sc[0][2], sc[0][3])),
                           fmaxf(fmaxf(sc[1][0], sc[1][1]), fmaxf(sc[1][2], sc[1][3])));
        tmax = fmaxf(tmax, fmaxf(fmaxf(fmaxf(sc[2][0], sc[2][1]), fmaxf(sc[2][2], sc[2][3])),
                                 fmaxf(fmaxf(sc[3][0], sc[3][1]), fmaxf(sc[3][2], sc[3][3]))));
        tmax = fmaxf(tmax, __shfl_xor(tmax, 16));
        tmax = fmaxf(tmax, __shfl_xor(tmax, 32));

        // defer-max: rescale only when the running max grew by > 8
        if (__any(tmax > m_run + 8.0f)) {
            float m_new = fmaxf(m_run, tmax);
            float corr = __expf(m_run - m_new);
            float co[4];
            #pragma unroll
            for (int r = 0; r < 4; ++r) co[r] = __shfl(corr, g * 4 + r);
            #pragma unroll
            for (int dc = 0; dc < 4; ++dc)
                #pragma unroll
                for (int r = 0; r < 4; ++r) o[dc][r] *= co[r];
            l_run *= corr;
            m_run = m_new;
        }

        float p[4][4];
        float ladd = 0.f;
        #pragma unroll
        for (int c = 0; c < 4; ++c)
            #pragma unroll
            for (int r = 0; r < 4; ++r) {
                float pe = __expf(sc[c][r] - m_run);
                p[c][r] = pe;
                ladd += pe;
            }
        ladd += __shfl_xor(ladd, 16);
        ladd += __shfl_xor(ladd, 32);
        l_run += ladd;

        {
            unsigned* Pw = Pu + w * 512 + l15 * 32;
            #pragma unroll
            for (int c = 0; c < 4; ++c) {
                int u32i = 8 * c + 2 * g;
                int usw = (((u32i >> 2) ^ lx) << 2) | (u32i & 3);
                Pw[usw]     = pack_bf16(p[c][0], p[c][1]);
                Pw[usw + 1] = pack_bf16(p[c][2], p[c][3]);
            }
        }
        __syncthreads();   // P visible to own wave (and Ks/Vs reuse below)

        #pragma unroll
        for (int kkc = 0; kkc < 2; ++kkc) {
            short8_t ap = *(const short8_t*)((const char*)Pu + w * 2048 + l15 * 128 + (((kkc * 4 + g) ^ lx) * 16));
            #pragma unroll
            for (int dc = 0; dc < 4; ++dc) {
                int vrow = dc * 16 + l15;
                short8_t bv = *(const short8_t*)((const char*)Vs + vrow * 128 + (((kkc * 4 + g) ^ lx) * 16));
                o[dc] = __builtin_amdgcn_mfma_f32_16x16x32_bf16(ap, bv, o[dc], 0, 0, 0);
            }
        }
        __syncthreads();
    }

    const size_t rbase = (size_t)(split * B_ + b) * N_;
    #pragma unroll
    for (int dc = 0; dc < 4; ++dc)
        #pragma unroll
        for (int r = 0; r < 4; ++r) {
            int row = q0 + w * 16 + g * 4 + r;
            osp[(rbase + row) * 64 + dc * 16 + l15] = o[dc][r];
        }
    if (l < 16) {
        int row = q0 + w * 16 + l15;
        mls[(rbase + row) * 2]     = m_run;
        mls[(rbase + row) * 2 + 1] = l_run;
    }
}

// =====================================================================
// combine the 4 splits -> catb cols [0,64)
// =====================================================================
__global__ __launch_bounds__(256)
void attn_combine(const float* __restrict__ osp, const float* __restrict__ mls,
                  ushort_t* __restrict__ catb) {
    int idx = blockIdx.x * 256 + threadIdx.x;   // B*N*64
    int col = idx & 63;
    size_t rn = (size_t)(idx >> 6);             // b*N + row
    const size_t BN = (size_t)B_ * N_;
    float ms[NSPLIT], ls[NSPLIT];
    float m = -3.0e38f;
    #pragma unroll
    for (int s = 0; s < NSPLIT; ++s) {
        ms[s] = mls[(s * BN + rn) * 2];
        ls[s] = mls[(s * BN + rn) * 2 + 1];
        m = fmaxf(m, ms[s]);
    }
    float lsum = 0.f, acc = 0.f;
    #pragma unroll
    for (int s = 0; s < NSPLIT; ++s) {
        float wgt = __expf(ms[s] - m);
        lsum += ls[s] * wgt;
        acc  += osp[(s * BN + rn) * 64 + col] * wgt;
    }
    catb[rn * DIM_ + col] = bf16r(acc / lsum);
}

// =====================================================================
// depthwise 3x3 + bias on x_l, vectorized: 4 channels x 4 y-rows / thread
// =====================================================================
__global__ __launch_bounds__(256)
void dwt_kernel(const float* __restrict__ x, const float* __restrict__ w,
                const float* __restrict__ bias, ushort_t* __restrict__ out) {
    int idx = blockIdx.x * 256 + threadIdx.x;
    int c4 = idx % 112;
    int t1 = idx / 112;
    int xx = t1 % 112;
    int t2 = t1 / 112;
    int yg = t2 % 28;
    int b  = t2 / 28;
    int c0 = c4 * 4;
    int y0 = yg * 4;

    float4v w4[9];
    #pragma unroll
    for (int kt = 0; kt < 9; ++kt) {
        w4[kt][0] = w[(c0 + 0) * 9 + kt];
        w4[kt][1] = w[(c0 + 1) * 9 + kt];
        w4[kt][2] = w[(c0 + 2) * 9 + kt];
        w4[kt][3] = w[(c0 + 3) * 9 + kt];
    }
    float4v bv = *(const float4v*)(bias + c0);
    float4v acc[4];
    #pragma unroll
    for (int o2 = 0; o2 < 4; ++o2) acc[o2] = bv;

    #pragma unroll
    for (int yy = 0; yy < 6; ++yy) {
        int Y = y0 - 1 + yy;
        if (Y < 0 || Y >= Himg) continue;
        #pragma unroll
        for (int xt = 0; xt < 3; ++xt) {
            int X = xx - 1 + xt;
            if (X < 0 || X >= Wimg) continue;
            float4v v = *(const float4v*)(x + ((size_t)b * N_ + Y * Wimg + X) * DIM_ + D0_ + c0);
            constexpr int olo_t[6] = {0, 0, 0, 1, 2, 3};
            constexpr int ohi_t[6] = {0, 1, 2, 3, 3, 3};
            #pragma unroll
            for (int o2 = olo_t[yy]; o2 <= ohi_t[yy]; ++o2) {
                float4v wv = w4[(yy - o2) * 3 + xt];
                acc[o2][0] += v[0] * wv[0];
                acc[o2][1] += v[1] * wv[1];
                acc[o2][2] += v[2] * wv[2];
                acc[o2][3] += v[3] * wv[3];
            }
        }
    }
    #pragma unroll
    for (int o2 = 0; o2 < 4; ++o2) {
        uint2v pk;
        pk[0] = pack_bf16(acc[o2][0], acc[o2][1]);
        pk[1] = pack_bf16(acc[o2][2], acc[o2][3]);
        *(uint2v*)(out + ((size_t)b * N_ + (y0 + o2) * Wimg + xx) * DL_ + c0) = pk;
    }
}

// =====================================================================
// "scrambled mean", block-parallel: one block per (b,h,n).
// =====================================================================
template<int L, int NBW, int STRIDE, int DIL, int CHOFF>
__global__ void local_mean2_kernel(const float* __restrict__ kvl,
                                   float* __restrict__ kvm) {
    __shared__ float slo[L], shi[L];
    const int blk = blockIdx.x;                  // b*NH*49 + h*49 + n
    const int n = blk % 49;
    const int h = (blk / 49) % NH_;
    const int b = blk / (49 * NH_);
    const int wy = n / 7, wx = n % 7;
    const int t = threadIdx.x;

    if (t < L) {
        const int by = t / NBW, bx = t % NBW;
        int Y = by * STRIDE + DIL * wy;
        int X = bx * STRIDE + DIL * wx;
        if (Y >= Himg) Y = 2 * Himg - 2 - Y;     // reflect
        if (X >= Wimg) X = 2 * Wimg - 2 - X;
        const float* src = kvl + ((size_t)b * N_ + Y * Wimg + X) * DL_ + CHOFF + h * HD_;
        float v[28];
        #pragma unroll
        for (int i = 0; i < 7; ++i) {
            float4v q4 = ((const float4v*)src)[i];
            v[i * 4] = q4[0]; v[i * 4 + 1] = q4[1]; v[i * 4 + 2] = q4[2]; v[i * 4 + 3] = q4[3];
        }
        const int f0 = t * HD_;
        const int bin0 = f0 / L;
        const int nlo = min(HD_, (bin0 + 1) * L - f0);   // elems in bin0
        float s0 = 0.f, s1 = 0.f;
        #pragma unroll
        for (int j = 0; j < HD_; ++j) {
            if (j < nlo) s0 += v[j]; else s1 += v[j];
        }
        slo[t] = s0;
        shi[t] = s1;
    }
    __syncthreads();
    if (t < HD_) {
        const int t_lo = (t * L) / HD_;
        const int t_hi = min(L - 1, (t * L + L - 1) / HD_);
        float sum = 0.f;
        for (int u = t_lo; u <= t_hi; ++u) {
            int f0 = u * HD_;
            int b0 = f0 / L;
            int b1 = (f0 + HD_ - 1) / L;
            if (b0 == t) sum += slo[u];
            if (b1 == t && b1 != b0) sum += shi[u];
        }
        kvm[(size_t)blk * HD_ + t] = sum * (1.0f / (float)L);
    }
}

// =====================================================================
// kv = kvm @ fc_w @ sh_w -> (B*NH, 49, 56)
// =====================================================================
__global__ __launch_bounds__(64)
void fcsh_kernel(const float* __restrict__ kvm, const float* __restrict__ fcw,
                 const float* __restrict__ shw, float* __restrict__ out) {
    int bh = blockIdx.x;
    __shared__ float kin[49][28];
    __shared__ float tmp[49][28];
    __shared__ float fw[28 * 28];
    __shared__ float sw[28 * 56];
    int t = threadIdx.x;
    for (int i = t; i < 49 * 28; i += 64) kin[i / 28][i % 28] = kvm[bh * 49 * 28 + i];
    for (int i = t; i < 28 * 28; i += 64) fw[i] = fcw[i];
    for (int i = t; i < 28 * 56; i += 64) sw[i] = shw[i];
    __syncthreads();
    for (int i = t; i < 49 * 28; i += 64) {
        int rr = i / 28, j = i % 28;
        float s = 0.f;
        for (int k = 0; k < 28; ++k) s += kin[rr][k] * fw[k * 28 + j];
        tmp[rr][j] = s;
    }
    __syncthreads();
    for (int i = t; i < 49 * 56; i += 64) {
        int rr = i / 56, j = i % 56;
        float s = 0.f;
        for (int k = 0; k < 28; ++k) s += tmp[rr][k] * sw[k * 56 + j];
        out[bh * 49 * 56 + i] = s;
    }
}

// =====================================================================
// v_ + depthwise3x3(v_img 7x7) + bias -> vc (B*NH, 49, 28)
// =====================================================================
__global__ __launch_bounds__(256)
void vconv_kernel(const float* __restrict__ kvsh, const float* __restrict__ w,
                  const float* __restrict__ bias, float* __restrict__ vc) {
    int idx = blockIdx.x * 256 + threadIdx.x;
    if (idx >= B_ * NH_ * 49 * HD_) return;
    int d  = idx % HD_;
    int n  = (idx / HD_) % 49;
    int bh = idx / (HD_ * 49);
    int h  = bh % NH_;
    int y = n / 7, xx = n % 7;
    int c = h * HD_ + d;
    float sum = kvsh[(bh * 49 + n) * 56 + 28 + d] + bias[c];
    #pragma unroll
    for (int ky = 0; ky < 3; ++ky)
        #pragma unroll
        for (int kx = 0; kx < 3; ++kx) {
            int yy = y + ky - 1, x2 = xx + kx - 1;
            if (yy >= 0 && yy < 7 && x2 >= 0 && x2 < 7)
                sum += kvsh[(bh * 49 + yy * 7 + x2) * 56 + 28 + d] * w[c * 9 + ky * 3 + kx];
        }
    vc[idx] = sum;
}

// =====================================================================
// local attention: 49 keys, hd=28. one thread per q-row.
// =====================================================================
__global__ __launch_bounds__(256)
void attn_local_kernel(const float* __restrict__ q, const float* __restrict__ kvsh,
                       const float* __restrict__ vc, ushort_t* __restrict__ catb,
                       int qcoloff, int outcoloff) {
    const int bh = blockIdx.y;
    const int b = bh / NH_, h = bh % NH_;
    const int n = blockIdx.x * 256 + threadIdx.x;
    __shared__ float Ks[49][28];
    __shared__ float Vsh[49][28];
    const int t = threadIdx.x;
    for (int i = t; i < 49 * 28; i += 256) {
        int rr = i / 28, d = i % 28;
        Ks[rr][d]  = kvsh[(bh * 49 + rr) * 56 + d];
        Vsh[rr][d] = vc[(bh * 49 + rr) * 28 + d];
    }
    __syncthreads();
    float qr[28];
    {
        const float4v* qp4 = (const float4v*)(q + ((size_t)b * N_ + n) * DIM_ + qcoloff + h * 56);
        #pragma unroll
        for (int i = 0; i < 7; ++i) {
            float4v v = qp4[i];
            qr[i * 4] = v[0]; qr[i * 4 + 1] = v[1]; qr[i * 4 + 2] = v[2]; qr[i * 4 + 3] = v[3];
        }
    }
    const float scale = 0.1889822365046136f;   // 28^-0.5
    float mx = -1e30f;
    for (int k = 0; k < 49; ++k) {
        float s = 0.f;
        #pragma unroll
        for (int d = 0; d < 28; ++d) s += qr[d] * Ks[k][d];
        mx = fmaxf(mx, s * scale);
    }
    float l = 0.f;
    float acc[28] = {};
    for (int k = 0; k < 49; ++k) {
        float s = 0.f;
        #pragma unroll
        for (int d = 0; d < 28; ++d) s += qr[d] * Ks[k][d];
        float p = __expf(s * scale - mx);
        l += p;
        #pragma unroll
        for (int d = 0; d < 28; ++d) acc[d] += p * Vsh[k][d];
    }
    float inv = 1.f / l;
    ushort_t* op = catb + ((size_t)b * N_ + n) * DIM_ + outcoloff + h * HD_;
    #pragma unroll
    for (int d = 0; d < 28; ++d) op[d] = bf16r(acc[d] * inv);
}

// =====================================================================
extern "C" void kernel_launch(void* const* d_in, const int* in_sizes, int n_in,
                              void* d_out, int out_size, void* d_ws, size_t ws_size,
                              hipStream_t stream) {
    const float* x      = (const float*)d_in[0];
    const float* Wq     = (const float*)d_in[1];
    const float* Wkv_g  = (const float*)d_in[2];
    const float* sr_w   = (const float*)d_in[3];
    const float* sr_b   = (const float*)d_in[4];
    const float* ln_g   = (const float*)d_in[5];
    const float* ln_b   = (const float*)d_in[6];
    const float* lcg_w  = (const float*)d_in[7];
    const float* lcg_b  = (const float*)d_in[8];
    const float* kvl_dw = (const float*)d_in[9];
    const float* kvl_db = (const float*)d_in[10];
    const float* kvl_pw = (const float*)d_in[11];
    const float* kvl_pb = (const float*)d_in[12];
    const float* fc1_w  = (const float*)d_in[13];
    const float* sh1_w  = (const float*)d_in[14];
    const float* lc1_w  = (const float*)d_in[15];
    const float* lc1_b  = (const float*)d_in[16];
    const float* fc2_w  = (const float*)d_in[17];
    const float* sh2_w  = (const float*)d_in[18];
    const float* lc2_w  = (const float*)d_in[19];
    const float* lc2_b  = (const float*)d_in[20];
    const float* proj_w = (const float*)d_in[21];
    const float* proj_b = (const float*)d_in[22];
    float* out = (float*)d_out;
    char* base = (char*)d_ws;

    // ---- workspace layout (256B aligned) ----
    size_t o = 0;
    auto alloc = [&](size_t bytes) -> void* {
        void* p = base + o;
        o = (o + bytes + 255) & ~(size_t)255;
        return p;
    };
    float*    q     = (float*)   alloc((size_t)B_ * N_ * DIM_ * 4);
    float*    kvl   = (float*)   alloc((size_t)B_ * N_ * DL_ * 4);   // later osp+mls
    ushort_t* xcat  = (ushort_t*)alloc((size_t)B_ * N_ * DIM_ * 2);  // xbf, then cat
    ushort_t* dwtb  = (ushort_t*)alloc((size_t)B_ * N_ * DL_ * 2);
    ushort_t* kgb   = (ushort_t*)alloc((size_t)B_ * NR_ * 64 * 2);
    float*    vg    = (float*)   alloc((size_t)B_ * NR_ * 64 * 4);
    float*    vg2   = (float*)   alloc((size_t)B_ * NR_ * 64 * 4);
    ushort_t* vtb   = (ushort_t*)alloc((size_t)B_ * 64 * NR_ * 2);
    ushort_t* wqt   = (ushort_t*)alloc((size_t)512 * 512 * 2);
    ushort_t* pwt   = (ushort_t*)alloc((size_t)512 * 448 * 2);
    ushort_t* projt = (ushort_t*)alloc((size_t)512 * 512 * 2);
    float*    kvm1  = (float*)   alloc((size_t)B_ * NH_ * 49 * HD_ * 4);
    float*    kvm2  = (float*)   alloc((size_t)B_ * NH_ * 49 * HD_ * 4);
    float*    kv1   = (float*)   alloc((size_t)B_ * NH_ * 49 * 56 * 4);
    float*    kv2   = (float*)   alloc((size_t)B_ * NH_ * 49 * 56 * 4);
    float*    v1c   = (float*)   alloc((size_t)B_ * NH_ * 49 * HD_ * 4);
    float*    v2c   = (float*)   alloc((size_t)B_ * NH_ * 49 * HD_ * 4);
    ushort_t* xbf  = xcat;
    ushort_t* catb = xcat;
    // osp/mls alias kvl (consumed by local_mean before attention runs)
    float* osp = kvl;                                        // NSPLIT*B*N*64 floats
    float* mls = kvl + (size_t)NSPLIT * B_ * N_ * 64;        // NSPLIT*B*N*2 floats

    const int M = B_ * N_;   // 25088

    // 0. weight converts + x -> bf16
    convw_kernel<<<512 * 512 / 256, 256, 0, stream>>>(Wq, wqt, 512, 512, 1);
    convw_kernel<<<512 * 448 / 256, 256, 0, stream>>>(kvl_pw, pwt, 448, 448, 0);
    convw_kernel<<<512 * 512 / 256, 256, 0, stream>>>(proj_w, projt, 512, 512, 1);
    convx_kernel<<<(B_ * N_ * DIM_ / 8) / 256, 256, 0, stream>>>(x, xbf);

    // 1. q = x @ Wq   (bf16 MFMA)
    gemm_bf16_kernel<false><<<dim3(M / 128, 4), 256, 0, stream>>>(
        xbf, wqt, nullptr, q, 512, 512, 512);

    // 2. depthwise on x_l -> dwtb (bf16), 4ch x 4row per thread
    dwt_kernel<<<(B_ * 28 * 112 * 112) / 256, 256, 0, stream>>>(x, kvl_dw, kvl_db, dwtb);

    // 3. pointwise: kvl = dwtb @ pwt^T + pb
    gemm_bf16_kernel<true><<<dim3(M / 128, 4), 256, 0, stream>>>(
        dwtb, pwt, kvl_pb, kvl, 448, 448, 448);

    // 4. global branch: sr conv + LN + kv (K as bf16)
    srlnkv_kernel<<<B_ * NR_, 64, 0, stream>>>(x, sr_w, sr_b, ln_g, ln_b, Wkv_g, kgb, vg);

    // 5. vg2 = vg + depthwise(vg); then transpose+convert to vtb
    lcg_kernel<<<(B_ * NR_ * 64) / 256, 256, 0, stream>>>(vg, lcg_w, lcg_b, vg2);
    vtrans_kernel<<<dim3(NR_ / 64, B_), 256, 0, stream>>>(vg2, vtb);

    // 7-9. local branch pipeline (consumes kvl BEFORE osp aliases it)
    {
        local_mean2_kernel<256, 16, 7, 1, 0><<<B_ * NH_ * 49, 256, 0, stream>>>(kvl, kvm1);
        local_mean2_kernel<81, 9, 13, 2, 224><<<B_ * NH_ * 49, 128, 0, stream>>>(kvl, kvm2);
        fcsh_kernel<<<B_ * NH_, 64, 0, stream>>>(kvm1, fc1_w, sh1_w, kv1);
        fcsh_kernel<<<B_ * NH_, 64, 0, stream>>>(kvm2, fc2_w, sh2_w, kv2);
        int tot = B_ * NH_ * 49 * HD_;
        int blocks = (tot + 255) / 256;
        vconv_kernel<<<blocks, 256, 0, stream>>>(kv1, lc1_w, lc1_b, v1c);
        vconv_kernel<<<blocks, 256, 0, stream>>>(kv2, lc2_w, lc2_b, v2c);
    }

    // 6. global flash attention, split-K=4 -> combine into catb cols [0,64)
    attn_global_split<<<dim3(N_ / 32, B_ * NSPLIT), 128, 0, stream>>>(q, kgb, vtb, osp, mls);
    attn_combine<<<(B_ * N_ * 64) / 256, 256, 0, stream>>>(osp, mls, catb);

    // 10. local attention -> catb cols [64,288) and [288,512)
    attn_local_kernel<<<dim3(N_ / 256, B_ * NH_), 256, 0, stream>>>(
        q, kv1, v1c, catb, D0_, D0_);
    attn_local_kernel<<<dim3(N_ / 256, B_ * NH_), 256, 0, stream>>>(
        q, kv2, v2c, catb, D0_ + HD_, D0_ + 224);

    // 11. out = catb @ projt^T + proj_b
    gemm_bf16_kernel<true><<<dim3(M / 128, 4), 256, 0, stream>>>(
        catb, projt, proj_b, out, 512, 512, 512);
}

// Round 9
// 413.995 us; speedup vs baseline: 7.0356x; 1.0264x over previous
//
#include <hip/hip_runtime.h>
#include <hip/hip_bf16.h>
#include <math.h>
#include <stdint.h>

// ---- problem constants ----
static constexpr int B_    = 2;
static constexpr int N_    = 12544;   // 112*112
static constexpr int DIM_  = 512;
static constexpr int D0_   = 64;
static constexpr int DL_   = 448;
static constexpr int Himg  = 112;
static constexpr int Wimg  = 112;
static constexpr int HS_   = 56;
static constexpr int NR_   = 3136;    // 56*56
static constexpr int NH_   = 8;
static constexpr int HD_   = 28;
static constexpr int NSPLIT = 4;

typedef unsigned short ushort_t;
typedef __attribute__((ext_vector_type(8))) short short8_t;
typedef __attribute__((ext_vector_type(4))) float float4v;
typedef __attribute__((ext_vector_type(4))) unsigned uint4v;
typedef __attribute__((ext_vector_type(2))) unsigned uint2v;

// round-to-nearest-even f32 -> bf16
static __device__ inline ushort_t bf16r(float x) {
    unsigned u = __builtin_bit_cast(unsigned, x);
    u = (u + 0x7FFFu + ((u >> 16) & 1u)) >> 16;
    return (ushort_t)u;
}
// pack two f32 -> u32 of 2 bf16 (lo, hi) -- software RNE (memory-bound kernels)
static __device__ inline unsigned pack_bf16(float lo, float hi) {
    unsigned a = __builtin_bit_cast(unsigned, lo);
    unsigned b = __builtin_bit_cast(unsigned, hi);
    a = (a + 0x7FFFu + ((a >> 16) & 1u)) >> 16;
    b = (b + 0x7FFFu + ((b >> 16) & 1u)) >> 16;
    return a | (b << 16);
}
// HW v_cvt_pk_bf16_f32 path (RNE, identical bits) for VALU-bound kernels
static __device__ inline unsigned cvtpk(float lo, float hi) {
    float2 f2; f2.x = lo; f2.y = hi;
    __hip_bfloat162 h = __float22bfloat162_rn(f2);
    unsigned u;
    __builtin_memcpy(&u, &h, 4);
    return u;
}

using gptr_t = const __attribute__((address_space(1))) void*;
using lptr_t = __attribute__((address_space(3))) void*;
static __device__ inline void gload16(const void* g, void* l) {
    __builtin_amdgcn_global_load_lds((gptr_t)(uintptr_t)g, (lptr_t)(uintptr_t)l, 16, 0, 0);
}

// =====================================================================
// bf16 MFMA GEMM: C[M][ldc] (fp32) = A[M][K](bf16) @ Bt[Npad][K](bf16)^T
// 128x128 tile, BK=64, 256 threads (4 waves in 2x2), single-buffer loop.
// =====================================================================
template<bool HASBIAS>
__global__ __launch_bounds__(256, 2)
void gemm_bf16_kernel(const ushort_t* __restrict__ A,
                      const ushort_t* __restrict__ Bt,
                      const float* __restrict__ bias,
                      float* __restrict__ C,
                      int Nn, int K, int ldc) {
    constexpr int BM = 128, BK = 64;
    __shared__ __align__(16) ushort_t As[BM * BK];
    __shared__ __align__(16) ushort_t Bs[BM * BK];
    const int bm = blockIdx.x * BM;
    const int bn = blockIdx.y * BM;
    const int tid = threadIdx.x;
    const int l15 = tid & 15;
    const int g   = (tid & 63) >> 4;
    const int w   = tid >> 6;
    const int wr  = w >> 1, wc = w & 1;

    float4v acc[4][4];
    #pragma unroll
    for (int m = 0; m < 4; ++m)
        #pragma unroll
        for (int n = 0; n < 4; ++n) acc[m][n] = (float4v){0.f, 0.f, 0.f, 0.f};

    for (int k0 = 0; k0 < K; k0 += BK) {
        #pragma unroll
        for (int i = 0; i < 4; ++i) {
            int c = i * 256 + tid;
            int r = c >> 3, ch = c & 7;
            int sch = ch ^ (r & 7);
            gload16(A  + (size_t)(bm + r) * K + k0 + sch * 8, (void*)(As + c * 8));
            gload16(Bt + (size_t)(bn + r) * K + k0 + sch * 8, (void*)(Bs + c * 8));
        }
        __syncthreads();

        short8_t af[4][2], bfr[4][2];
        #pragma unroll
        for (int m = 0; m < 4; ++m) {
            int ar = wr * 64 + m * 16 + l15;
            #pragma unroll
            for (int h = 0; h < 2; ++h)
                af[m][h] = *(const short8_t*)((const char*)As + ar * 128 + (((h * 4 + g) ^ (ar & 7)) * 16));
        }
        #pragma unroll
        for (int n = 0; n < 4; ++n) {
            int br = wc * 64 + n * 16 + l15;
            #pragma unroll
            for (int h = 0; h < 2; ++h)
                bfr[n][h] = *(const short8_t*)((const char*)Bs + br * 128 + (((h * 4 + g) ^ (br & 7)) * 16));
        }
        #pragma unroll
        for (int m = 0; m < 4; ++m)
            #pragma unroll
            for (int n = 0; n < 4; ++n) {
                acc[m][n] = __builtin_amdgcn_mfma_f32_16x16x32_bf16(af[m][0], bfr[n][0], acc[m][n], 0, 0, 0);
                acc[m][n] = __builtin_amdgcn_mfma_f32_16x16x32_bf16(af[m][1], bfr[n][1], acc[m][n], 0, 0, 0);
            }
        __syncthreads();
    }

    #pragma unroll
    for (int n = 0; n < 4; ++n) {
        int ccol = bn + wc * 64 + n * 16 + l15;
        if (ccol < Nn) {
            float bv = HASBIAS ? bias[ccol] : 0.f;
            #pragma unroll
            for (int m = 0; m < 4; ++m) {
                int crow = bm + wr * 64 + m * 16 + g * 4;
                #pragma unroll
                for (int j = 0; j < 4; ++j)
                    C[(size_t)(crow + j) * ldc + ccol] = acc[m][n][j] + bv;
            }
        }
    }
}

// =====================================================================
// weight convert: Wt[Npad][K] bf16 from W (transpose? W[K][Nn] : W[Nn][K])
// =====================================================================
__global__ __launch_bounds__(256)
void convw_kernel(const float* __restrict__ W, ushort_t* __restrict__ Wt,
                  int K, int Nn, int transpose) {
    int idx = blockIdx.x * 256 + threadIdx.x;
    int n = idx / K, k = idx % K;
    float v = 0.f;
    if (n < Nn) v = transpose ? W[(size_t)k * Nn + n] : W[(size_t)n * K + k];
    Wt[idx] = bf16r(v);
}

// fp32 -> bf16 bulk convert, 8 elems/thread
__global__ __launch_bounds__(256)
void convx_kernel(const float* __restrict__ in, ushort_t* __restrict__ outp) {
    int i = blockIdx.x * 256 + threadIdx.x;
    const float4v* p = (const float4v*)(in + (size_t)i * 8);
    float4v a = p[0], b = p[1];
    uint4v u;
    u[0] = pack_bf16(a[0], a[1]);
    u[1] = pack_bf16(a[2], a[3]);
    u[2] = pack_bf16(b[0], b[1]);
    u[3] = pack_bf16(b[2], b[3]);
    *(uint4v*)(outp + (size_t)i * 8) = u;
}

// =====================================================================
// sr-conv (2x2 stride2, 64->64) + LayerNorm(64) + kv GEMM (64->128)
// =====================================================================
__global__ __launch_bounds__(64)
void srlnkv_kernel(const float* __restrict__ x,
                   const float* __restrict__ sr_w, const float* __restrict__ sr_b,
                   const float* __restrict__ ln_g, const float* __restrict__ ln_b,
                   const float* __restrict__ wkv,
                   ushort_t* __restrict__ kgb, float* __restrict__ vg) {
    const int pos = blockIdx.x;              // b*NR + n
    const int b = pos / NR_, n = pos % NR_;
    const int y = n / HS_, xx = n % HS_;
    const int o = threadIdx.x;               // 0..63
    __shared__ float xs[4][64];
    __shared__ float lnv_s[64];
    #pragma unroll
    for (int tap = 0; tap < 4; ++tap) {
        int ky = tap / 2, kx = tap % 2;
        xs[tap][o] = x[((size_t)b * N_ + (2 * y + ky) * Wimg + 2 * xx + kx) * DIM_ + o];
    }
    __syncthreads();
    float sum = sr_b[o];
    for (int i = 0; i < 64; ++i) {
        const float* w = sr_w + o * 256 + i * 4;
        sum += xs[0][i] * w[0] + xs[1][i] * w[1] + xs[2][i] * w[2] + xs[3][i] * w[3];
    }
    float m = sum;
    #pragma unroll
    for (int off = 1; off < 64; off <<= 1) m += __shfl_xor(m, off);
    m *= (1.0f / 64.0f);
    float d = sum - m;
    float v = d * d;
    #pragma unroll
    for (int off = 1; off < 64; off <<= 1) v += __shfl_xor(v, off);
    v *= (1.0f / 64.0f);
    float lnv = d * rsqrtf(v + 1e-5f) * ln_g[o] + ln_b[o];
    lnv_s[o] = lnv;
    __syncthreads();
    float s0 = 0.f, s1 = 0.f;
    for (int i = 0; i < 64; ++i) {
        float lv = lnv_s[i];
        s0 += lv * wkv[i * 128 + o];
        s1 += lv * wkv[i * 128 + o + 64];
    }
    kgb[((size_t)b * NR_ + n) * 64 + o] = bf16r(s0);
    vg[((size_t)b * NR_ + n) * 64 + o] = s1;
}

// =====================================================================
// depthwise 3x3 + bias on v_g image; vg2 = vg + conv (fp32)
// =====================================================================
__global__ __launch_bounds__(256)
void lcg_kernel(const float* __restrict__ vg, const float* __restrict__ w,
                const float* __restrict__ bias, float* __restrict__ vg2) {
    int idx = blockIdx.x * 256 + threadIdx.x;
    if (idx >= B_ * NR_ * 64) return;
    int c = idx % 64;
    int n = (idx / 64) % NR_;
    int b = idx / (64 * NR_);
    int y = n / HS_, xx = n % HS_;
    float sum = vg[idx] + bias[c];
    #pragma unroll
    for (int ky = 0; ky < 3; ++ky)
        #pragma unroll
        for (int kx = 0; kx < 3; ++kx) {
            int yy = y + ky - 1, x2 = xx + kx - 1;
            if (yy >= 0 && yy < HS_ && x2 >= 0 && x2 < HS_)
                sum += vg[((size_t)b * NR_ + yy * HS_ + x2) * 64 + c] * w[c * 9 + ky * 3 + kx];
        }
    vg2[idx] = sum;
}

// =====================================================================
// transpose+convert: vg2 fp32 [B][NR][64] -> vtb bf16 [B][64][NR]
// =====================================================================
__global__ __launch_bounds__(256)
void vtrans_kernel(const float* __restrict__ vg2, ushort_t* __restrict__ vtb) {
    __shared__ float ld[64][65];
    const int b = blockIdx.y, n0 = blockIdx.x * 64, tid = threadIdx.x;
    #pragma unroll
    for (int i = 0; i < 16; ++i) {
        int idx = i * 256 + tid;
        int n = idx >> 6, c = idx & 63;
        ld[n][c] = vg2[((size_t)b * NR_ + n0 + n) * 64 + c];
    }
    __syncthreads();
    #pragma unroll
    for (int i = 0; i < 16; ++i) {
        int idx = i * 256 + tid;
        int d = idx >> 6, nn = idx & 63;
        vtb[(size_t)(b * 64 + d) * NR_ + n0 + nn] = bf16r(ld[nn][d]);
    }
}

// =====================================================================
// Global-branch flash attention, split-K (4 splits), bf16 MFMA.
// 256 threads (4 waves), 64 q-rows/block. exp2-domain softmax:
// Q pre-scaled by 0.125*log2(e); exp = bare v_exp_f32; defer-max THR=11.
// P -> bf16 via HW v_cvt_pk_bf16_f32.
// =====================================================================
__global__ __launch_bounds__(256)
void attn_global_split(const float* __restrict__ q,
                       const ushort_t* __restrict__ kgb,
                       const ushort_t* __restrict__ vtb,
                       float* __restrict__ osp, float* __restrict__ mls) {
    __shared__ __align__(16) ushort_t Ks[64 * 64];
    __shared__ __align__(16) ushort_t Vs[64 * 64];
    __shared__ __align__(16) unsigned Pu[4 * 512];   // 4 waves x 16 rows x 32 u32
    const int split = blockIdx.y & 3;
    const int b     = blockIdx.y >> 2;
    const int q0    = blockIdx.x * 64;
    const int tid   = threadIdx.x;
    const int w     = tid >> 6;       // wave 0..3
    const int l     = tid & 63;
    const int l15   = l & 15;
    const int g     = l >> 4;
    const int lx    = l15 & 7;
    const float SC  = 0.125f * 1.44269504088896340736f;   // scale * log2(e)

    // Q fragments pre-scaled into exp2 domain
    short8_t qf[2];
    {
        const float* qrow = q + ((size_t)b * N_ + q0 + w * 16 + l15) * DIM_;
        #pragma unroll
        for (int dc = 0; dc < 2; ++dc) {
            const float4v* p4 = (const float4v*)(qrow + g * 8 + 32 * dc);
            float4v x0 = p4[0], x1 = p4[1];
            uint4v uv;
            uv[0] = cvtpk(x0[0] * SC, x0[1] * SC);
            uv[1] = cvtpk(x0[2] * SC, x0[3] * SC);
            uv[2] = cvtpk(x1[0] * SC, x1[1] * SC);
            uv[3] = cvtpk(x1[2] * SC, x1[3] * SC);
            qf[dc] = __builtin_bit_cast(short8_t, uv);
        }
    }

    float4v o[4];
    #pragma unroll
    for (int i = 0; i < 4; ++i) o[i] = (float4v){0.f, 0.f, 0.f, 0.f};
    float m_run = -3.0e38f, l_run = 0.f;

    const int t0 = split ? split * 12 + 1 : 0;
    const int t1 = split * 12 + 13;
    for (int t = t0; t < t1; ++t) {
        const int k0 = t * 64;
        // stage K (64x64) + Vt (64x64) bf16: 2 chunks each per thread
        #pragma unroll
        for (int i = 0; i < 2; ++i) {
            int c = i * 256 + tid;          // 0..511
            int r = c >> 3, ch = c & 7;
            int sch = ch ^ (r & 7);
            gload16(kgb + ((size_t)(b * NR_ + k0 + r) << 6) + sch * 8, (void*)(Ks + c * 8));
            gload16(vtb + (size_t)(b * 64 + r) * NR_ + k0 + sch * 8, (void*)(Vs + c * 8));
        }
        __syncthreads();

        float4v sc[4];
        #pragma unroll
        for (int c = 0; c < 4; ++c) {
            float4v acc = (float4v){0.f, 0.f, 0.f, 0.f};
            #pragma unroll
            for (int dc = 0; dc < 2; ++dc) {
                int row = c * 16 + l15;
                short8_t ak = *(const short8_t*)((const char*)Ks + row * 128 + (((g + 4 * dc) ^ lx) * 16));
                acc = __builtin_amdgcn_mfma_f32_16x16x32_bf16(ak, qf[dc], acc, 0, 0, 0);
            }
            sc[c] = acc;
        }

        // row max (lane holds all 16 scores of qrow l15; reduce across g-lanes)
        float tmax = fmaxf(fmaxf(fmaxf(sc[0][0], sc[0][1]), fmaxf(sc[0][2], sc[0][3])),
                           fmaxf(fmaxf(sc[1][0], sc[1][1]), fmaxf(sc[1][2], sc[1][3])));
        tmax = fmaxf(tmax, fmaxf(fmaxf(fmaxf(sc[2][0], sc[2][1]), fmaxf(sc[2][2], sc[2][3])),
                                 fmaxf(fmaxf(sc[3][0], sc[3][1]), fmaxf(sc[3][2], sc[3][3]))));
        tmax = fmaxf(tmax, __shfl_xor(tmax, 16));
        tmax = fmaxf(tmax, __shfl_xor(tmax, 32));

        // defer-max: rescale only when max grew by > 11 (=8*log2e, exp2 dom.)
        if (__any(tmax > m_run + 11.0f)) {
            float m_new = fmaxf(m_run, tmax);
            float corr = __builtin_amdgcn_exp2f(m_run - m_new);
            float co[4];
            #pragma unroll
            for (int r = 0; r < 4; ++r) co[r] = __shfl(corr, g * 4 + r);
            #pragma unroll
            for (int dc = 0; dc < 4; ++dc)
                #pragma unroll
                for (int r = 0; r < 4; ++r) o[dc][r] *= co[r];
            l_run *= corr;
            m_run = m_new;
        }

        float p[4][4];
        float ladd = 0.f;
        #pragma unroll
        for (int c = 0; c < 4; ++c)
            #pragma unroll
            for (int r = 0; r < 4; ++r) {
                float pe = __builtin_amdgcn_exp2f(sc[c][r] - m_run);
                p[c][r] = pe;
                ladd += pe;
            }
        ladd += __shfl_xor(ladd, 16);
        ladd += __shfl_xor(ladd, 32);
        l_run += ladd;

        {
            unsigned* Pw = Pu + w * 512 + l15 * 32;
            #pragma unroll
            for (int c = 0; c < 4; ++c) {
                int u32i = 8 * c + 2 * g;
                int usw = (((u32i >> 2) ^ lx) << 2) | (u32i & 3);
                Pw[usw]     = cvtpk(p[c][0], p[c][1]);
                Pw[usw + 1] = cvtpk(p[c][2], p[c][3]);
            }
        }
        __syncthreads();

        #pragma unroll
        for (int kkc = 0; kkc < 2; ++kkc) {
            short8_t ap = *(const short8_t*)((const char*)Pu + w * 2048 + l15 * 128 + (((kkc * 4 + g) ^ lx) * 16));
            #pragma unroll
            for (int dc = 0; dc < 4; ++dc) {
                int vrow = dc * 16 + l15;
                short8_t bv = *(const short8_t*)((const char*)Vs + vrow * 128 + (((kkc * 4 + g) ^ lx) * 16));
                o[dc] = __builtin_amdgcn_mfma_f32_16x16x32_bf16(ap, bv, o[dc], 0, 0, 0);
            }
        }
        __syncthreads();
    }

    const size_t rbase = (size_t)(split * B_ + b) * N_;
    #pragma unroll
    for (int dc = 0; dc < 4; ++dc)
        #pragma unroll
        for (int r = 0; r < 4; ++r) {
            int row = q0 + w * 16 + g * 4 + r;
            osp[(rbase + row) * 64 + dc * 16 + l15] = o[dc][r];
        }
    if (l < 16) {
        int row = q0 + w * 16 + l15;
        mls[(rbase + row) * 2]     = m_run;
        mls[(rbase + row) * 2 + 1] = l_run;
    }
}

// =====================================================================
// combine the 4 splits (exp2 domain) -> catb cols [0,64)
// =====================================================================
__global__ __launch_bounds__(256)
void attn_combine(const float* __restrict__ osp, const float* __restrict__ mls,
                  ushort_t* __restrict__ catb) {
    int idx = blockIdx.x * 256 + threadIdx.x;   // B*N*64
    int col = idx & 63;
    size_t rn = (size_t)(idx >> 6);             // b*N + row
    const size_t BN = (size_t)B_ * N_;
    float ms[NSPLIT], ls[NSPLIT];
    float m = -3.0e38f;
    #pragma unroll
    for (int s = 0; s < NSPLIT; ++s) {
        ms[s] = mls[(s * BN + rn) * 2];
        ls[s] = mls[(s * BN + rn) * 2 + 1];
        m = fmaxf(m, ms[s]);
    }
    float lsum = 0.f, acc = 0.f;
    #pragma unroll
    for (int s = 0; s < NSPLIT; ++s) {
        float wgt = __builtin_amdgcn_exp2f(ms[s] - m);
        lsum += ls[s] * wgt;
        acc  += osp[(s * BN + rn) * 64 + col] * wgt;
    }
    catb[rn * DIM_ + col] = bf16r(acc / lsum);
}

// =====================================================================
// depthwise 3x3 + bias on x_l, vectorized: 4 channels x 4 y-rows / thread
// =====================================================================
__global__ __launch_bounds__(256)
void dwt_kernel(const float* __restrict__ x, const float* __restrict__ w,
                const float* __restrict__ bias, ushort_t* __restrict__ out) {
    int idx = blockIdx.x * 256 + threadIdx.x;
    int c4 = idx % 112;
    int t1 = idx / 112;
    int xx = t1 % 112;
    int t2 = t1 / 112;
    int yg = t2 % 28;
    int b  = t2 / 28;
    int c0 = c4 * 4;
    int y0 = yg * 4;

    float4v w4[9];
    #pragma unroll
    for (int kt = 0; kt < 9; ++kt) {
        w4[kt][0] = w[(c0 + 0) * 9 + kt];
        w4[kt][1] = w[(c0 + 1) * 9 + kt];
        w4[kt][2] = w[(c0 + 2) * 9 + kt];
        w4[kt][3] = w[(c0 + 3) * 9 + kt];
    }
    float4v bv = *(const float4v*)(bias + c0);
    float4v acc[4];
    #pragma unroll
    for (int o2 = 0; o2 < 4; ++o2) acc[o2] = bv;

    #pragma unroll
    for (int yy = 0; yy < 6; ++yy) {
        int Y = y0 - 1 + yy;
        if (Y < 0 || Y >= Himg) continue;
        #pragma unroll
        for (int xt = 0; xt < 3; ++xt) {
            int X = xx - 1 + xt;
            if (X < 0 || X >= Wimg) continue;
            float4v v = *(const float4v*)(x + ((size_t)b * N_ + Y * Wimg + X) * DIM_ + D0_ + c0);
            constexpr int olo_t[6] = {0, 0, 0, 1, 2, 3};
            constexpr int ohi_t[6] = {0, 1, 2, 3, 3, 3};
            #pragma unroll
            for (int o2 = olo_t[yy]; o2 <= ohi_t[yy]; ++o2) {
                float4v wv = w4[(yy - o2) * 3 + xt];
                acc[o2][0] += v[0] * wv[0];
                acc[o2][1] += v[1] * wv[1];
                acc[o2][2] += v[2] * wv[2];
                acc[o2][3] += v[3] * wv[3];
            }
        }
    }
    #pragma unroll
    for (int o2 = 0; o2 < 4; ++o2) {
        uint2v pk;
        pk[0] = pack_bf16(acc[o2][0], acc[o2][1]);
        pk[1] = pack_bf16(acc[o2][2], acc[o2][3]);
        *(uint2v*)(out + ((size_t)b * N_ + (y0 + o2) * Wimg + xx) * DL_ + c0) = pk;
    }
}

// =====================================================================
// "scrambled mean", block-parallel: one block per (b,h,n).
// =====================================================================
template<int L, int NBW, int STRIDE, int DIL, int CHOFF>
__global__ void local_mean2_kernel(const float* __restrict__ kvl,
                                   float* __restrict__ kvm) {
    __shared__ float slo[L], shi[L];
    const int blk = blockIdx.x;                  // b*NH*49 + h*49 + n
    const int n = blk % 49;
    const int h = (blk / 49) % NH_;
    const int b = blk / (49 * NH_);
    const int wy = n / 7, wx = n % 7;
    const int t = threadIdx.x;

    if (t < L) {
        const int by = t / NBW, bx = t % NBW;
        int Y = by * STRIDE + DIL * wy;
        int X = bx * STRIDE + DIL * wx;
        if (Y >= Himg) Y = 2 * Himg - 2 - Y;     // reflect
        if (X >= Wimg) X = 2 * Wimg - 2 - X;
        const float* src = kvl + ((size_t)b * N_ + Y * Wimg + X) * DL_ + CHOFF + h * HD_;
        float v[28];
        #pragma unroll
        for (int i = 0; i < 7; ++i) {
            float4v q4 = ((const float4v*)src)[i];
            v[i * 4] = q4[0]; v[i * 4 + 1] = q4[1]; v[i * 4 + 2] = q4[2]; v[i * 4 + 3] = q4[3];
        }
        const int f0 = t * HD_;
        const int bin0 = f0 / L;
        const int nlo = min(HD_, (bin0 + 1) * L - f0);   // elems in bin0
        float s0 = 0.f, s1 = 0.f;
        #pragma unroll
        for (int j = 0; j < HD_; ++j) {
            if (j < nlo) s0 += v[j]; else s1 += v[j];
        }
        slo[t] = s0;
        shi[t] = s1;
    }
    __syncthreads();
    if (t < HD_) {
        const int t_lo = (t * L) / HD_;
        const int t_hi = min(L - 1, (t * L + L - 1) / HD_);
        float sum = 0.f;
        for (int u = t_lo; u <= t_hi; ++u) {
            int f0 = u * HD_;
            int b0 = f0 / L;
            int b1 = (f0 + HD_ - 1) / L;
            if (b0 == t) sum += slo[u];
            if (b1 == t && b1 != b0) sum += shi[u];
        }
        kvm[(size_t)blk * HD_ + t] = sum * (1.0f / (float)L);
    }
}

// =====================================================================
// kv = kvm @ fc_w @ sh_w -> (B*NH, 49, 56)
// =====================================================================
__global__ __launch_bounds__(64)
void fcsh_kernel(const float* __restrict__ kvm, const float* __restrict__ fcw,
                 const float* __restrict__ shw, float* __restrict__ out) {
    int bh = blockIdx.x;
    __shared__ float kin[49][28];
    __shared__ float tmp[49][28];
    __shared__ float fw[28 * 28];
    __shared__ float sw[28 * 56];
    int t = threadIdx.x;
    for (int i = t; i < 49 * 28; i += 64) kin[i / 28][i % 28] = kvm[bh * 49 * 28 + i];
    for (int i = t; i < 28 * 28; i += 64) fw[i] = fcw[i];
    for (int i = t; i < 28 * 56; i += 64) sw[i] = shw[i];
    __syncthreads();
    for (int i = t; i < 49 * 28; i += 64) {
        int rr = i / 28, j = i % 28;
        float s = 0.f;
        for (int k = 0; k < 28; ++k) s += kin[rr][k] * fw[k * 28 + j];
        tmp[rr][j] = s;
    }
    __syncthreads();
    for (int i = t; i < 49 * 56; i += 64) {
        int rr = i / 56, j = i % 56;
        float s = 0.f;
        for (int k = 0; k < 28; ++k) s += tmp[rr][k] * sw[k * 56 + j];
        out[bh * 49 * 56 + i] = s;
    }
}

// =====================================================================
// v_ + depthwise3x3(v_img 7x7) + bias -> vc (B*NH, 49, 28)
// =====================================================================
__global__ __launch_bounds__(256)
void vconv_kernel(const float* __restrict__ kvsh, const float* __restrict__ w,
                  const float* __restrict__ bias, float* __restrict__ vc) {
    int idx = blockIdx.x * 256 + threadIdx.x;
    if (idx >= B_ * NH_ * 49 * HD_) return;
    int d  = idx % HD_;
    int n  = (idx / HD_) % 49;
    int bh = idx / (HD_ * 49);
    int h  = bh % NH_;
    int y = n / 7, xx = n % 7;
    int c = h * HD_ + d;
    float sum = kvsh[(bh * 49 + n) * 56 + 28 + d] + bias[c];
    #pragma unroll
    for (int ky = 0; ky < 3; ++ky)
        #pragma unroll
        for (int kx = 0; kx < 3; ++kx) {
            int yy = y + ky - 1, x2 = xx + kx - 1;
            if (yy >= 0 && yy < 7 && x2 >= 0 && x2 < 7)
                sum += kvsh[(bh * 49 + yy * 7 + x2) * 56 + 28 + d] * w[c * 9 + ky * 3 + kx];
        }
    vc[idx] = sum;
}

// =====================================================================
// local attention: 49 keys, hd=28. one thread per q-row.
// =====================================================================
__global__ __launch_bounds__(256)
void attn_local_kernel(const float* __restrict__ q, const float* __restrict__ kvsh,
                       const float* __restrict__ vc, ushort_t* __restrict__ catb,
                       int qcoloff, int outcoloff) {
    const int bh = blockIdx.y;
    const int b = bh / NH_, h = bh % NH_;
    const int n = blockIdx.x * 256 + threadIdx.x;
    __shared__ float Ks[49][28];
    __shared__ float Vsh[49][28];
    const int t = threadIdx.x;
    for (int i = t; i < 49 * 28; i += 256) {
        int rr = i / 28, d = i % 28;
        Ks[rr][d]  = kvsh[(bh * 49 + rr) * 56 + d];
        Vsh[rr][d] = vc[(bh * 49 + rr) * 28 + d];
    }
    __syncthreads();
    float qr[28];
    {
        const float4v* qp4 = (const float4v*)(q + ((size_t)b * N_ + n) * DIM_ + qcoloff + h * 56);
        #pragma unroll
        for (int i = 0; i < 7; ++i) {
            float4v v = qp4[i];
            qr[i * 4] = v[0]; qr[i * 4 + 1] = v[1]; qr[i * 4 + 2] = v[2]; qr[i * 4 + 3] = v[3];
        }
    }
    const float scale = 0.1889822365046136f;   // 28^-0.5
    float mx = -1e30f;
    for (int k = 0; k < 49; ++k) {
        float s = 0.f;
        #pragma unroll
        for (int d = 0; d < 28; ++d) s += qr[d] * Ks[k][d];
        mx = fmaxf(mx, s * scale);
    }
    float l = 0.f;
    float acc[28] = {};
    for (int k = 0; k < 49; ++k) {
        float s = 0.f;
        #pragma unroll
        for (int d = 0; d < 28; ++d) s += qr[d] * Ks[k][d];
        float p = __expf(s * scale - mx);
        l += p;
        #pragma unroll
        for (int d = 0; d < 28; ++d) acc[d] += p * Vsh[k][d];
    }
    float inv = 1.f / l;
    ushort_t* op = catb + ((size_t)b * N_ + n) * DIM_ + outcoloff + h * HD_;
    #pragma unroll
    for (int d = 0; d < 28; ++d) op[d] = bf16r(acc[d] * inv);
}

// =====================================================================
extern "C" void kernel_launch(void* const* d_in, const int* in_sizes, int n_in,
                              void* d_out, int out_size, void* d_ws, size_t ws_size,
                              hipStream_t stream) {
    const float* x      = (const float*)d_in[0];
    const float* Wq     = (const float*)d_in[1];
    const float* Wkv_g  = (const float*)d_in[2];
    const float* sr_w   = (const float*)d_in[3];
    const float* sr_b   = (const float*)d_in[4];
    const float* ln_g   = (const float*)d_in[5];
    const float* ln_b   = (const float*)d_in[6];
    const float* lcg_w  = (const float*)d_in[7];
    const float* lcg_b  = (const float*)d_in[8];
    const float* kvl_dw = (const float*)d_in[9];
    const float* kvl_db = (const float*)d_in[10];
    const float* kvl_pw = (const float*)d_in[11];
    const float* kvl_pb = (const float*)d_in[12];
    const float* fc1_w  = (const float*)d_in[13];
    const float* sh1_w  = (const float*)d_in[14];
    const float* lc1_w  = (const float*)d_in[15];
    const float* lc1_b  = (const float*)d_in[16];
    const float* fc2_w  = (const float*)d_in[17];
    const float* sh2_w  = (const float*)d_in[18];
    const float* lc2_w  = (const float*)d_in[19];
    const float* lc2_b  = (const float*)d_in[20];
    const float* proj_w = (const float*)d_in[21];
    const float* proj_b = (const float*)d_in[22];
    float* out = (float*)d_out;
    char* base = (char*)d_ws;

    // ---- workspace layout (256B aligned) ----
    size_t o = 0;
    auto alloc = [&](size_t bytes) -> void* {
        void* p = base + o;
        o = (o + bytes + 255) & ~(size_t)255;
        return p;
    };
    float*    q     = (float*)   alloc((size_t)B_ * N_ * DIM_ * 4);
    float*    kvl   = (float*)   alloc((size_t)B_ * N_ * DL_ * 4);   // later osp+mls
    ushort_t* xcat  = (ushort_t*)alloc((size_t)B_ * N_ * DIM_ * 2);  // xbf, then cat
    ushort_t* dwtb  = (ushort_t*)alloc((size_t)B_ * N_ * DL_ * 2);
    ushort_t* kgb   = (ushort_t*)alloc((size_t)B_ * NR_ * 64 * 2);
    float*    vg    = (float*)   alloc((size_t)B_ * NR_ * 64 * 4);
    float*    vg2   = (float*)   alloc((size_t)B_ * NR_ * 64 * 4);
    ushort_t* vtb   = (ushort_t*)alloc((size_t)B_ * 64 * NR_ * 2);
    ushort_t* wqt   = (ushort_t*)alloc((size_t)512 * 512 * 2);
    ushort_t* pwt   = (ushort_t*)alloc((size_t)512 * 448 * 2);
    ushort_t* projt = (ushort_t*)alloc((size_t)512 * 512 * 2);
    float*    kvm1  = (float*)   alloc((size_t)B_ * NH_ * 49 * HD_ * 4);
    float*    kvm2  = (float*)   alloc((size_t)B_ * NH_ * 49 * HD_ * 4);
    float*    kv1   = (float*)   alloc((size_t)B_ * NH_ * 49 * 56 * 4);
    float*    kv2   = (float*)   alloc((size_t)B_ * NH_ * 49 * 56 * 4);
    float*    v1c   = (float*)   alloc((size_t)B_ * NH_ * 49 * HD_ * 4);
    float*    v2c   = (float*)   alloc((size_t)B_ * NH_ * 49 * HD_ * 4);
    ushort_t* xbf  = xcat;
    ushort_t* catb = xcat;
    // osp/mls alias kvl (consumed by local_mean before attention runs)
    float* osp = kvl;                                        // NSPLIT*B*N*64 floats
    float* mls = kvl + (size_t)NSPLIT * B_ * N_ * 64;        // NSPLIT*B*N*2 floats

    const int M = B_ * N_;   // 25088

    // 0. weight converts + x -> bf16
    convw_kernel<<<512 * 512 / 256, 256, 0, stream>>>(Wq, wqt, 512, 512, 1);
    convw_kernel<<<512 * 448 / 256, 256, 0, stream>>>(kvl_pw, pwt, 448, 448, 0);
    convw_kernel<<<512 * 512 / 256, 256, 0, stream>>>(proj_w, projt, 512, 512, 1);
    convx_kernel<<<(B_ * N_ * DIM_ / 8) / 256, 256, 0, stream>>>(x, xbf);

    // 1. q = x @ Wq   (bf16 MFMA)
    gemm_bf16_kernel<false><<<dim3(M / 128, 4), 256, 0, stream>>>(
        xbf, wqt, nullptr, q, 512, 512, 512);

    // 2. depthwise on x_l -> dwtb (bf16), 4ch x 4row per thread
    dwt_kernel<<<(B_ * 28 * 112 * 112) / 256, 256, 0, stream>>>(x, kvl_dw, kvl_db, dwtb);

    // 3. pointwise: kvl = dwtb @ pwt^T + pb
    gemm_bf16_kernel<true><<<dim3(M / 128, 4), 256, 0, stream>>>(
        dwtb, pwt, kvl_pb, kvl, 448, 448, 448);

    // 4. global branch: sr conv + LN + kv (K as bf16)
    srlnkv_kernel<<<B_ * NR_, 64, 0, stream>>>(x, sr_w, sr_b, ln_g, ln_b, Wkv_g, kgb, vg);

    // 5. vg2 = vg + depthwise(vg); then transpose+convert to vtb
    lcg_kernel<<<(B_ * NR_ * 64) / 256, 256, 0, stream>>>(vg, lcg_w, lcg_b, vg2);
    vtrans_kernel<<<dim3(NR_ / 64, B_), 256, 0, stream>>>(vg2, vtb);

    // 7-9. local branch pipeline (consumes kvl BEFORE osp aliases it)
    {
        local_mean2_kernel<256, 16, 7, 1, 0><<<B_ * NH_ * 49, 256, 0, stream>>>(kvl, kvm1);
        local_mean2_kernel<81, 9, 13, 2, 224><<<B_ * NH_ * 49, 128, 0, stream>>>(kvl, kvm2);
        fcsh_kernel<<<B_ * NH_, 64, 0, stream>>>(kvm1, fc1_w, sh1_w, kv1);
        fcsh_kernel<<<B_ * NH_, 64, 0, stream>>>(kvm2, fc2_w, sh2_w, kv2);
        int tot = B_ * NH_ * 49 * HD_;
        int blocks = (tot + 255) / 256;
        vconv_kernel<<<blocks, 256, 0, stream>>>(kv1, lc1_w, lc1_b, v1c);
        vconv_kernel<<<blocks, 256, 0, stream>>>(kv2, lc2_w, lc2_b, v2c);
    }

    // 6. global flash attention, split-K=4 -> combine into catb cols [0,64)
    attn_global_split<<<dim3(N_ / 64, B_ * NSPLIT), 256, 0, stream>>>(q, kgb, vtb, osp, mls);
    attn_combine<<<(B_ * N_ * 64) / 256, 256, 0, stream>>>(osp, mls, catb);

    // 10. local attention -> catb cols [64,288) and [288,512)
    attn_local_kernel<<<dim3(N_ / 256, B_ * NH_), 256, 0, stream>>>(
        q, kv1, v1c, catb, D0_, D0_);
    attn_local_kernel<<<dim3(N_ / 256, B_ * NH_), 256, 0, stream>>>(
        q, kv2, v2c, catb, D0_ + HD_, D0_ + 224);

    // 11. out = catb @ projt^T + proj_b
    gemm_bf16_kernel<true><<<dim3(M / 128, 4), 256, 0, stream>>>(
        catb, projt, proj_b, out, 512, 512, 512);
}

// Round 10
// 387.444 us; speedup vs baseline: 7.5178x; 1.0685x over previous
//
#include <hip/hip_runtime.h>
#include <hip/hip_bf16.h>
#include <math.h>
#include <stdint.h>

// ---- problem constants ----
static constexpr int B_    = 2;
static constexpr int N_    = 12544;   // 112*112
static constexpr int DIM_  = 512;
static constexpr int D0_   = 64;
static constexpr int DL_   = 448;
static constexpr int Himg  = 112;
static constexpr int Wimg  = 112;
static constexpr int HS_   = 56;
static constexpr int NR_   = 3136;    // 56*56
static constexpr int NH_   = 8;
static constexpr int HD_   = 28;
static constexpr int NSPLIT = 4;

typedef unsigned short ushort_t;
typedef __attribute__((ext_vector_type(8))) short short8_t;
typedef __attribute__((ext_vector_type(4))) float float4v;
typedef __attribute__((ext_vector_type(4))) unsigned uint4v;
typedef __attribute__((ext_vector_type(2))) unsigned uint2v;

// round-to-nearest-even f32 -> bf16
static __device__ inline ushort_t bf16r(float x) {
    unsigned u = __builtin_bit_cast(unsigned, x);
    u = (u + 0x7FFFu + ((u >> 16) & 1u)) >> 16;
    return (ushort_t)u;
}
// pack two f32 -> u32 of 2 bf16 (lo, hi) -- software RNE (memory-bound kernels)
static __device__ inline unsigned pack_bf16(float lo, float hi) {
    unsigned a = __builtin_bit_cast(unsigned, lo);
    unsigned b = __builtin_bit_cast(unsigned, hi);
    a = (a + 0x7FFFu + ((a >> 16) & 1u)) >> 16;
    b = (b + 0x7FFFu + ((b >> 16) & 1u)) >> 16;
    return a | (b << 16);
}
// HW v_cvt_pk_bf16_f32 path (RNE, identical bits) for VALU-bound kernels
static __device__ inline unsigned cvtpk(float lo, float hi) {
    float2 f2; f2.x = lo; f2.y = hi;
    __hip_bfloat162 h = __float22bfloat162_rn(f2);
    unsigned u;
    __builtin_memcpy(&u, &h, 4);
    return u;
}

using gptr_t = const __attribute__((address_space(1))) void*;
using lptr_t = __attribute__((address_space(3))) void*;
static __device__ inline void gload16(const void* g, void* l) {
    __builtin_amdgcn_global_load_lds((gptr_t)(uintptr_t)g, (lptr_t)(uintptr_t)l, 16, 0, 0);
}

// =====================================================================
// bf16 MFMA GEMM: C[M][ldc] (fp32) = A[M][K](bf16) @ Bt[Npad][K](bf16)^T
// 128x128 tile, BK=64, 256 threads (4 waves in 2x2), single-buffer loop.
// =====================================================================
template<bool HASBIAS>
__global__ __launch_bounds__(256, 2)
void gemm_bf16_kernel(const ushort_t* __restrict__ A,
                      const ushort_t* __restrict__ Bt,
                      const float* __restrict__ bias,
                      float* __restrict__ C,
                      int Nn, int K, int ldc) {
    constexpr int BM = 128, BK = 64;
    __shared__ __align__(16) ushort_t As[BM * BK];
    __shared__ __align__(16) ushort_t Bs[BM * BK];
    const int bm = blockIdx.x * BM;
    const int bn = blockIdx.y * BM;
    const int tid = threadIdx.x;
    const int l15 = tid & 15;
    const int g   = (tid & 63) >> 4;
    const int w   = tid >> 6;
    const int wr  = w >> 1, wc = w & 1;

    float4v acc[4][4];
    #pragma unroll
    for (int m = 0; m < 4; ++m)
        #pragma unroll
        for (int n = 0; n < 4; ++n) acc[m][n] = (float4v){0.f, 0.f, 0.f, 0.f};

    for (int k0 = 0; k0 < K; k0 += BK) {
        #pragma unroll
        for (int i = 0; i < 4; ++i) {
            int c = i * 256 + tid;
            int r = c >> 3, ch = c & 7;
            int sch = ch ^ (r & 7);
            gload16(A  + (size_t)(bm + r) * K + k0 + sch * 8, (void*)(As + c * 8));
            gload16(Bt + (size_t)(bn + r) * K + k0 + sch * 8, (void*)(Bs + c * 8));
        }
        __syncthreads();

        short8_t af[4][2], bfr[4][2];
        #pragma unroll
        for (int m = 0; m < 4; ++m) {
            int ar = wr * 64 + m * 16 + l15;
            #pragma unroll
            for (int h = 0; h < 2; ++h)
                af[m][h] = *(const short8_t*)((const char*)As + ar * 128 + (((h * 4 + g) ^ (ar & 7)) * 16));
        }
        #pragma unroll
        for (int n = 0; n < 4; ++n) {
            int br = wc * 64 + n * 16 + l15;
            #pragma unroll
            for (int h = 0; h < 2; ++h)
                bfr[n][h] = *(const short8_t*)((const char*)Bs + br * 128 + (((h * 4 + g) ^ (br & 7)) * 16));
        }
        #pragma unroll
        for (int m = 0; m < 4; ++m)
            #pragma unroll
            for (int n = 0; n < 4; ++n) {
                acc[m][n] = __builtin_amdgcn_mfma_f32_16x16x32_bf16(af[m][0], bfr[n][0], acc[m][n], 0, 0, 0);
                acc[m][n] = __builtin_amdgcn_mfma_f32_16x16x32_bf16(af[m][1], bfr[n][1], acc[m][n], 0, 0, 0);
            }
        __syncthreads();
    }

    #pragma unroll
    for (int n = 0; n < 4; ++n) {
        int ccol = bn + wc * 64 + n * 16 + l15;
        if (ccol < Nn) {
            float bv = HASBIAS ? bias[ccol] : 0.f;
            #pragma unroll
            for (int m = 0; m < 4; ++m) {
                int crow = bm + wr * 64 + m * 16 + g * 4;
                #pragma unroll
                for (int j = 0; j < 4; ++j)
                    C[(size_t)(crow + j) * ldc + ccol] = acc[m][n][j] + bv;
            }
        }
    }
}

// =====================================================================
// weight convert: Wt[Npad][K] bf16 from W (transpose? W[K][Nn] : W[Nn][K])
// =====================================================================
__global__ __launch_bounds__(256)
void convw_kernel(const float* __restrict__ W, ushort_t* __restrict__ Wt,
                  int K, int Nn, int transpose) {
    int idx = blockIdx.x * 256 + threadIdx.x;
    int n = idx / K, k = idx % K;
    float v = 0.f;
    if (n < Nn) v = transpose ? W[(size_t)k * Nn + n] : W[(size_t)n * K + k];
    Wt[idx] = bf16r(v);
}

// sr_w transpose: wT[f][o] = sr_w[o*256 + f]  (fp32, 64x256 -> 256x64)
__global__ __launch_bounds__(256)
void srwt_kernel(const float* __restrict__ W, float* __restrict__ wT) {
    int idx = blockIdx.x * 256 + threadIdx.x;   // f*64 + o, 16384 total
    int f = idx >> 6, o = idx & 63;
    wT[idx] = W[o * 256 + f];
}

// fp32 -> bf16 bulk convert, 8 elems/thread
__global__ __launch_bounds__(256)
void convx_kernel(const float* __restrict__ in, ushort_t* __restrict__ outp) {
    int i = blockIdx.x * 256 + threadIdx.x;
    const float4v* p = (const float4v*)(in + (size_t)i * 8);
    float4v a = p[0], b = p[1];
    uint4v u;
    u[0] = pack_bf16(a[0], a[1]);
    u[1] = pack_bf16(a[2], a[3]);
    u[2] = pack_bf16(b[0], b[1]);
    u[3] = pack_bf16(b[2], b[3]);
    *(uint4v*)(outp + (size_t)i * 8) = u;
}

// =====================================================================
// sr-conv (2x2 stride2, 64->64, TRANSPOSED coalesced weights) +
// LayerNorm(64) + kv GEMM (64->128)
// =====================================================================
__global__ __launch_bounds__(64)
void srlnkv_kernel(const float* __restrict__ x,
                   const float* __restrict__ wT, const float* __restrict__ sr_b,
                   const float* __restrict__ ln_g, const float* __restrict__ ln_b,
                   const float* __restrict__ wkv,
                   ushort_t* __restrict__ kgb, float* __restrict__ vg) {
    const int pos = blockIdx.x;              // b*NR + n
    const int b = pos / NR_, n = pos % NR_;
    const int y = n / HS_, xx = n % HS_;
    const int o = threadIdx.x;               // 0..63
    __shared__ float xs[4][64];
    __shared__ float lnv_s[64];
    #pragma unroll
    for (int tap = 0; tap < 4; ++tap) {
        int ky = tap / 2, kx = tap % 2;
        xs[tap][o] = x[((size_t)b * N_ + (2 * y + ky) * Wimg + 2 * xx + kx) * DIM_ + o];
    }
    __syncthreads();
    float sum = sr_b[o];
    for (int i = 0; i < 64; ++i) {
        const float* wr = wT + (i * 4) * 64 + o;   // lane-coalesced rows
        sum += xs[0][i] * wr[0] + xs[1][i] * wr[64] + xs[2][i] * wr[128] + xs[3][i] * wr[192];
    }
    float m = sum;
    #pragma unroll
    for (int off = 1; off < 64; off <<= 1) m += __shfl_xor(m, off);
    m *= (1.0f / 64.0f);
    float d = sum - m;
    float v = d * d;
    #pragma unroll
    for (int off = 1; off < 64; off <<= 1) v += __shfl_xor(v, off);
    v *= (1.0f / 64.0f);
    float lnv = d * rsqrtf(v + 1e-5f) * ln_g[o] + ln_b[o];
    lnv_s[o] = lnv;
    __syncthreads();
    float s0 = 0.f, s1 = 0.f;
    for (int i = 0; i < 64; ++i) {
        float lv = lnv_s[i];
        s0 += lv * wkv[i * 128 + o];
        s1 += lv * wkv[i * 128 + o + 64];
    }
    kgb[((size_t)b * NR_ + n) * 64 + o] = bf16r(s0);
    vg[((size_t)b * NR_ + n) * 64 + o] = s1;
}

// =====================================================================
// depthwise 3x3 + bias on v_g image; vg2 = vg + conv (fp32)
// =====================================================================
__global__ __launch_bounds__(256)
void lcg_kernel(const float* __restrict__ vg, const float* __restrict__ w,
                const float* __restrict__ bias, float* __restrict__ vg2) {
    int idx = blockIdx.x * 256 + threadIdx.x;
    if (idx >= B_ * NR_ * 64) return;
    int c = idx % 64;
    int n = (idx / 64) % NR_;
    int b = idx / (64 * NR_);
    int y = n / HS_, xx = n % HS_;
    float sum = vg[idx] + bias[c];
    #pragma unroll
    for (int ky = 0; ky < 3; ++ky)
        #pragma unroll
        for (int kx = 0; kx < 3; ++kx) {
            int yy = y + ky - 1, x2 = xx + kx - 1;
            if (yy >= 0 && yy < HS_ && x2 >= 0 && x2 < HS_)
                sum += vg[((size_t)b * NR_ + yy * HS_ + x2) * 64 + c] * w[c * 9 + ky * 3 + kx];
        }
    vg2[idx] = sum;
}

// =====================================================================
// transpose+convert: vg2 fp32 [B][NR][64] -> vtb bf16 [B][64][NR]
// =====================================================================
__global__ __launch_bounds__(256)
void vtrans_kernel(const float* __restrict__ vg2, ushort_t* __restrict__ vtb) {
    __shared__ float ld[64][65];
    const int b = blockIdx.y, n0 = blockIdx.x * 64, tid = threadIdx.x;
    #pragma unroll
    for (int i = 0; i < 16; ++i) {
        int idx = i * 256 + tid;
        int n = idx >> 6, c = idx & 63;
        ld[n][c] = vg2[((size_t)b * NR_ + n0 + n) * 64 + c];
    }
    __syncthreads();
    #pragma unroll
    for (int i = 0; i < 16; ++i) {
        int idx = i * 256 + tid;
        int d = idx >> 6, nn = idx & 63;
        vtb[(size_t)(b * 64 + d) * NR_ + n0 + nn] = bf16r(ld[nn][d]);
    }
}

// =====================================================================
// Global-branch flash attention, split-K (4 splits), bf16 MFMA.
// 256 threads (4 waves), 64 q-rows/block. exp2-domain softmax.
// =====================================================================
__global__ __launch_bounds__(256)
void attn_global_split(const float* __restrict__ q,
                       const ushort_t* __restrict__ kgb,
                       const ushort_t* __restrict__ vtb,
                       float* __restrict__ osp, float* __restrict__ mls) {
    __shared__ __align__(16) ushort_t Ks[64 * 64];
    __shared__ __align__(16) ushort_t Vs[64 * 64];
    __shared__ __align__(16) unsigned Pu[4 * 512];   // 4 waves x 16 rows x 32 u32
    const int split = blockIdx.y & 3;
    const int b     = blockIdx.y >> 2;
    const int q0    = blockIdx.x * 64;
    const int tid   = threadIdx.x;
    const int w     = tid >> 6;       // wave 0..3
    const int l     = tid & 63;
    const int l15   = l & 15;
    const int g     = l >> 4;
    const int lx    = l15 & 7;
    const float SC  = 0.125f * 1.44269504088896340736f;   // scale * log2(e)

    short8_t qf[2];
    {
        const float* qrow = q + ((size_t)b * N_ + q0 + w * 16 + l15) * DIM_;
        #pragma unroll
        for (int dc = 0; dc < 2; ++dc) {
            const float4v* p4 = (const float4v*)(qrow + g * 8 + 32 * dc);
            float4v x0 = p4[0], x1 = p4[1];
            uint4v uv;
            uv[0] = cvtpk(x0[0] * SC, x0[1] * SC);
            uv[1] = cvtpk(x0[2] * SC, x0[3] * SC);
            uv[2] = cvtpk(x1[0] * SC, x1[1] * SC);
            uv[3] = cvtpk(x1[2] * SC, x1[3] * SC);
            qf[dc] = __builtin_bit_cast(short8_t, uv);
        }
    }

    float4v o[4];
    #pragma unroll
    for (int i = 0; i < 4; ++i) o[i] = (float4v){0.f, 0.f, 0.f, 0.f};
    float m_run = -3.0e38f, l_run = 0.f;

    const int t0 = split ? split * 12 + 1 : 0;
    const int t1 = split * 12 + 13;
    for (int t = t0; t < t1; ++t) {
        const int k0 = t * 64;
        #pragma unroll
        for (int i = 0; i < 2; ++i) {
            int c = i * 256 + tid;          // 0..511
            int r = c >> 3, ch = c & 7;
            int sch = ch ^ (r & 7);
            gload16(kgb + ((size_t)(b * NR_ + k0 + r) << 6) + sch * 8, (void*)(Ks + c * 8));
            gload16(vtb + (size_t)(b * 64 + r) * NR_ + k0 + sch * 8, (void*)(Vs + c * 8));
        }
        __syncthreads();

        float4v sc[4];
        #pragma unroll
        for (int c = 0; c < 4; ++c) {
            float4v acc = (float4v){0.f, 0.f, 0.f, 0.f};
            #pragma unroll
            for (int dc = 0; dc < 2; ++dc) {
                int row = c * 16 + l15;
                short8_t ak = *(const short8_t*)((const char*)Ks + row * 128 + (((g + 4 * dc) ^ lx) * 16));
                acc = __builtin_amdgcn_mfma_f32_16x16x32_bf16(ak, qf[dc], acc, 0, 0, 0);
            }
            sc[c] = acc;
        }

        float tmax = fmaxf(fmaxf(fmaxf(sc[0][0], sc[0][1]), fmaxf(sc[0][2], sc[0][3])),
                           fmaxf(fmaxf(sc[1][0], sc[1][1]), fmaxf(sc[1][2], sc[1][3])));
        tmax = fmaxf(tmax, fmaxf(fmaxf(fmaxf(sc[2][0], sc[2][1]), fmaxf(sc[2][2], sc[2][3])),
                                 fmaxf(fmaxf(sc[3][0], sc[3][1]), fmaxf(sc[3][2], sc[3][3]))));
        tmax = fmaxf(tmax, __shfl_xor(tmax, 16));
        tmax = fmaxf(tmax, __shfl_xor(tmax, 32));

        if (__any(tmax > m_run + 11.0f)) {
            float m_new = fmaxf(m_run, tmax);
            float corr = __builtin_amdgcn_exp2f(m_run - m_new);
            float co[4];
            #pragma unroll
            for (int r = 0; r < 4; ++r) co[r] = __shfl(corr, g * 4 + r);
            #pragma unroll
            for (int dc = 0; dc < 4; ++dc)
                #pragma unroll
                for (int r = 0; r < 4; ++r) o[dc][r] *= co[r];
            l_run *= corr;
            m_run = m_new;
        }

        float p[4][4];
        float ladd = 0.f;
        #pragma unroll
        for (int c = 0; c < 4; ++c)
            #pragma unroll
            for (int r = 0; r < 4; ++r) {
                float pe = __builtin_amdgcn_exp2f(sc[c][r] - m_run);
                p[c][r] = pe;
                ladd += pe;
            }
        ladd += __shfl_xor(ladd, 16);
        ladd += __shfl_xor(ladd, 32);
        l_run += ladd;

        {
            unsigned* Pw = Pu + w * 512 + l15 * 32;
            #pragma unroll
            for (int c = 0; c < 4; ++c) {
                int u32i = 8 * c + 2 * g;
                int usw = (((u32i >> 2) ^ lx) << 2) | (u32i & 3);
                Pw[usw]     = cvtpk(p[c][0], p[c][1]);
                Pw[usw + 1] = cvtpk(p[c][2], p[c][3]);
            }
        }
        __syncthreads();

        #pragma unroll
        for (int kkc = 0; kkc < 2; ++kkc) {
            short8_t ap = *(const short8_t*)((const char*)Pu + w * 2048 + l15 * 128 + (((kkc * 4 + g) ^ lx) * 16));
            #pragma unroll
            for (int dc = 0; dc < 4; ++dc) {
                int vrow = dc * 16 + l15;
                short8_t bv = *(const short8_t*)((const char*)Vs + vrow * 128 + (((kkc * 4 + g) ^ lx) * 16));
                o[dc] = __builtin_amdgcn_mfma_f32_16x16x32_bf16(ap, bv, o[dc], 0, 0, 0);
            }
        }
        __syncthreads();
    }

    const size_t rbase = (size_t)(split * B_ + b) * N_;
    #pragma unroll
    for (int dc = 0; dc < 4; ++dc)
        #pragma unroll
        for (int r = 0; r < 4; ++r) {
            int row = q0 + w * 16 + g * 4 + r;
            osp[(rbase + row) * 64 + dc * 16 + l15] = o[dc][r];
        }
    if (l < 16) {
        int row = q0 + w * 16 + l15;
        mls[(rbase + row) * 2]     = m_run;
        mls[(rbase + row) * 2 + 1] = l_run;
    }
}

// =====================================================================
// combine the 4 splits (exp2 domain) -> catb cols [0,64)
// =====================================================================
__global__ __launch_bounds__(256)
void attn_combine(const float* __restrict__ osp, const float* __restrict__ mls,
                  ushort_t* __restrict__ catb) {
    int idx = blockIdx.x * 256 + threadIdx.x;   // B*N*64
    int col = idx & 63;
    size_t rn = (size_t)(idx >> 6);             // b*N + row
    const size_t BN = (size_t)B_ * N_;
    float ms[NSPLIT], ls[NSPLIT];
    float m = -3.0e38f;
    #pragma unroll
    for (int s = 0; s < NSPLIT; ++s) {
        ms[s] = mls[(s * BN + rn) * 2];
        ls[s] = mls[(s * BN + rn) * 2 + 1];
        m = fmaxf(m, ms[s]);
    }
    float lsum = 0.f, acc = 0.f;
    #pragma unroll
    for (int s = 0; s < NSPLIT; ++s) {
        float wgt = __builtin_amdgcn_exp2f(ms[s] - m);
        lsum += ls[s] * wgt;
        acc  += osp[(s * BN + rn) * 64 + col] * wgt;
    }
    catb[rn * DIM_ + col] = bf16r(acc / lsum);
}

// =====================================================================
// depthwise 3x3 + bias on x_l, vectorized: 4 channels x 4 y-rows / thread
// =====================================================================
__global__ __launch_bounds__(256)
void dwt_kernel(const float* __restrict__ x, const float* __restrict__ w,
                const float* __restrict__ bias, ushort_t* __restrict__ out) {
    int idx = blockIdx.x * 256 + threadIdx.x;
    int c4 = idx % 112;
    int t1 = idx / 112;
    int xx = t1 % 112;
    int t2 = t1 / 112;
    int yg = t2 % 28;
    int b  = t2 / 28;
    int c0 = c4 * 4;
    int y0 = yg * 4;

    float4v w4[9];
    #pragma unroll
    for (int kt = 0; kt < 9; ++kt) {
        w4[kt][0] = w[(c0 + 0) * 9 + kt];
        w4[kt][1] = w[(c0 + 1) * 9 + kt];
        w4[kt][2] = w[(c0 + 2) * 9 + kt];
        w4[kt][3] = w[(c0 + 3) * 9 + kt];
    }
    float4v bv = *(const float4v*)(bias + c0);
    float4v acc[4];
    #pragma unroll
    for (int o2 = 0; o2 < 4; ++o2) acc[o2] = bv;

    #pragma unroll
    for (int yy = 0; yy < 6; ++yy) {
        int Y = y0 - 1 + yy;
        if (Y < 0 || Y >= Himg) continue;
        #pragma unroll
        for (int xt = 0; xt < 3; ++xt) {
            int X = xx - 1 + xt;
            if (X < 0 || X >= Wimg) continue;
            float4v v = *(const float4v*)(x + ((size_t)b * N_ + Y * Wimg + X) * DIM_ + D0_ + c0);
            constexpr int olo_t[6] = {0, 0, 0, 1, 2, 3};
            constexpr int ohi_t[6] = {0, 1, 2, 3, 3, 3};
            #pragma unroll
            for (int o2 = olo_t[yy]; o2 <= ohi_t[yy]; ++o2) {
                float4v wv = w4[(yy - o2) * 3 + xt];
                acc[o2][0] += v[0] * wv[0];
                acc[o2][1] += v[1] * wv[1];
                acc[o2][2] += v[2] * wv[2];
                acc[o2][3] += v[3] * wv[3];
            }
        }
    }
    #pragma unroll
    for (int o2 = 0; o2 < 4; ++o2) {
        uint2v pk;
        pk[0] = pack_bf16(acc[o2][0], acc[o2][1]);
        pk[1] = pack_bf16(acc[o2][2], acc[o2][3]);
        *(uint2v*)(out + ((size_t)b * N_ + (y0 + o2) * Wimg + xx) * DL_ + c0) = pk;
    }
}

// =====================================================================
// "scrambled mean", block-parallel: one block per (b,h,n).
// =====================================================================
template<int L, int NBW, int STRIDE, int DIL, int CHOFF>
__global__ void local_mean2_kernel(const float* __restrict__ kvl,
                                   float* __restrict__ kvm) {
    __shared__ float slo[L], shi[L];
    const int blk = blockIdx.x;                  // b*NH*49 + h*49 + n
    const int n = blk % 49;
    const int h = (blk / 49) % NH_;
    const int b = blk / (49 * NH_);
    const int wy = n / 7, wx = n % 7;
    const int t = threadIdx.x;

    if (t < L) {
        const int by = t / NBW, bx = t % NBW;
        int Y = by * STRIDE + DIL * wy;
        int X = bx * STRIDE + DIL * wx;
        if (Y >= Himg) Y = 2 * Himg - 2 - Y;     // reflect
        if (X >= Wimg) X = 2 * Wimg - 2 - X;
        const float* src = kvl + ((size_t)b * N_ + Y * Wimg + X) * DL_ + CHOFF + h * HD_;
        float v[28];
        #pragma unroll
        for (int i = 0; i < 7; ++i) {
            float4v q4 = ((const float4v*)src)[i];
            v[i * 4] = q4[0]; v[i * 4 + 1] = q4[1]; v[i * 4 + 2] = q4[2]; v[i * 4 + 3] = q4[3];
        }
        const int f0 = t * HD_;
        const int bin0 = f0 / L;
        const int nlo = min(HD_, (bin0 + 1) * L - f0);   // elems in bin0
        float s0 = 0.f, s1 = 0.f;
        #pragma unroll
        for (int j = 0; j < HD_; ++j) {
            if (j < nlo) s0 += v[j]; else s1 += v[j];
        }
        slo[t] = s0;
        shi[t] = s1;
    }
    __syncthreads();
    if (t < HD_) {
        const int t_lo = (t * L) / HD_;
        const int t_hi = min(L - 1, (t * L + L - 1) / HD_);
        float sum = 0.f;
        for (int u = t_lo; u <= t_hi; ++u) {
            int f0 = u * HD_;
            int b0 = f0 / L;
            int b1 = (f0 + HD_ - 1) / L;
            if (b0 == t) sum += slo[u];
            if (b1 == t && b1 != b0) sum += shi[u];
        }
        kvm[(size_t)blk * HD_ + t] = sum * (1.0f / (float)L);
    }
}

// =====================================================================
// kv = kvm @ fc_w @ sh_w -> (B*NH, 49, 56)
// =====================================================================
__global__ __launch_bounds__(64)
void fcsh_kernel(const float* __restrict__ kvm, const float* __restrict__ fcw,
                 const float* __restrict__ shw, float* __restrict__ out) {
    int bh = blockIdx.x;
    __shared__ float kin[49][28];
    __shared__ float tmp[49][28];
    __shared__ float fw[28 * 28];
    __shared__ float sw[28 * 56];
    int t = threadIdx.x;
    for (int i = t; i < 49 * 28; i += 64) kin[i / 28][i % 28] = kvm[bh * 49 * 28 + i];
    for (int i = t; i < 28 * 28; i += 64) fw[i] = fcw[i];
    for (int i = t; i < 28 * 56; i += 64) sw[i] = shw[i];
    __syncthreads();
    for (int i = t; i < 49 * 28; i += 64) {
        int rr = i / 28, j = i % 28;
        float s = 0.f;
        for (int k = 0; k < 28; ++k) s += kin[rr][k] * fw[k * 28 + j];
        tmp[rr][j] = s;
    }
    __syncthreads();
    for (int i = t; i < 49 * 56; i += 64) {
        int rr = i / 56, j = i % 56;
        float s = 0.f;
        for (int k = 0; k < 28; ++k) s += tmp[rr][k] * sw[k * 56 + j];
        out[bh * 49 * 56 + i] = s;
    }
}

// =====================================================================
// v_ + depthwise3x3(v_img 7x7) + bias -> vc (B*NH, 49, 28)
// =====================================================================
__global__ __launch_bounds__(256)
void vconv_kernel(const float* __restrict__ kvsh, const float* __restrict__ w,
                  const float* __restrict__ bias, float* __restrict__ vc) {
    int idx = blockIdx.x * 256 + threadIdx.x;
    if (idx >= B_ * NH_ * 49 * HD_) return;
    int d  = idx % HD_;
    int n  = (idx / HD_) % 49;
    int bh = idx / (HD_ * 49);
    int h  = bh % NH_;
    int y = n / 7, xx = n % 7;
    int c = h * HD_ + d;
    float sum = kvsh[(bh * 49 + n) * 56 + 28 + d] + bias[c];
    #pragma unroll
    for (int ky = 0; ky < 3; ++ky)
        #pragma unroll
        for (int kx = 0; kx < 3; ++kx) {
            int yy = y + ky - 1, x2 = xx + kx - 1;
            if (yy >= 0 && yy < 7 && x2 >= 0 && x2 < 7)
                sum += kvsh[(bh * 49 + yy * 7 + x2) * 56 + 28 + d] * w[c * 9 + ky * 3 + kx];
        }
    vc[idx] = sum;
}

// =====================================================================
// local attention: 49 keys, hd=28. one thread per q-row.
// =====================================================================
__global__ __launch_bounds__(256)
void attn_local_kernel(const float* __restrict__ q, const float* __restrict__ kvsh,
                       const float* __restrict__ vc, ushort_t* __restrict__ catb,
                       int qcoloff, int outcoloff) {
    const int bh = blockIdx.y;
    const int b = bh / NH_, h = bh % NH_;
    const int n = blockIdx.x * 256 + threadIdx.x;
    __shared__ float Ks[49][28];
    __shared__ float Vsh[49][28];
    const int t = threadIdx.x;
    for (int i = t; i < 49 * 28; i += 256) {
        int rr = i / 28, d = i % 28;
        Ks[rr][d]  = kvsh[(bh * 49 + rr) * 56 + d];
        Vsh[rr][d] = vc[(bh * 49 + rr) * 28 + d];
    }
    __syncthreads();
    float qr[28];
    {
        const float4v* qp4 = (const float4v*)(q + ((size_t)b * N_ + n) * DIM_ + qcoloff + h * 56);
        #pragma unroll
        for (int i = 0; i < 7; ++i) {
            float4v v = qp4[i];
            qr[i * 4] = v[0]; qr[i * 4 + 1] = v[1]; qr[i * 4 + 2] = v[2]; qr[i * 4 + 3] = v[3];
        }
    }
    const float scale = 0.1889822365046136f;   // 28^-0.5
    float mx = -1e30f;
    for (int k = 0; k < 49; ++k) {
        float s = 0.f;
        #pragma unroll
        for (int d = 0; d < 28; ++d) s += qr[d] * Ks[k][d];
        mx = fmaxf(mx, s * scale);
    }
    float l = 0.f;
    float acc[28] = {};
    for (int k = 0; k < 49; ++k) {
        float s = 0.f;
        #pragma unroll
        for (int d = 0; d < 28; ++d) s += qr[d] * Ks[k][d];
        float p = __expf(s * scale - mx);
        l += p;
        #pragma unroll
        for (int d = 0; d < 28; ++d) acc[d] += p * Vsh[k][d];
    }
    float inv = 1.f / l;
    ushort_t* op = catb + ((size_t)b * N_ + n) * DIM_ + outcoloff + h * HD_;
    #pragma unroll
    for (int d = 0; d < 28; ++d) op[d] = bf16r(acc[d] * inv);
}

// =====================================================================
extern "C" void kernel_launch(void* const* d_in, const int* in_sizes, int n_in,
                              void* d_out, int out_size, void* d_ws, size_t ws_size,
                              hipStream_t stream) {
    const float* x      = (const float*)d_in[0];
    const float* Wq     = (const float*)d_in[1];
    const float* Wkv_g  = (const float*)d_in[2];
    const float* sr_w   = (const float*)d_in[3];
    const float* sr_b   = (const float*)d_in[4];
    const float* ln_g   = (const float*)d_in[5];
    const float* ln_b   = (const float*)d_in[6];
    const float* lcg_w  = (const float*)d_in[7];
    const float* lcg_b  = (const float*)d_in[8];
    const float* kvl_dw = (const float*)d_in[9];
    const float* kvl_db = (const float*)d_in[10];
    const float* kvl_pw = (const float*)d_in[11];
    const float* kvl_pb = (const float*)d_in[12];
    const float* fc1_w  = (const float*)d_in[13];
    const float* sh1_w  = (const float*)d_in[14];
    const float* lc1_w  = (const float*)d_in[15];
    const float* lc1_b  = (const float*)d_in[16];
    const float* fc2_w  = (const float*)d_in[17];
    const float* sh2_w  = (const float*)d_in[18];
    const float* lc2_w  = (const float*)d_in[19];
    const float* lc2_b  = (const float*)d_in[20];
    const float* proj_w = (const float*)d_in[21];
    const float* proj_b = (const float*)d_in[22];
    float* out = (float*)d_out;
    char* base = (char*)d_ws;

    // ---- workspace layout (256B aligned) ----
    size_t o = 0;
    auto alloc = [&](size_t bytes) -> void* {
        void* p = base + o;
        o = (o + bytes + 255) & ~(size_t)255;
        return p;
    };
    float*    q     = (float*)   alloc((size_t)B_ * N_ * DIM_ * 4);
    float*    kvl   = (float*)   alloc((size_t)B_ * N_ * DL_ * 4);   // later osp+mls
    ushort_t* xcat  = (ushort_t*)alloc((size_t)B_ * N_ * DIM_ * 2);  // xbf, then cat
    ushort_t* dwtb  = (ushort_t*)alloc((size_t)B_ * N_ * DL_ * 2);
    ushort_t* kgb   = (ushort_t*)alloc((size_t)B_ * NR_ * 64 * 2);
    float*    vg    = (float*)   alloc((size_t)B_ * NR_ * 64 * 4);
    float*    vg2   = (float*)   alloc((size_t)B_ * NR_ * 64 * 4);
    ushort_t* vtb   = (ushort_t*)alloc((size_t)B_ * 64 * NR_ * 2);
    ushort_t* wqt   = (ushort_t*)alloc((size_t)512 * 512 * 2);
    ushort_t* pwt   = (ushort_t*)alloc((size_t)512 * 448 * 2);
    ushort_t* projt = (ushort_t*)alloc((size_t)512 * 512 * 2);
    float*    srwt  = (float*)   alloc((size_t)256 * 64 * 4);
    float*    kvm1  = (float*)   alloc((size_t)B_ * NH_ * 49 * HD_ * 4);
    float*    kvm2  = (float*)   alloc((size_t)B_ * NH_ * 49 * HD_ * 4);
    float*    kv1   = (float*)   alloc((size_t)B_ * NH_ * 49 * 56 * 4);
    float*    kv2   = (float*)   alloc((size_t)B_ * NH_ * 49 * 56 * 4);
    float*    v1c   = (float*)   alloc((size_t)B_ * NH_ * 49 * HD_ * 4);
    float*    v2c   = (float*)   alloc((size_t)B_ * NH_ * 49 * HD_ * 4);
    ushort_t* xbf  = xcat;
    ushort_t* catb = xcat;
    // osp/mls alias kvl (consumed by local_mean before attention runs)
    float* osp = kvl;                                        // NSPLIT*B*N*64 floats
    float* mls = kvl + (size_t)NSPLIT * B_ * N_ * 64;        // NSPLIT*B*N*2 floats

    const int M = B_ * N_;   // 25088

    // 0. weight converts + x -> bf16
    convw_kernel<<<512 * 512 / 256, 256, 0, stream>>>(Wq, wqt, 512, 512, 1);
    convw_kernel<<<512 * 448 / 256, 256, 0, stream>>>(kvl_pw, pwt, 448, 448, 0);
    convw_kernel<<<512 * 512 / 256, 256, 0, stream>>>(proj_w, projt, 512, 512, 1);
    srwt_kernel<<<64, 256, 0, stream>>>(sr_w, srwt);
    convx_kernel<<<(B_ * N_ * DIM_ / 8) / 256, 256, 0, stream>>>(x, xbf);

    // 1. q = x @ Wq   (bf16 MFMA)
    gemm_bf16_kernel<false><<<dim3(M / 128, 4), 256, 0, stream>>>(
        xbf, wqt, nullptr, q, 512, 512, 512);

    // 2. depthwise on x_l -> dwtb (bf16), 4ch x 4row per thread
    dwt_kernel<<<(B_ * 28 * 112 * 112) / 256, 256, 0, stream>>>(x, kvl_dw, kvl_db, dwtb);

    // 3. pointwise: kvl = dwtb @ pwt^T + pb
    gemm_bf16_kernel<true><<<dim3(M / 128, 4), 256, 0, stream>>>(
        dwtb, pwt, kvl_pb, kvl, 448, 448, 448);

    // 4. global branch: sr conv (coalesced wT) + LN + kv (K as bf16)
    srlnkv_kernel<<<B_ * NR_, 64, 0, stream>>>(x, srwt, sr_b, ln_g, ln_b, Wkv_g, kgb, vg);

    // 5. vg2 = vg + depthwise(vg); then transpose+convert to vtb
    lcg_kernel<<<(B_ * NR_ * 64) / 256, 256, 0, stream>>>(vg, lcg_w, lcg_b, vg2);
    vtrans_kernel<<<dim3(NR_ / 64, B_), 256, 0, stream>>>(vg2, vtb);

    // 7-9. local branch pipeline (consumes kvl BEFORE osp aliases it)
    {
        local_mean2_kernel<256, 16, 7, 1, 0><<<B_ * NH_ * 49, 256, 0, stream>>>(kvl, kvm1);
        local_mean2_kernel<81, 9, 13, 2, 224><<<B_ * NH_ * 49, 128, 0, stream>>>(kvl, kvm2);
        fcsh_kernel<<<B_ * NH_, 64, 0, stream>>>(kvm1, fc1_w, sh1_w, kv1);
        fcsh_kernel<<<B_ * NH_, 64, 0, stream>>>(kvm2, fc2_w, sh2_w, kv2);
        int tot = B_ * NH_ * 49 * HD_;
        int blocks = (tot + 255) / 256;
        vconv_kernel<<<blocks, 256, 0, stream>>>(kv1, lc1_w, lc1_b, v1c);
        vconv_kernel<<<blocks, 256, 0, stream>>>(kv2, lc2_w, lc2_b, v2c);
    }

    // 6. global flash attention, split-K=4 -> combine into catb cols [0,64)
    attn_global_split<<<dim3(N_ / 64, B_ * NSPLIT), 256, 0, stream>>>(q, kgb, vtb, osp, mls);
    attn_combine<<<(B_ * N_ * 64) / 256, 256, 0, stream>>>(osp, mls, catb);

    // 10. local attention -> catb cols [64,288) and [288,512)
    attn_local_kernel<<<dim3(N_ / 256, B_ * NH_), 256, 0, stream>>>(
        q, kv1, v1c, catb, D0_, D0_);
    attn_local_kernel<<<dim3(N_ / 256, B_ * NH_), 256, 0, stream>>>(
        q, kv2, v2c, catb, D0_ + HD_, D0_ + 224);

    // 11. out = catb @ projt^T + proj_b
    gemm_bf16_kernel<true><<<dim3(M / 128, 4), 256, 0, stream>>>(
        catb, projt, proj_b, out, 512, 512, 512);
}